// Round 1
// baseline (12994.832 us; speedup 1.0000x reference)
//
#include <hip/hip_runtime.h>

// ---------------------------------------------------------------------------
// TransMIL forward on MI355X — round 0: correctness-first fp32 baseline.
//
// Pipeline:
//  1. ft = relu(maxpool2(x) @ fc1_w + b)        (20480x1024x512 GEMM, pool fused)
//     -> written directly into h rows 1..20480 and wrap rows 20481..20736
//  2. h[0] = cls
//  3. layer { LN -> padded xp; qkv GEMM (head-major scatter, q*0.125);
//             landmarks (mean over 82); a2 = softmax(ql@kl^T);
//             pinv: scale + 6x Newton-Schulz (4 bmm256 each);
//             t1 = softmax(ql@k^T)@v   (online softmax, 1 wave/(h,lm));
//             t2 = z@t1; out = softmax(q@kl^T)@t2 + depthwise-conv33(v);
//             h += out @ out_w + out_b }
//  4. PPEG depthwise 7/5/3 convs on 144x144 image (channels=512)
//  5. layer (l2 weights)
//  6. LN row0 -> fc3 -> logits/softmax/argmax -> d_out[9]
//
// Workspace: ~219 MiB fp32 (h, xp(=out_m,=ppeg tmp), q, k, v, pinv smalls).
// ---------------------------------------------------------------------------

constexpr int D_    = 512;
constexpr int E_    = 1024;
constexpr int NTOK  = 20737;
constexpr int NP_   = 20992;   // padded seq len (255 zero rows at FRONT)
constexpr int NH_   = 8;
constexpr int HD_   = 64;
constexpr int MLM   = 256;     // landmarks
constexpr int LCH   = 82;      // tokens per landmark
constexpr int HHW   = 144;
constexpr int NFEAT = 20736;   // 144*144
constexpr int PADR  = 255;

// ---------------- reduction helpers ----------------
__device__ __forceinline__ float waveMaxF(float v){
#pragma unroll
  for (int o = 32; o > 0; o >>= 1) v = fmaxf(v, __shfl_xor(v, o));
  return v;
}
__device__ __forceinline__ float waveSumF(float v){
#pragma unroll
  for (int o = 32; o > 0; o >>= 1) v += __shfl_xor(v, o);
  return v;
}
// 256-thread block reductions (sbuf: >=4 floats of LDS)
__device__ __forceinline__ float blockMax256(float v, float* sbuf){
  v = waveMaxF(v);
  if ((threadIdx.x & 63) == 0) sbuf[threadIdx.x >> 6] = v;
  __syncthreads();
  float r = fmaxf(fmaxf(sbuf[0], sbuf[1]), fmaxf(sbuf[2], sbuf[3]));
  __syncthreads();
  return r;
}
__device__ __forceinline__ float blockSum256(float v, float* sbuf){
  v = waveSumF(v);
  if ((threadIdx.x & 63) == 0) sbuf[threadIdx.x >> 6] = v;
  __syncthreads();
  float r = sbuf[0] + sbuf[1] + sbuf[2] + sbuf[3];
  __syncthreads();
  return r;
}

// ---------------- 1. fc1: relu(maxpool2(x) @ w + b) -> h rows ----------------
// grid (320, 8), block (16,16)
__global__ __launch_bounds__(256) void fc1_kernel(
    const float* __restrict__ x, const float* __restrict__ w,
    const float* __restrict__ bias, float* __restrict__ h){
  __shared__ float As[16][65];
  __shared__ float Bs[16][65];
  const int bm = blockIdx.x * 64, bn = blockIdx.y * 64;
  const int tid = threadIdx.y * 16 + threadIdx.x;
  float acc[4][4] = {};
  for (int k0 = 0; k0 < E_; k0 += 16){
#pragma unroll
    for (int r = 0; r < 4; r++){
      int e = tid + r * 256;
      int m = e >> 4, kk = e & 15;
      size_t row = (size_t)(bm + m) * 2;
      float v0 = x[row * E_ + k0 + kk];
      float v1 = x[(row + 1) * E_ + k0 + kk];
      As[kk][m] = fmaxf(v0, v1);
    }
#pragma unroll
    for (int r = 0; r < 4; r++){
      int e = tid + r * 256;
      int kk = e >> 6, n = e & 63;
      Bs[kk][n] = w[(size_t)(k0 + kk) * D_ + bn + n];
    }
    __syncthreads();
#pragma unroll
    for (int kk = 0; kk < 16; kk++){
      float a[4], b[4];
#pragma unroll
      for (int i = 0; i < 4; i++) a[i] = As[kk][threadIdx.y * 4 + i];
#pragma unroll
      for (int j = 0; j < 4; j++) b[j] = Bs[kk][threadIdx.x * 4 + j];
#pragma unroll
      for (int i = 0; i < 4; i++)
#pragma unroll
        for (int j = 0; j < 4; j++) acc[i][j] += a[i] * b[j];
    }
    __syncthreads();
  }
#pragma unroll
  for (int i = 0; i < 4; i++){
    int row = bm + threadIdx.y * 4 + i;
#pragma unroll
    for (int j = 0; j < 4; j++){
      int col = bn + threadIdx.x * 4 + j;
      float v = fmaxf(acc[i][j] + bias[col], 0.f);
      h[(size_t)(1 + row) * D_ + col] = v;                 // h rows 1..20480
      if (row < 256) h[(size_t)(20481 + row) * D_ + col] = v;  // wrap rows
    }
  }
}

__global__ void cls_kernel(const float* __restrict__ cls, float* __restrict__ h){
  int c = blockIdx.x * 256 + threadIdx.x;
  if (c < D_) h[c] = cls[c];
}

// ---------------- layernorm -> zero-padded xp ----------------
// grid NP_, block 256 (2 elems/thread)
__global__ __launch_bounds__(256) void ln_pad_kernel(
    const float* __restrict__ h, const float* __restrict__ w,
    const float* __restrict__ b, float* __restrict__ xp){
  const int r = blockIdx.x;
  const int t = threadIdx.x;
  if (r < PADR){
    xp[(size_t)r * D_ + t] = 0.f;
    xp[(size_t)r * D_ + 256 + t] = 0.f;
    return;
  }
  __shared__ float s4[4];
  const float* x = h + (size_t)(r - PADR) * D_;
  float a0 = x[t], a1 = x[t + 256];
  float mu = blockSum256(a0 + a1, s4) * (1.f / 512.f);
  float d0 = a0 - mu, d1 = a1 - mu;
  float var = blockSum256(d0 * d0 + d1 * d1, s4) * (1.f / 512.f);
  float rs = rsqrtf(var + 1e-5f);
  xp[(size_t)r * D_ + t]       = d0 * rs * w[t] + b[t];
  xp[(size_t)r * D_ + 256 + t] = d1 * rs * w[t + 256] + b[t + 256];
}

// ---------------- qkv GEMM: xp(20992x512) @ qkv_w(512x1536) ----------------
// scatter epilogue to head-major q/k/v; q scaled by 1/8. grid (328,24), block(16,16)
__global__ __launch_bounds__(256) void qkv_kernel(
    const float* __restrict__ A, const float* __restrict__ B,
    float* __restrict__ q, float* __restrict__ k, float* __restrict__ v){
  __shared__ float As[16][65];
  __shared__ float Bs[16][65];
  const int bm = blockIdx.x * 64, bn = blockIdx.y * 64;
  const int tid = threadIdx.y * 16 + threadIdx.x;
  float acc[4][4] = {};
  for (int k0 = 0; k0 < D_; k0 += 16){
#pragma unroll
    for (int r = 0; r < 4; r++){
      int e = tid + r * 256;
      int m = e >> 4, kk = e & 15;
      As[kk][m] = A[(size_t)(bm + m) * D_ + k0 + kk];
    }
#pragma unroll
    for (int r = 0; r < 4; r++){
      int e = tid + r * 256;
      int kk = e >> 6, n = e & 63;
      Bs[kk][n] = B[(size_t)(k0 + kk) * 1536 + bn + n];
    }
    __syncthreads();
#pragma unroll
    for (int kk = 0; kk < 16; kk++){
      float a[4], b[4];
#pragma unroll
      for (int i = 0; i < 4; i++) a[i] = As[kk][threadIdx.y * 4 + i];
#pragma unroll
      for (int j = 0; j < 4; j++) b[j] = Bs[kk][threadIdx.x * 4 + j];
#pragma unroll
      for (int i = 0; i < 4; i++)
#pragma unroll
        for (int j = 0; j < 4; j++) acc[i][j] += a[i] * b[j];
    }
    __syncthreads();
  }
#pragma unroll
  for (int i = 0; i < 4; i++){
    int row = bm + threadIdx.y * 4 + i;
#pragma unroll
    for (int j = 0; j < 4; j++){
      int col = bn + threadIdx.x * 4 + j;
      int which = col >> 9;
      int hh = (col >> 6) & 7;
      int d = col & 63;
      float val = acc[i][j];
      float* dst;
      if (which == 0){ dst = q; val *= 0.125f; }
      else if (which == 1) dst = k;
      else dst = v;
      dst[((size_t)hh * NP_ + row) * HD_ + d] = val;
    }
  }
}

// ---------------- landmarks: mean over 82-token chunks ----------------
// grid (256, 8), block 64
__global__ __launch_bounds__(64) void landmark_kernel(
    const float* __restrict__ q, const float* __restrict__ k,
    float* __restrict__ ql, float* __restrict__ kl){
  const int im = blockIdx.x, h = blockIdx.y, d = threadIdx.x;
  size_t base = ((size_t)h * NP_ + (size_t)im * LCH) * HD_ + d;
  float sq = 0.f, sk = 0.f;
  for (int r = 0; r < LCH; r++){
    sq += q[base + (size_t)r * HD_];
    sk += k[base + (size_t)r * HD_];
  }
  ql[((size_t)h * MLM + im) * HD_ + d] = sq * (1.f / 82.f);
  kl[((size_t)h * MLM + im) * HD_ + d] = sk * (1.f / 82.f);
}

// ---------------- a2 = softmax(ql @ kl^T) ----------------
// grid (256, 8), block 256
__global__ __launch_bounds__(256) void a2_kernel(
    const float* __restrict__ ql, const float* __restrict__ kl,
    float* __restrict__ a2){
  const int im = blockIdx.x, h = blockIdx.y, t = threadIdx.x;
  __shared__ float qs[64];
  __shared__ float s4[4];
  if (t < 64) qs[t] = ql[((size_t)h * MLM + im) * HD_ + t];
  __syncthreads();
  const float* kr = kl + ((size_t)h * MLM + t) * HD_;
  float s = 0.f;
#pragma unroll 16
  for (int d = 0; d < 64; d++) s += qs[d] * kr[d];
  float mx = blockMax256(s, s4);
  float e = __expf(s - mx);
  float S = blockSum256(e, s4);
  a2[((size_t)h * MLM + im) * MLM + t] = e / S;
}

// ---------------- pinv scaling ----------------
__global__ void zero2_kernel(unsigned int* p){ if (threadIdx.x < 2) p[threadIdx.x] = 0u; }

// grid 8, block 256: per-head row/col sums, atomicMax of maxima (uint bits of positive floats)
__global__ __launch_bounds__(256) void pinv_scale_kernel(
    const float* __restrict__ a2, unsigned int* __restrict__ scal){
  const int h = blockIdx.x, j = threadIdx.x;
  const float* A = a2 + (size_t)h * MLM * MLM;
  float rs = 0.f, cs = 0.f;
  for (int t = 0; t < MLM; t++){
    rs += fabsf(A[(size_t)j * MLM + t]);
    cs += fabsf(A[(size_t)t * MLM + j]);
  }
  __shared__ float s4[4];
  float rmax = blockMax256(rs, s4);
  float cmax = blockMax256(cs, s4);
  if (j == 0){
    atomicMax(&scal[0], __float_as_uint(rmax));
    atomicMax(&scal[1], __float_as_uint(cmax));
  }
}

// grid (256, 8), block 256: z = a2^T / (rmax*cmax)
__global__ __launch_bounds__(256) void pinv_init_kernel(
    const float* __restrict__ a2, const unsigned int* __restrict__ scal,
    float* __restrict__ z){
  const int i = blockIdx.x, h = blockIdx.y, j = threadIdx.x;
  float inv = 1.f / (__uint_as_float(scal[0]) * __uint_as_float(scal[1]));
  z[((size_t)h * MLM + i) * MLM + j] = a2[((size_t)h * MLM + j) * MLM + i] * inv;
}

// ---------------- batched 256x256x256: C = c1 * (A @ (c0*I + sgn*B)) ----------------
// grid (4,4,8), block (16,16)
__global__ __launch_bounds__(256) void bmm256_kernel(
    const float* __restrict__ Ab, const float* __restrict__ Bb,
    float* __restrict__ Cb, float c0, float sgn, float c1){
  const int h = blockIdx.z;
  const float* A = Ab + (size_t)h * 65536;
  const float* B = Bb + (size_t)h * 65536;
  float* C = Cb + (size_t)h * 65536;
  __shared__ float As[16][65];
  __shared__ float Bs[16][65];
  const int bm = blockIdx.x * 64, bn = blockIdx.y * 64;
  const int tid = threadIdx.y * 16 + threadIdx.x;
  float acc[4][4] = {};
  for (int k0 = 0; k0 < 256; k0 += 16){
#pragma unroll
    for (int r = 0; r < 4; r++){
      int e = tid + r * 256;
      int m = e >> 4, kk = e & 15;
      As[kk][m] = A[(size_t)(bm + m) * 256 + k0 + kk];
    }
#pragma unroll
    for (int r = 0; r < 4; r++){
      int e = tid + r * 256;
      int kk = e >> 6, n = e & 63;
      int gk = k0 + kk, gn = bn + n;
      float bv = sgn * B[(size_t)gk * 256 + gn];
      if (gk == gn) bv += c0;
      Bs[kk][n] = bv;
    }
    __syncthreads();
#pragma unroll
    for (int kk = 0; kk < 16; kk++){
      float a[4], b[4];
#pragma unroll
      for (int i = 0; i < 4; i++) a[i] = As[kk][threadIdx.y * 4 + i];
#pragma unroll
      for (int j = 0; j < 4; j++) b[j] = Bs[kk][threadIdx.x * 4 + j];
#pragma unroll
      for (int i = 0; i < 4; i++)
#pragma unroll
        for (int j = 0; j < 4; j++) acc[i][j] += a[i] * b[j];
    }
    __syncthreads();
  }
#pragma unroll
  for (int i = 0; i < 4; i++){
    int row = bm + threadIdx.y * 4 + i;
#pragma unroll
    for (int j = 0; j < 4; j++){
      int col = bn + threadIdx.x * 4 + j;
      C[(size_t)row * 256 + col] = c1 * acc[i][j];
    }
  }
}

// ---------------- t1 = softmax_n(ql @ k^T) @ v  (online softmax) ----------------
// grid (256, 8), block 64 (one wave); lane = output dim d
__global__ __launch_bounds__(64) void a3v_kernel(
    const float* __restrict__ ql, const float* __restrict__ k,
    const float* __restrict__ v, float* __restrict__ t1){
  const int im = blockIdx.x, h = blockIdx.y, lane = threadIdx.x;
  __shared__ float qs[64];
  __shared__ float es[64];
  qs[lane] = ql[((size_t)h * MLM + im) * HD_ + lane];
  __syncthreads();
  const float* kh = k + (size_t)h * NP_ * HD_;
  const float* vh = v + (size_t)h * NP_ * HD_;
  float m = -3.0e38f, l = 0.f, acc = 0.f;
  for (int n0 = 0; n0 < NP_; n0 += 64){
    const float* kr = kh + (size_t)(n0 + lane) * HD_;
    float s = 0.f;
#pragma unroll 16
    for (int d = 0; d < 64; d++) s += qs[d] * kr[d];
    float cm = waveMaxF(s);
    float mn = fmaxf(m, cm);
    float scale = __expf(m - mn);
    es[lane] = __expf(s - mn);
    __syncthreads();
    acc *= scale; l *= scale;
    float lsum = 0.f;
#pragma unroll 8
    for (int j = 0; j < 64; j++){
      float ej = es[j];
      lsum += ej;
      acc += ej * vh[(size_t)(n0 + j) * HD_ + lane];
    }
    l += lsum;
    m = mn;
    __syncthreads();
  }
  t1[((size_t)h * MLM + im) * HD_ + lane] = acc / l;
}

// ---------------- t2 = z @ t1 ----------------
// grid (64, 8), block 256: 4 rows x 64 cols per block
__global__ __launch_bounds__(256) void zt1_kernel(
    const float* __restrict__ z, const float* __restrict__ t1,
    float* __restrict__ t2){
  const int h = blockIdx.y;
  const int t = threadIdx.x;
  const int d = t & 63, ri = t >> 6;
  const int im = blockIdx.x * 4 + ri;
  const float* zr = z + ((size_t)h * MLM + im) * MLM;
  const float* t1h = t1 + (size_t)h * MLM * HD_;
  float acc = 0.f;
#pragma unroll 8
  for (int kk = 0; kk < MLM; kk++) acc += zr[kk] * t1h[(size_t)kk * HD_ + d];
  t2[((size_t)h * MLM + im) * HD_ + d] = acc;
}

// ---------------- out = softmax(q @ kl^T) @ t2 + conv33(v) ----------------
// grid (20737, 8), block 256; writes out_m (20737 x 512)
__global__ __launch_bounds__(256) void out_kernel(
    const float* __restrict__ q, const float* __restrict__ kl,
    const float* __restrict__ t2, const float* __restrict__ v,
    const float* __restrict__ resw, float* __restrict__ outm){
  const int n = PADR + blockIdx.x;
  const int h = blockIdx.y;
  const int t = threadIdx.x;
  __shared__ float qs[64];
  __shared__ float p[256];
  __shared__ float ps[4][64];
  __shared__ float s4[4];
  if (t < 64) qs[t] = q[((size_t)h * NP_ + n) * HD_ + t];
  __syncthreads();
  const float* kr = kl + ((size_t)h * MLM + t) * HD_;
  float s = 0.f;
#pragma unroll 16
  for (int d = 0; d < 64; d++) s += qs[d] * kr[d];
  float mx = blockMax256(s, s4);
  float e = __expf(s - mx);
  p[t] = e;
  float S = blockSum256(e, s4);   // barrier also publishes p[]
  const int g = t >> 6, d = t & 63;
  const float* t2h = t2 + (size_t)h * MLM * HD_;
  float o = 0.f;
#pragma unroll 8
  for (int jm = g * 64; jm < g * 64 + 64; jm++) o += p[jm] * t2h[(size_t)jm * HD_ + d];
  ps[g][d] = o;
  __syncthreads();
  if (t < 64){
    float oo = (ps[0][t] + ps[1][t] + ps[2][t] + ps[3][t]) / S;
    // depthwise conv33 residual on v
    float r = 0.f;
    const float* vh = v + (size_t)h * NP_ * HD_;
    const float* wr = resw + h * 33;
#pragma unroll
    for (int kk = 0; kk < 33; kk++){
      int nn = n - 16 + kk;
      if (nn >= 0 && nn < NP_) r += vh[(size_t)nn * HD_ + t] * wr[kk];
    }
    outm[(size_t)(n - PADR) * D_ + h * HD_ + t] = oo + r;
  }
}

// ---------------- h += out_m @ out_w + out_b ----------------
// grid (325, 8), block (16,16); M=20737 guarded
__global__ __launch_bounds__(256) void proj_kernel(
    const float* __restrict__ A, const float* __restrict__ B,
    const float* __restrict__ bias, float* __restrict__ h){
  __shared__ float As[16][65];
  __shared__ float Bs[16][65];
  const int bm = blockIdx.x * 64, bn = blockIdx.y * 64;
  const int tid = threadIdx.y * 16 + threadIdx.x;
  float acc[4][4] = {};
  for (int k0 = 0; k0 < D_; k0 += 16){
#pragma unroll
    for (int r = 0; r < 4; r++){
      int e = tid + r * 256;
      int m = e >> 4, kk = e & 15;
      int row = bm + m;
      As[kk][m] = (row < NTOK) ? A[(size_t)row * D_ + k0 + kk] : 0.f;
    }
#pragma unroll
    for (int r = 0; r < 4; r++){
      int e = tid + r * 256;
      int kk = e >> 6, n = e & 63;
      Bs[kk][n] = B[(size_t)(k0 + kk) * D_ + bn + n];
    }
    __syncthreads();
#pragma unroll
    for (int kk = 0; kk < 16; kk++){
      float a[4], b[4];
#pragma unroll
      for (int i = 0; i < 4; i++) a[i] = As[kk][threadIdx.y * 4 + i];
#pragma unroll
      for (int j = 0; j < 4; j++) b[j] = Bs[kk][threadIdx.x * 4 + j];
#pragma unroll
      for (int i = 0; i < 4; i++)
#pragma unroll
        for (int j = 0; j < 4; j++) acc[i][j] += a[i] * b[j];
    }
    __syncthreads();
  }
#pragma unroll
  for (int i = 0; i < 4; i++){
    int row = bm + threadIdx.y * 4 + i;
    if (row >= NTOK) continue;
#pragma unroll
    for (int j = 0; j < 4; j++){
      int col = bn + threadIdx.x * 4 + j;
      h[(size_t)row * D_ + col] += acc[i][j] + bias[col];
    }
  }
}

// ---------------- PPEG: y = f + dw7 + dw5 + dw3 (depthwise, biases) ----------------
// grid (144,144), block 512 (thread = channel)
__global__ __launch_bounds__(512) void ppeg_kernel(
    const float* __restrict__ h,
    const float* __restrict__ w7, const float* __restrict__ b7,
    const float* __restrict__ w5, const float* __restrict__ b5,
    const float* __restrict__ w3, const float* __restrict__ b3,
    float* __restrict__ tmp){
  const int px = blockIdx.x, py = blockIdx.y, c = threadIdx.x;
  float acc = h[(size_t)(1 + py * HHW + px) * D_ + c] + b7[c] + b5[c] + b3[c];
#pragma unroll
  for (int i = 0; i < 7; i++){
    int y = py + i - 3;
    if (y < 0 || y >= HHW) continue;
#pragma unroll
    for (int j = 0; j < 7; j++){
      int x = px + j - 3;
      if (x < 0 || x >= HHW) continue;
      acc += h[(size_t)(1 + y * HHW + x) * D_ + c] * w7[(size_t)c * 49 + i * 7 + j];
    }
  }
#pragma unroll
  for (int i = 0; i < 5; i++){
    int y = py + i - 2;
    if (y < 0 || y >= HHW) continue;
#pragma unroll
    for (int j = 0; j < 5; j++){
      int x = px + j - 2;
      if (x < 0 || x >= HHW) continue;
      acc += h[(size_t)(1 + y * HHW + x) * D_ + c] * w5[(size_t)c * 25 + i * 5 + j];
    }
  }
#pragma unroll
  for (int i = 0; i < 3; i++){
    int y = py + i - 1;
    if (y < 0 || y >= HHW) continue;
#pragma unroll
    for (int j = 0; j < 3; j++){
      int x = px + j - 1;
      if (x < 0 || x >= HHW) continue;
      acc += h[(size_t)(1 + y * HHW + x) * D_ + c] * w3[(size_t)c * 9 + i * 3 + j];
    }
  }
  tmp[(size_t)(py * HHW + px) * D_ + c] = acc;
}

__global__ void ppeg_copy_kernel(const float* __restrict__ tmp, float* __restrict__ h){
  size_t idx = (size_t)blockIdx.x * 256 + threadIdx.x;
  if (idx < (size_t)NFEAT * D_) h[idx + D_] = tmp[idx];
}

// ---------------- final: LN(h[0]) -> fc3 -> logits/softmax/argmax ----------------
// 1 block, 512 threads
__global__ __launch_bounds__(512) void final_kernel(
    const float* __restrict__ h, const float* __restrict__ w,
    const float* __restrict__ b, const float* __restrict__ fc3w,
    const float* __restrict__ fc3b, float* __restrict__ out){
  __shared__ float vec[512];
  __shared__ float s8[8];
  __shared__ float lg[4];
  const int t = threadIdx.x;
  float x = h[t];
  float v = waveSumF(x);
  if ((t & 63) == 0) s8[t >> 6] = v;
  __syncthreads();
  float sum = 0.f;
#pragma unroll
  for (int i = 0; i < 8; i++) sum += s8[i];
  float mu = sum * (1.f / 512.f);
  __syncthreads();
  float d = x - mu;
  v = waveSumF(d * d);
  if ((t & 63) == 0) s8[t >> 6] = v;
  __syncthreads();
  float var = 0.f;
#pragma unroll
  for (int i = 0; i < 8; i++) var += s8[i];
  var *= (1.f / 512.f);
  float rs = rsqrtf(var + 1e-5f);
  vec[t] = d * rs * w[t] + b[t];
  __syncthreads();
  if (t < 4){
    float acc = fc3b[t];
    for (int kk = 0; kk < 512; kk++) acc += vec[kk] * fc3w[kk * 4 + t];
    lg[t] = acc;
  }
  __syncthreads();
  if (t == 0){
    float m = fmaxf(fmaxf(lg[0], lg[1]), fmaxf(lg[2], lg[3]));
    float e[4], se = 0.f;
#pragma unroll
    for (int i = 0; i < 4; i++){ e[i] = __expf(lg[i] - m); se += e[i]; }
    int am = 0; float bm = lg[0];
#pragma unroll
    for (int i = 1; i < 4; i++) if (lg[i] > bm){ bm = lg[i]; am = i; }
#pragma unroll
    for (int i = 0; i < 4; i++){ out[i] = lg[i]; out[4 + i] = e[i] / se; }
    out[8] = (float)am;
  }
}

// ---------------------------------------------------------------------------
extern "C" void kernel_launch(void* const* d_in, const int* in_sizes, int n_in,
                              void* d_out, int out_size, void* d_ws, size_t ws_size,
                              hipStream_t stream) {
  const float* x       = (const float*)d_in[0];
  const float* fc1_w   = (const float*)d_in[1];
  const float* fc1_b   = (const float*)d_in[2];
  const float* cls_tok = (const float*)d_in[3];
  const float* l1_nw   = (const float*)d_in[4];
  const float* l1_nb   = (const float*)d_in[5];
  const float* l1_qkvw = (const float*)d_in[6];
  const float* l1_outw = (const float*)d_in[7];
  const float* l1_outb = (const float*)d_in[8];
  const float* l1_resw = (const float*)d_in[9];
  const float* ppeg_w7 = (const float*)d_in[10];
  const float* ppeg_b7 = (const float*)d_in[11];
  const float* ppeg_w5 = (const float*)d_in[12];
  const float* ppeg_b5 = (const float*)d_in[13];
  const float* ppeg_w3 = (const float*)d_in[14];
  const float* ppeg_b3 = (const float*)d_in[15];
  const float* l2_nw   = (const float*)d_in[16];
  const float* l2_nb   = (const float*)d_in[17];
  const float* l2_qkvw = (const float*)d_in[18];
  const float* l2_outw = (const float*)d_in[19];
  const float* l2_outb = (const float*)d_in[20];
  const float* l2_resw = (const float*)d_in[21];
  const float* norm_w  = (const float*)d_in[22];
  const float* norm_b  = (const float*)d_in[23];
  const float* fc3_w   = (const float*)d_in[24];
  const float* fc3_b   = (const float*)d_in[25];

  // workspace layout (floats)
  float* W = (float*)d_ws;
  size_t o = 0;
  float* hbuf = W + o; o += (size_t)NTOK * D_;        // 10,617,344
  float* xp   = W + o; o += (size_t)NP_ * D_;         // 10,747,904 (also out_m, ppeg tmp)
  float* qb   = W + o; o += (size_t)NH_ * NP_ * HD_;  // 10,747,904
  float* kb   = W + o; o += (size_t)NH_ * NP_ * HD_;
  float* vb   = W + o; o += (size_t)NH_ * NP_ * HD_;
  float* qlb  = W + o; o += (size_t)NH_ * MLM * HD_;  // 131,072
  float* klb  = W + o; o += (size_t)NH_ * MLM * HD_;
  float* a2b  = W + o; o += (size_t)NH_ * MLM * MLM;  // 524,288
  float* z0   = W + o; o += (size_t)NH_ * MLM * MLM;
  float* z1   = W + o; o += (size_t)NH_ * MLM * MLM;
  float* ta   = W + o; o += (size_t)NH_ * MLM * MLM;
  float* tb   = W + o; o += (size_t)NH_ * MLM * MLM;
  float* tc   = W + o; o += (size_t)NH_ * MLM * MLM;
  float* t1b  = W + o; o += (size_t)NH_ * MLM * HD_;
  float* t2b  = W + o; o += (size_t)NH_ * MLM * HD_;
  unsigned int* scal = (unsigned int*)(W + o); o += 16;
  float* outm = xp;  // alias: xp free after qkv GEMM

  // 1. fc1 (pool fused) directly into h rows; cls row
  fc1_kernel<<<dim3(320, 8), dim3(16, 16), 0, stream>>>(x, fc1_w, fc1_b, hbuf);
  cls_kernel<<<2, 256, 0, stream>>>(cls_tok, hbuf);

  auto run_layer = [&](const float* nw, const float* nb, const float* qkvw,
                       const float* outw, const float* outb, const float* resw){
    ln_pad_kernel<<<NP_, 256, 0, stream>>>(hbuf, nw, nb, xp);
    qkv_kernel<<<dim3(328, 24), dim3(16, 16), 0, stream>>>(xp, qkvw, qb, kb, vb);
    landmark_kernel<<<dim3(256, 8), 64, 0, stream>>>(qb, kb, qlb, klb);
    a2_kernel<<<dim3(256, 8), 256, 0, stream>>>(qlb, klb, a2b);
    zero2_kernel<<<1, 64, 0, stream>>>(scal);
    pinv_scale_kernel<<<8, 256, 0, stream>>>(a2b, scal);
    pinv_init_kernel<<<dim3(256, 8), 256, 0, stream>>>(a2b, scal, z0);
    float* zc = z0; float* za = z1;
    for (int it = 0; it < 6; it++){
      // xz = a2 @ z
      bmm256_kernel<<<dim3(4, 4, 8), dim3(16, 16), 0, stream>>>(a2b, zc, ta, 0.f, 1.f, 1.f);
      // M1 = xz @ (7I - xz)
      bmm256_kernel<<<dim3(4, 4, 8), dim3(16, 16), 0, stream>>>(ta, ta, tb, 7.f, -1.f, 1.f);
      // M2 = xz @ (15I - M1)
      bmm256_kernel<<<dim3(4, 4, 8), dim3(16, 16), 0, stream>>>(ta, tb, tc, 15.f, -1.f, 1.f);
      // z_new = 0.25 * z @ (13I - M2)
      bmm256_kernel<<<dim3(4, 4, 8), dim3(16, 16), 0, stream>>>(zc, tc, za, 13.f, -1.f, 0.25f);
      float* tswap = zc; zc = za; za = tswap;
    }
    a3v_kernel<<<dim3(256, 8), 64, 0, stream>>>(qlb, kb, vb, t1b);
    zt1_kernel<<<dim3(64, 8), 256, 0, stream>>>(zc, t1b, t2b);
    out_kernel<<<dim3(NTOK, 8), 256, 0, stream>>>(qb, klb, t2b, vb, resw, outm);
    proj_kernel<<<dim3(325, 8), dim3(16, 16), 0, stream>>>(outm, outw, outb, hbuf);
  };

  // 3. layer 1
  run_layer(l1_nw, l1_nb, l1_qkvw, l1_outw, l1_outb, l1_resw);
  // 4. PPEG
  ppeg_kernel<<<dim3(HHW, HHW), 512, 0, stream>>>(hbuf, ppeg_w7, ppeg_b7,
                                                  ppeg_w5, ppeg_b5, ppeg_w3, ppeg_b3, xp);
  ppeg_copy_kernel<<<(NFEAT * D_ + 255) / 256, 256, 0, stream>>>(xp, hbuf);
  // 5. layer 2
  run_layer(l2_nw, l2_nb, l2_qkvw, l2_outw, l2_outb, l2_resw);
  // 6. final
  final_kernel<<<1, 512, 0, stream>>>(hbuf, norm_w, norm_b, fc3_w, fc3_b, (float*)d_out);
}

// Round 2
// 10181.855 us; speedup vs baseline: 1.2763x; 1.2763x over previous
//
#include <hip/hip_runtime.h>

// ---------------------------------------------------------------------------
// TransMIL forward on MI355X — round 1: PPEG rewrite.
//   r0: 12995 us, ppeg_kernel alone 2945 us (VALUBusy 1.7%, VGPR=8,
//       serialized loads + 64-way-split weight loads).
//   r1: collapse 7x7+5x5+3x3+identity into ONE combined 7x7 depthwise conv
//       (precomputed transposed weights), register-tiled 8 px/block.
// Everything else identical to round 0 (passed, absmax 0.0).
// ---------------------------------------------------------------------------

constexpr int D_    = 512;
constexpr int E_    = 1024;
constexpr int NTOK  = 20737;
constexpr int NP_   = 20992;   // padded seq len (255 zero rows at FRONT)
constexpr int NH_   = 8;
constexpr int HD_   = 64;
constexpr int MLM   = 256;     // landmarks
constexpr int LCH   = 82;      // tokens per landmark
constexpr int HHW   = 144;
constexpr int NFEAT = 20736;   // 144*144
constexpr int PADR  = 255;

// ---------------- reduction helpers ----------------
__device__ __forceinline__ float waveMaxF(float v){
#pragma unroll
  for (int o = 32; o > 0; o >>= 1) v = fmaxf(v, __shfl_xor(v, o));
  return v;
}
__device__ __forceinline__ float waveSumF(float v){
#pragma unroll
  for (int o = 32; o > 0; o >>= 1) v += __shfl_xor(v, o);
  return v;
}
// 256-thread block reductions (sbuf: >=4 floats of LDS)
__device__ __forceinline__ float blockMax256(float v, float* sbuf){
  v = waveMaxF(v);
  if ((threadIdx.x & 63) == 0) sbuf[threadIdx.x >> 6] = v;
  __syncthreads();
  float r = fmaxf(fmaxf(sbuf[0], sbuf[1]), fmaxf(sbuf[2], sbuf[3]));
  __syncthreads();
  return r;
}
__device__ __forceinline__ float blockSum256(float v, float* sbuf){
  v = waveSumF(v);
  if ((threadIdx.x & 63) == 0) sbuf[threadIdx.x >> 6] = v;
  __syncthreads();
  float r = sbuf[0] + sbuf[1] + sbuf[2] + sbuf[3];
  __syncthreads();
  return r;
}

// ---------------- 1. fc1: relu(maxpool2(x) @ w + b) -> h rows ----------------
// grid (320, 8), block (16,16)
__global__ __launch_bounds__(256) void fc1_kernel(
    const float* __restrict__ x, const float* __restrict__ w,
    const float* __restrict__ bias, float* __restrict__ h){
  __shared__ float As[16][65];
  __shared__ float Bs[16][65];
  const int bm = blockIdx.x * 64, bn = blockIdx.y * 64;
  const int tid = threadIdx.y * 16 + threadIdx.x;
  float acc[4][4] = {};
  for (int k0 = 0; k0 < E_; k0 += 16){
#pragma unroll
    for (int r = 0; r < 4; r++){
      int e = tid + r * 256;
      int m = e >> 4, kk = e & 15;
      size_t row = (size_t)(bm + m) * 2;
      float v0 = x[row * E_ + k0 + kk];
      float v1 = x[(row + 1) * E_ + k0 + kk];
      As[kk][m] = fmaxf(v0, v1);
    }
#pragma unroll
    for (int r = 0; r < 4; r++){
      int e = tid + r * 256;
      int kk = e >> 6, n = e & 63;
      Bs[kk][n] = w[(size_t)(k0 + kk) * D_ + bn + n];
    }
    __syncthreads();
#pragma unroll
    for (int kk = 0; kk < 16; kk++){
      float a[4], b[4];
#pragma unroll
      for (int i = 0; i < 4; i++) a[i] = As[kk][threadIdx.y * 4 + i];
#pragma unroll
      for (int j = 0; j < 4; j++) b[j] = Bs[kk][threadIdx.x * 4 + j];
#pragma unroll
      for (int i = 0; i < 4; i++)
#pragma unroll
        for (int j = 0; j < 4; j++) acc[i][j] += a[i] * b[j];
    }
    __syncthreads();
  }
#pragma unroll
  for (int i = 0; i < 4; i++){
    int row = bm + threadIdx.y * 4 + i;
#pragma unroll
    for (int j = 0; j < 4; j++){
      int col = bn + threadIdx.x * 4 + j;
      float v = fmaxf(acc[i][j] + bias[col], 0.f);
      h[(size_t)(1 + row) * D_ + col] = v;                 // h rows 1..20480
      if (row < 256) h[(size_t)(20481 + row) * D_ + col] = v;  // wrap rows
    }
  }
}

__global__ void cls_kernel(const float* __restrict__ cls, float* __restrict__ h){
  int c = blockIdx.x * 256 + threadIdx.x;
  if (c < D_) h[c] = cls[c];
}

// ---------------- layernorm -> zero-padded xp ----------------
// grid NP_, block 256 (2 elems/thread)
__global__ __launch_bounds__(256) void ln_pad_kernel(
    const float* __restrict__ h, const float* __restrict__ w,
    const float* __restrict__ b, float* __restrict__ xp){
  const int r = blockIdx.x;
  const int t = threadIdx.x;
  if (r < PADR){
    xp[(size_t)r * D_ + t] = 0.f;
    xp[(size_t)r * D_ + 256 + t] = 0.f;
    return;
  }
  __shared__ float s4[4];
  const float* x = h + (size_t)(r - PADR) * D_;
  float a0 = x[t], a1 = x[t + 256];
  float mu = blockSum256(a0 + a1, s4) * (1.f / 512.f);
  float d0 = a0 - mu, d1 = a1 - mu;
  float var = blockSum256(d0 * d0 + d1 * d1, s4) * (1.f / 512.f);
  float rs = rsqrtf(var + 1e-5f);
  xp[(size_t)r * D_ + t]       = d0 * rs * w[t] + b[t];
  xp[(size_t)r * D_ + 256 + t] = d1 * rs * w[t + 256] + b[t + 256];
}

// ---------------- qkv GEMM: xp(20992x512) @ qkv_w(512x1536) ----------------
// scatter epilogue to head-major q/k/v; q scaled by 1/8. grid (328,24), block(16,16)
__global__ __launch_bounds__(256) void qkv_kernel(
    const float* __restrict__ A, const float* __restrict__ B,
    float* __restrict__ q, float* __restrict__ k, float* __restrict__ v){
  __shared__ float As[16][65];
  __shared__ float Bs[16][65];
  const int bm = blockIdx.x * 64, bn = blockIdx.y * 64;
  const int tid = threadIdx.y * 16 + threadIdx.x;
  float acc[4][4] = {};
  for (int k0 = 0; k0 < D_; k0 += 16){
#pragma unroll
    for (int r = 0; r < 4; r++){
      int e = tid + r * 256;
      int m = e >> 4, kk = e & 15;
      As[kk][m] = A[(size_t)(bm + m) * D_ + k0 + kk];
    }
#pragma unroll
    for (int r = 0; r < 4; r++){
      int e = tid + r * 256;
      int kk = e >> 6, n = e & 63;
      Bs[kk][n] = B[(size_t)(k0 + kk) * 1536 + bn + n];
    }
    __syncthreads();
#pragma unroll
    for (int kk = 0; kk < 16; kk++){
      float a[4], b[4];
#pragma unroll
      for (int i = 0; i < 4; i++) a[i] = As[kk][threadIdx.y * 4 + i];
#pragma unroll
      for (int j = 0; j < 4; j++) b[j] = Bs[kk][threadIdx.x * 4 + j];
#pragma unroll
      for (int i = 0; i < 4; i++)
#pragma unroll
        for (int j = 0; j < 4; j++) acc[i][j] += a[i] * b[j];
    }
    __syncthreads();
  }
#pragma unroll
  for (int i = 0; i < 4; i++){
    int row = bm + threadIdx.y * 4 + i;
#pragma unroll
    for (int j = 0; j < 4; j++){
      int col = bn + threadIdx.x * 4 + j;
      int which = col >> 9;
      int hh = (col >> 6) & 7;
      int d = col & 63;
      float val = acc[i][j];
      float* dst;
      if (which == 0){ dst = q; val *= 0.125f; }
      else if (which == 1) dst = k;
      else dst = v;
      dst[((size_t)hh * NP_ + row) * HD_ + d] = val;
    }
  }
}

// ---------------- landmarks: mean over 82-token chunks ----------------
// grid (256, 8), block 64
__global__ __launch_bounds__(64) void landmark_kernel(
    const float* __restrict__ q, const float* __restrict__ k,
    float* __restrict__ ql, float* __restrict__ kl){
  const int im = blockIdx.x, h = blockIdx.y, d = threadIdx.x;
  size_t base = ((size_t)h * NP_ + (size_t)im * LCH) * HD_ + d;
  float sq = 0.f, sk = 0.f;
  for (int r = 0; r < LCH; r++){
    sq += q[base + (size_t)r * HD_];
    sk += k[base + (size_t)r * HD_];
  }
  ql[((size_t)h * MLM + im) * HD_ + d] = sq * (1.f / 82.f);
  kl[((size_t)h * MLM + im) * HD_ + d] = sk * (1.f / 82.f);
}

// ---------------- a2 = softmax(ql @ kl^T) ----------------
// grid (256, 8), block 256
__global__ __launch_bounds__(256) void a2_kernel(
    const float* __restrict__ ql, const float* __restrict__ kl,
    float* __restrict__ a2){
  const int im = blockIdx.x, h = blockIdx.y, t = threadIdx.x;
  __shared__ float qs[64];
  __shared__ float s4[4];
  if (t < 64) qs[t] = ql[((size_t)h * MLM + im) * HD_ + t];
  __syncthreads();
  const float* kr = kl + ((size_t)h * MLM + t) * HD_;
  float s = 0.f;
#pragma unroll 16
  for (int d = 0; d < 64; d++) s += qs[d] * kr[d];
  float mx = blockMax256(s, s4);
  float e = __expf(s - mx);
  float S = blockSum256(e, s4);
  a2[((size_t)h * MLM + im) * MLM + t] = e / S;
}

// ---------------- pinv scaling ----------------
__global__ void zero2_kernel(unsigned int* p){ if (threadIdx.x < 2) p[threadIdx.x] = 0u; }

// grid 8, block 256: per-head row/col sums, atomicMax of maxima (uint bits of positive floats)
__global__ __launch_bounds__(256) void pinv_scale_kernel(
    const float* __restrict__ a2, unsigned int* __restrict__ scal){
  const int h = blockIdx.x, j = threadIdx.x;
  const float* A = a2 + (size_t)h * MLM * MLM;
  float rs = 0.f, cs = 0.f;
  for (int t = 0; t < MLM; t++){
    rs += fabsf(A[(size_t)j * MLM + t]);
    cs += fabsf(A[(size_t)t * MLM + j]);
  }
  __shared__ float s4[4];
  float rmax = blockMax256(rs, s4);
  float cmax = blockMax256(cs, s4);
  if (j == 0){
    atomicMax(&scal[0], __float_as_uint(rmax));
    atomicMax(&scal[1], __float_as_uint(cmax));
  }
}

// grid (256, 8), block 256: z = a2^T / (rmax*cmax)
__global__ __launch_bounds__(256) void pinv_init_kernel(
    const float* __restrict__ a2, const unsigned int* __restrict__ scal,
    float* __restrict__ z){
  const int i = blockIdx.x, h = blockIdx.y, j = threadIdx.x;
  float inv = 1.f / (__uint_as_float(scal[0]) * __uint_as_float(scal[1]));
  z[((size_t)h * MLM + i) * MLM + j] = a2[((size_t)h * MLM + j) * MLM + i] * inv;
}

// ---------------- batched 256x256x256: C = c1 * (A @ (c0*I + sgn*B)) ----------------
// grid (4,4,8), block (16,16)
__global__ __launch_bounds__(256) void bmm256_kernel(
    const float* __restrict__ Ab, const float* __restrict__ Bb,
    float* __restrict__ Cb, float c0, float sgn, float c1){
  const int h = blockIdx.z;
  const float* A = Ab + (size_t)h * 65536;
  const float* B = Bb + (size_t)h * 65536;
  float* C = Cb + (size_t)h * 65536;
  __shared__ float As[16][65];
  __shared__ float Bs[16][65];
  const int bm = blockIdx.x * 64, bn = blockIdx.y * 64;
  const int tid = threadIdx.y * 16 + threadIdx.x;
  float acc[4][4] = {};
  for (int k0 = 0; k0 < 256; k0 += 16){
#pragma unroll
    for (int r = 0; r < 4; r++){
      int e = tid + r * 256;
      int m = e >> 4, kk = e & 15;
      As[kk][m] = A[(size_t)(bm + m) * 256 + k0 + kk];
    }
#pragma unroll
    for (int r = 0; r < 4; r++){
      int e = tid + r * 256;
      int kk = e >> 6, n = e & 63;
      int gk = k0 + kk, gn = bn + n;
      float bv = sgn * B[(size_t)gk * 256 + gn];
      if (gk == gn) bv += c0;
      Bs[kk][n] = bv;
    }
    __syncthreads();
#pragma unroll
    for (int kk = 0; kk < 16; kk++){
      float a[4], b[4];
#pragma unroll
      for (int i = 0; i < 4; i++) a[i] = As[kk][threadIdx.y * 4 + i];
#pragma unroll
      for (int j = 0; j < 4; j++) b[j] = Bs[kk][threadIdx.x * 4 + j];
#pragma unroll
      for (int i = 0; i < 4; i++)
#pragma unroll
        for (int j = 0; j < 4; j++) acc[i][j] += a[i] * b[j];
    }
    __syncthreads();
  }
#pragma unroll
  for (int i = 0; i < 4; i++){
    int row = bm + threadIdx.y * 4 + i;
#pragma unroll
    for (int j = 0; j < 4; j++){
      int col = bn + threadIdx.x * 4 + j;
      C[(size_t)row * 256 + col] = c1 * acc[i][j];
    }
  }
}

// ---------------- t1 = softmax_n(ql @ k^T) @ v  (online softmax) ----------------
// grid (256, 8), block 64 (one wave); lane = output dim d
__global__ __launch_bounds__(64) void a3v_kernel(
    const float* __restrict__ ql, const float* __restrict__ k,
    const float* __restrict__ v, float* __restrict__ t1){
  const int im = blockIdx.x, h = blockIdx.y, lane = threadIdx.x;
  __shared__ float qs[64];
  __shared__ float es[64];
  qs[lane] = ql[((size_t)h * MLM + im) * HD_ + lane];
  __syncthreads();
  const float* kh = k + (size_t)h * NP_ * HD_;
  const float* vh = v + (size_t)h * NP_ * HD_;
  float m = -3.0e38f, l = 0.f, acc = 0.f;
  for (int n0 = 0; n0 < NP_; n0 += 64){
    const float* kr = kh + (size_t)(n0 + lane) * HD_;
    float s = 0.f;
#pragma unroll 16
    for (int d = 0; d < 64; d++) s += qs[d] * kr[d];
    float cm = waveMaxF(s);
    float mn = fmaxf(m, cm);
    float scale = __expf(m - mn);
    es[lane] = __expf(s - mn);
    __syncthreads();
    acc *= scale; l *= scale;
    float lsum = 0.f;
#pragma unroll 8
    for (int j = 0; j < 64; j++){
      float ej = es[j];
      lsum += ej;
      acc += ej * vh[(size_t)(n0 + j) * HD_ + lane];
    }
    l += lsum;
    m = mn;
    __syncthreads();
  }
  t1[((size_t)h * MLM + im) * HD_ + lane] = acc / l;
}

// ---------------- t2 = z @ t1 ----------------
// grid (64, 8), block 256: 4 rows x 64 cols per block
__global__ __launch_bounds__(256) void zt1_kernel(
    const float* __restrict__ z, const float* __restrict__ t1,
    float* __restrict__ t2){
  const int h = blockIdx.y;
  const int t = threadIdx.x;
  const int d = t & 63, ri = t >> 6;
  const int im = blockIdx.x * 4 + ri;
  const float* zr = z + ((size_t)h * MLM + im) * MLM;
  const float* t1h = t1 + (size_t)h * MLM * HD_;
  float acc = 0.f;
#pragma unroll 8
  for (int kk = 0; kk < MLM; kk++) acc += zr[kk] * t1h[(size_t)kk * HD_ + d];
  t2[((size_t)h * MLM + im) * HD_ + d] = acc;
}

// ---------------- out = softmax(q @ kl^T) @ t2 + conv33(v) ----------------
// grid (20737, 8), block 256; writes out_m (20737 x 512)
__global__ __launch_bounds__(256) void out_kernel(
    const float* __restrict__ q, const float* __restrict__ kl,
    const float* __restrict__ t2, const float* __restrict__ v,
    const float* __restrict__ resw, float* __restrict__ outm){
  const int n = PADR + blockIdx.x;
  const int h = blockIdx.y;
  const int t = threadIdx.x;
  __shared__ float qs[64];
  __shared__ float p[256];
  __shared__ float ps[4][64];
  __shared__ float s4[4];
  if (t < 64) qs[t] = q[((size_t)h * NP_ + n) * HD_ + t];
  __syncthreads();
  const float* kr = kl + ((size_t)h * MLM + t) * HD_;
  float s = 0.f;
#pragma unroll 16
  for (int d = 0; d < 64; d++) s += qs[d] * kr[d];
  float mx = blockMax256(s, s4);
  float e = __expf(s - mx);
  p[t] = e;
  float S = blockSum256(e, s4);   // barrier also publishes p[]
  const int g = t >> 6, d = t & 63;
  const float* t2h = t2 + (size_t)h * MLM * HD_;
  float o = 0.f;
#pragma unroll 8
  for (int jm = g * 64; jm < g * 64 + 64; jm++) o += p[jm] * t2h[(size_t)jm * HD_ + d];
  ps[g][d] = o;
  __syncthreads();
  if (t < 64){
    float oo = (ps[0][t] + ps[1][t] + ps[2][t] + ps[3][t]) / S;
    // depthwise conv33 residual on v
    float r = 0.f;
    const float* vh = v + (size_t)h * NP_ * HD_;
    const float* wr = resw + h * 33;
#pragma unroll
    for (int kk = 0; kk < 33; kk++){
      int nn = n - 16 + kk;
      if (nn >= 0 && nn < NP_) r += vh[(size_t)nn * HD_ + t] * wr[kk];
    }
    outm[(size_t)(n - PADR) * D_ + h * HD_ + t] = oo + r;
  }
}

// ---------------- h += out_m @ out_w + out_b ----------------
// grid (325, 8), block (16,16); M=20737 guarded
__global__ __launch_bounds__(256) void proj_kernel(
    const float* __restrict__ A, const float* __restrict__ B,
    const float* __restrict__ bias, float* __restrict__ h){
  __shared__ float As[16][65];
  __shared__ float Bs[16][65];
  const int bm = blockIdx.x * 64, bn = blockIdx.y * 64;
  const int tid = threadIdx.y * 16 + threadIdx.x;
  float acc[4][4] = {};
  for (int k0 = 0; k0 < D_; k0 += 16){
#pragma unroll
    for (int r = 0; r < 4; r++){
      int e = tid + r * 256;
      int m = e >> 4, kk = e & 15;
      int row = bm + m;
      As[kk][m] = (row < NTOK) ? A[(size_t)row * D_ + k0 + kk] : 0.f;
    }
#pragma unroll
    for (int r = 0; r < 4; r++){
      int e = tid + r * 256;
      int kk = e >> 6, n = e & 63;
      Bs[kk][n] = B[(size_t)(k0 + kk) * D_ + bn + n];
    }
    __syncthreads();
#pragma unroll
    for (int kk = 0; kk < 16; kk++){
      float a[4], b[4];
#pragma unroll
      for (int i = 0; i < 4; i++) a[i] = As[kk][threadIdx.y * 4 + i];
#pragma unroll
      for (int j = 0; j < 4; j++) b[j] = Bs[kk][threadIdx.x * 4 + j];
#pragma unroll
      for (int i = 0; i < 4; i++)
#pragma unroll
        for (int j = 0; j < 4; j++) acc[i][j] += a[i] * b[j];
    }
    __syncthreads();
  }
#pragma unroll
  for (int i = 0; i < 4; i++){
    int row = bm + threadIdx.y * 4 + i;
    if (row >= NTOK) continue;
#pragma unroll
    for (int j = 0; j < 4; j++){
      int col = bn + threadIdx.x * 4 + j;
      h[(size_t)row * D_ + col] += acc[i][j] + bias[col];
    }
  }
}

// ---------------- PPEG (rewritten) ----------------
// Step 1: combine w7 + pad(w5) + pad(w3) + identity into wcomb[49][512] (transposed)
// and bcomb[512] = b7+b5+b3. One block, 512 threads, one-time tiny cost.
__global__ __launch_bounds__(512) void ppeg_combine_kernel(
    const float* __restrict__ w7, const float* __restrict__ b7,
    const float* __restrict__ w5, const float* __restrict__ b5,
    const float* __restrict__ w3, const float* __restrict__ b3,
    float* __restrict__ wcomb, float* __restrict__ bcomb){
  const int c = threadIdx.x;
#pragma unroll
  for (int i = 0; i < 7; i++){
#pragma unroll
    for (int j = 0; j < 7; j++){
      int di = i - 3, dj = j - 3;
      float wv = w7[(size_t)c * 49 + i * 7 + j];
      if (di >= -2 && di <= 2 && dj >= -2 && dj <= 2)
        wv += w5[(size_t)c * 25 + (di + 2) * 5 + (dj + 2)];
      if (di >= -1 && di <= 1 && dj >= -1 && dj <= 1)
        wv += w3[(size_t)c * 9 + (di + 1) * 3 + (dj + 1)];
      if (di == 0 && dj == 0) wv += 1.f;   // identity (y = f + convs)
      wcomb[(size_t)(i * 7 + j) * 512 + c] = wv;   // [tap][channel] — coalesced reads later
    }
  }
  bcomb[c] = b7[c] + b5[c] + b3[c];
}

// Step 2: single 7x7 depthwise conv. grid (18, 144), block 512 (thread=channel).
// Each block: 8 output pixels in row y. Weights in 49 registers (coalesced load),
// 14-wide register line buffer per input row, 392 FMA/thread. All loads coalesced.
__global__ __launch_bounds__(512) void ppeg_conv_kernel(
    const float* __restrict__ h, const float* __restrict__ wcomb,
    const float* __restrict__ bcomb, float* __restrict__ tmp){
  const int c = threadIdx.x;
  const int y = blockIdx.y;
  const int x0 = blockIdx.x * 8;
  float wc[49];
#pragma unroll
  for (int kk = 0; kk < 49; kk++) wc[kk] = wcomb[(size_t)kk * 512 + c];
  float acc[8];
  const float bv = bcomb[c];
#pragma unroll
  for (int p = 0; p < 8; p++) acc[p] = bv;
#pragma unroll
  for (int i = 0; i < 7; i++){
    const int yy = y + i - 3;
    if (yy < 0 || yy >= HHW) continue;
    const float* hrow = h + (size_t)(1 + yy * HHW) * D_ + c;
    float line[14];
#pragma unroll
    for (int j = 0; j < 14; j++){
      const int xx = x0 + j - 3;
      line[j] = (xx >= 0 && xx < HHW) ? hrow[(size_t)xx * D_] : 0.f;
    }
#pragma unroll
    for (int p = 0; p < 8; p++)
#pragma unroll
      for (int j = 0; j < 7; j++)
        acc[p] += line[p + j] * wc[i * 7 + j];
  }
#pragma unroll
  for (int p = 0; p < 8; p++)
    tmp[(size_t)(y * HHW + x0 + p) * D_ + c] = acc[p];
}

__global__ void ppeg_copy_kernel(const float* __restrict__ tmp, float* __restrict__ h){
  size_t idx = (size_t)blockIdx.x * 256 + threadIdx.x;
  if (idx < (size_t)NFEAT * D_) h[idx + D_] = tmp[idx];
}

// ---------------- final: LN(h[0]) -> fc3 -> logits/softmax/argmax ----------------
// 1 block, 512 threads
__global__ __launch_bounds__(512) void final_kernel(
    const float* __restrict__ h, const float* __restrict__ w,
    const float* __restrict__ b, const float* __restrict__ fc3w,
    const float* __restrict__ fc3b, float* __restrict__ out){
  __shared__ float vec[512];
  __shared__ float s8[8];
  __shared__ float lg[4];
  const int t = threadIdx.x;
  float x = h[t];
  float v = waveSumF(x);
  if ((t & 63) == 0) s8[t >> 6] = v;
  __syncthreads();
  float sum = 0.f;
#pragma unroll
  for (int i = 0; i < 8; i++) sum += s8[i];
  float mu = sum * (1.f / 512.f);
  __syncthreads();
  float d = x - mu;
  v = waveSumF(d * d);
  if ((t & 63) == 0) s8[t >> 6] = v;
  __syncthreads();
  float var = 0.f;
#pragma unroll
  for (int i = 0; i < 8; i++) var += s8[i];
  var *= (1.f / 512.f);
  float rs = rsqrtf(var + 1e-5f);
  vec[t] = d * rs * w[t] + b[t];
  __syncthreads();
  if (t < 4){
    float acc = fc3b[t];
    for (int kk = 0; kk < 512; kk++) acc += vec[kk] * fc3w[kk * 4 + t];
    lg[t] = acc;
  }
  __syncthreads();
  if (t == 0){
    float m = fmaxf(fmaxf(lg[0], lg[1]), fmaxf(lg[2], lg[3]));
    float e[4], se = 0.f;
#pragma unroll
    for (int i = 0; i < 4; i++){ e[i] = __expf(lg[i] - m); se += e[i]; }
    int am = 0; float bm = lg[0];
#pragma unroll
    for (int i = 1; i < 4; i++) if (lg[i] > bm){ bm = lg[i]; am = i; }
#pragma unroll
    for (int i = 0; i < 4; i++){ out[i] = lg[i]; out[4 + i] = e[i] / se; }
    out[8] = (float)am;
  }
}

// ---------------------------------------------------------------------------
extern "C" void kernel_launch(void* const* d_in, const int* in_sizes, int n_in,
                              void* d_out, int out_size, void* d_ws, size_t ws_size,
                              hipStream_t stream) {
  const float* x       = (const float*)d_in[0];
  const float* fc1_w   = (const float*)d_in[1];
  const float* fc1_b   = (const float*)d_in[2];
  const float* cls_tok = (const float*)d_in[3];
  const float* l1_nw   = (const float*)d_in[4];
  const float* l1_nb   = (const float*)d_in[5];
  const float* l1_qkvw = (const float*)d_in[6];
  const float* l1_outw = (const float*)d_in[7];
  const float* l1_outb = (const float*)d_in[8];
  const float* l1_resw = (const float*)d_in[9];
  const float* ppeg_w7 = (const float*)d_in[10];
  const float* ppeg_b7 = (const float*)d_in[11];
  const float* ppeg_w5 = (const float*)d_in[12];
  const float* ppeg_b5 = (const float*)d_in[13];
  const float* ppeg_w3 = (const float*)d_in[14];
  const float* ppeg_b3 = (const float*)d_in[15];
  const float* l2_nw   = (const float*)d_in[16];
  const float* l2_nb   = (const float*)d_in[17];
  const float* l2_qkvw = (const float*)d_in[18];
  const float* l2_outw = (const float*)d_in[19];
  const float* l2_outb = (const float*)d_in[20];
  const float* l2_resw = (const float*)d_in[21];
  const float* norm_w  = (const float*)d_in[22];
  const float* norm_b  = (const float*)d_in[23];
  const float* fc3_w   = (const float*)d_in[24];
  const float* fc3_b   = (const float*)d_in[25];

  // workspace layout (floats)
  float* W = (float*)d_ws;
  size_t o = 0;
  float* hbuf = W + o; o += (size_t)NTOK * D_;        // 10,617,344
  float* xp   = W + o; o += (size_t)NP_ * D_;         // 10,747,904 (also out_m, ppeg tmp)
  float* qb   = W + o; o += (size_t)NH_ * NP_ * HD_;  // 10,747,904
  float* kb   = W + o; o += (size_t)NH_ * NP_ * HD_;
  float* vb   = W + o; o += (size_t)NH_ * NP_ * HD_;
  float* qlb  = W + o; o += (size_t)NH_ * MLM * HD_;  // 131,072
  float* klb  = W + o; o += (size_t)NH_ * MLM * HD_;
  float* a2b  = W + o; o += (size_t)NH_ * MLM * MLM;  // 524,288
  float* z0   = W + o; o += (size_t)NH_ * MLM * MLM;
  float* z1   = W + o; o += (size_t)NH_ * MLM * MLM;
  float* ta   = W + o; o += (size_t)NH_ * MLM * MLM;
  float* tb   = W + o; o += (size_t)NH_ * MLM * MLM;
  float* tc   = W + o; o += (size_t)NH_ * MLM * MLM;
  float* t1b  = W + o; o += (size_t)NH_ * MLM * HD_;
  float* t2b  = W + o; o += (size_t)NH_ * MLM * HD_;
  unsigned int* scal = (unsigned int*)(W + o); o += 16;
  float* wcomb = W + o; o += 49 * 512;
  float* bcomb = W + o; o += 512;
  float* outm = xp;  // alias: xp free after qkv GEMM

  // 1. fc1 (pool fused) directly into h rows; cls row
  fc1_kernel<<<dim3(320, 8), dim3(16, 16), 0, stream>>>(x, fc1_w, fc1_b, hbuf);
  cls_kernel<<<2, 256, 0, stream>>>(cls_tok, hbuf);
  // PPEG combined weights (tiny, once per launch; no dependence on h)
  ppeg_combine_kernel<<<1, 512, 0, stream>>>(ppeg_w7, ppeg_b7, ppeg_w5, ppeg_b5,
                                             ppeg_w3, ppeg_b3, wcomb, bcomb);

  auto run_layer = [&](const float* nw, const float* nb, const float* qkvw,
                       const float* outw, const float* outb, const float* resw){
    ln_pad_kernel<<<NP_, 256, 0, stream>>>(hbuf, nw, nb, xp);
    qkv_kernel<<<dim3(328, 24), dim3(16, 16), 0, stream>>>(xp, qkvw, qb, kb, vb);
    landmark_kernel<<<dim3(256, 8), 64, 0, stream>>>(qb, kb, qlb, klb);
    a2_kernel<<<dim3(256, 8), 256, 0, stream>>>(qlb, klb, a2b);
    zero2_kernel<<<1, 64, 0, stream>>>(scal);
    pinv_scale_kernel<<<8, 256, 0, stream>>>(a2b, scal);
    pinv_init_kernel<<<dim3(256, 8), 256, 0, stream>>>(a2b, scal, z0);
    float* zc = z0; float* za = z1;
    for (int it = 0; it < 6; it++){
      bmm256_kernel<<<dim3(4, 4, 8), dim3(16, 16), 0, stream>>>(a2b, zc, ta, 0.f, 1.f, 1.f);
      bmm256_kernel<<<dim3(4, 4, 8), dim3(16, 16), 0, stream>>>(ta, ta, tb, 7.f, -1.f, 1.f);
      bmm256_kernel<<<dim3(4, 4, 8), dim3(16, 16), 0, stream>>>(ta, tb, tc, 15.f, -1.f, 1.f);
      bmm256_kernel<<<dim3(4, 4, 8), dim3(16, 16), 0, stream>>>(zc, tc, za, 13.f, -1.f, 0.25f);
      float* tswap = zc; zc = za; za = tswap;
    }
    a3v_kernel<<<dim3(256, 8), 64, 0, stream>>>(qlb, kb, vb, t1b);
    zt1_kernel<<<dim3(64, 8), 256, 0, stream>>>(zc, t1b, t2b);
    out_kernel<<<dim3(NTOK, 8), 256, 0, stream>>>(qb, klb, t2b, vb, resw, outm);
    proj_kernel<<<dim3(325, 8), dim3(16, 16), 0, stream>>>(outm, outw, outb, hbuf);
  };

  // 3. layer 1
  run_layer(l1_nw, l1_nb, l1_qkvw, l1_outw, l1_outb, l1_resw);
  // 4. PPEG: single combined 7x7 depthwise conv
  ppeg_conv_kernel<<<dim3(HHW / 8, HHW), 512, 0, stream>>>(hbuf, wcomb, bcomb, xp);
  ppeg_copy_kernel<<<(NFEAT * D_ + 255) / 256, 256, 0, stream>>>(xp, hbuf);
  // 5. layer 2
  run_layer(l2_nw, l2_nb, l2_qkvw, l2_outw, l2_outb, l2_resw);
  // 6. final
  final_kernel<<<1, 512, 0, stream>>>(hbuf, norm_w, norm_b, fc3_w, fc3_b, (float*)d_out);
}

// Round 3
// 8278.242 us; speedup vs baseline: 1.5698x; 1.2300x over previous
//
#include <hip/hip_runtime.h>

// ---------------------------------------------------------------------------
// TransMIL forward on MI355X.
//   r0: 12995 us baseline (all-fp32, classic 64x64 tiled GEMMs).
//   r1: 10182 us — PPEG collapsed to one combined 7x7 depthwise conv.
//   r2: out_kernel rewritten as fused 32-token tile kernel (LDS-staged kl/t2/v,
//       register softmax); a3v k-row loads vectorized to float4.
// ---------------------------------------------------------------------------

constexpr int D_    = 512;
constexpr int E_    = 1024;
constexpr int NTOK  = 20737;
constexpr int NP_   = 20992;   // padded seq len (255 zero rows at FRONT)
constexpr int NH_   = 8;
constexpr int HD_   = 64;
constexpr int MLM   = 256;     // landmarks
constexpr int LCH   = 82;      // tokens per landmark
constexpr int HHW   = 144;
constexpr int NFEAT = 20736;   // 144*144
constexpr int PADR  = 255;

// ---------------- reduction helpers ----------------
__device__ __forceinline__ float waveMaxF(float v){
#pragma unroll
  for (int o = 32; o > 0; o >>= 1) v = fmaxf(v, __shfl_xor(v, o));
  return v;
}
__device__ __forceinline__ float waveSumF(float v){
#pragma unroll
  for (int o = 32; o > 0; o >>= 1) v += __shfl_xor(v, o);
  return v;
}
__device__ __forceinline__ float blockMax256(float v, float* sbuf){
  v = waveMaxF(v);
  if ((threadIdx.x & 63) == 0) sbuf[threadIdx.x >> 6] = v;
  __syncthreads();
  float r = fmaxf(fmaxf(sbuf[0], sbuf[1]), fmaxf(sbuf[2], sbuf[3]));
  __syncthreads();
  return r;
}
__device__ __forceinline__ float blockSum256(float v, float* sbuf){
  v = waveSumF(v);
  if ((threadIdx.x & 63) == 0) sbuf[threadIdx.x >> 6] = v;
  __syncthreads();
  float r = sbuf[0] + sbuf[1] + sbuf[2] + sbuf[3];
  __syncthreads();
  return r;
}

// ---------------- 1. fc1: relu(maxpool2(x) @ w + b) -> h rows ----------------
// grid (320, 8), block (16,16)
__global__ __launch_bounds__(256) void fc1_kernel(
    const float* __restrict__ x, const float* __restrict__ w,
    const float* __restrict__ bias, float* __restrict__ h){
  __shared__ float As[16][65];
  __shared__ float Bs[16][65];
  const int bm = blockIdx.x * 64, bn = blockIdx.y * 64;
  const int tid = threadIdx.y * 16 + threadIdx.x;
  float acc[4][4] = {};
  for (int k0 = 0; k0 < E_; k0 += 16){
#pragma unroll
    for (int r = 0; r < 4; r++){
      int e = tid + r * 256;
      int m = e >> 4, kk = e & 15;
      size_t row = (size_t)(bm + m) * 2;
      float v0 = x[row * E_ + k0 + kk];
      float v1 = x[(row + 1) * E_ + k0 + kk];
      As[kk][m] = fmaxf(v0, v1);
    }
#pragma unroll
    for (int r = 0; r < 4; r++){
      int e = tid + r * 256;
      int kk = e >> 6, n = e & 63;
      Bs[kk][n] = w[(size_t)(k0 + kk) * D_ + bn + n];
    }
    __syncthreads();
#pragma unroll
    for (int kk = 0; kk < 16; kk++){
      float a[4], b[4];
#pragma unroll
      for (int i = 0; i < 4; i++) a[i] = As[kk][threadIdx.y * 4 + i];
#pragma unroll
      for (int j = 0; j < 4; j++) b[j] = Bs[kk][threadIdx.x * 4 + j];
#pragma unroll
      for (int i = 0; i < 4; i++)
#pragma unroll
        for (int j = 0; j < 4; j++) acc[i][j] += a[i] * b[j];
    }
    __syncthreads();
  }
#pragma unroll
  for (int i = 0; i < 4; i++){
    int row = bm + threadIdx.y * 4 + i;
#pragma unroll
    for (int j = 0; j < 4; j++){
      int col = bn + threadIdx.x * 4 + j;
      float v = fmaxf(acc[i][j] + bias[col], 0.f);
      h[(size_t)(1 + row) * D_ + col] = v;                 // h rows 1..20480
      if (row < 256) h[(size_t)(20481 + row) * D_ + col] = v;  // wrap rows
    }
  }
}

__global__ void cls_kernel(const float* __restrict__ cls, float* __restrict__ h){
  int c = blockIdx.x * 256 + threadIdx.x;
  if (c < D_) h[c] = cls[c];
}

// ---------------- layernorm -> zero-padded xp ----------------
__global__ __launch_bounds__(256) void ln_pad_kernel(
    const float* __restrict__ h, const float* __restrict__ w,
    const float* __restrict__ b, float* __restrict__ xp){
  const int r = blockIdx.x;
  const int t = threadIdx.x;
  if (r < PADR){
    xp[(size_t)r * D_ + t] = 0.f;
    xp[(size_t)r * D_ + 256 + t] = 0.f;
    return;
  }
  __shared__ float s4[4];
  const float* x = h + (size_t)(r - PADR) * D_;
  float a0 = x[t], a1 = x[t + 256];
  float mu = blockSum256(a0 + a1, s4) * (1.f / 512.f);
  float d0 = a0 - mu, d1 = a1 - mu;
  float var = blockSum256(d0 * d0 + d1 * d1, s4) * (1.f / 512.f);
  float rs = rsqrtf(var + 1e-5f);
  xp[(size_t)r * D_ + t]       = d0 * rs * w[t] + b[t];
  xp[(size_t)r * D_ + 256 + t] = d1 * rs * w[t + 256] + b[t + 256];
}

// ---------------- qkv GEMM ----------------
__global__ __launch_bounds__(256) void qkv_kernel(
    const float* __restrict__ A, const float* __restrict__ B,
    float* __restrict__ q, float* __restrict__ k, float* __restrict__ v){
  __shared__ float As[16][65];
  __shared__ float Bs[16][65];
  const int bm = blockIdx.x * 64, bn = blockIdx.y * 64;
  const int tid = threadIdx.y * 16 + threadIdx.x;
  float acc[4][4] = {};
  for (int k0 = 0; k0 < D_; k0 += 16){
#pragma unroll
    for (int r = 0; r < 4; r++){
      int e = tid + r * 256;
      int m = e >> 4, kk = e & 15;
      As[kk][m] = A[(size_t)(bm + m) * D_ + k0 + kk];
    }
#pragma unroll
    for (int r = 0; r < 4; r++){
      int e = tid + r * 256;
      int kk = e >> 6, n = e & 63;
      Bs[kk][n] = B[(size_t)(k0 + kk) * 1536 + bn + n];
    }
    __syncthreads();
#pragma unroll
    for (int kk = 0; kk < 16; kk++){
      float a[4], b[4];
#pragma unroll
      for (int i = 0; i < 4; i++) a[i] = As[kk][threadIdx.y * 4 + i];
#pragma unroll
      for (int j = 0; j < 4; j++) b[j] = Bs[kk][threadIdx.x * 4 + j];
#pragma unroll
      for (int i = 0; i < 4; i++)
#pragma unroll
        for (int j = 0; j < 4; j++) acc[i][j] += a[i] * b[j];
    }
    __syncthreads();
  }
#pragma unroll
  for (int i = 0; i < 4; i++){
    int row = bm + threadIdx.y * 4 + i;
#pragma unroll
    for (int j = 0; j < 4; j++){
      int col = bn + threadIdx.x * 4 + j;
      int which = col >> 9;
      int hh = (col >> 6) & 7;
      int d = col & 63;
      float val = acc[i][j];
      float* dst;
      if (which == 0){ dst = q; val *= 0.125f; }
      else if (which == 1) dst = k;
      else dst = v;
      dst[((size_t)hh * NP_ + row) * HD_ + d] = val;
    }
  }
}

// ---------------- landmarks ----------------
__global__ __launch_bounds__(64) void landmark_kernel(
    const float* __restrict__ q, const float* __restrict__ k,
    float* __restrict__ ql, float* __restrict__ kl){
  const int im = blockIdx.x, h = blockIdx.y, d = threadIdx.x;
  size_t base = ((size_t)h * NP_ + (size_t)im * LCH) * HD_ + d;
  float sq = 0.f, sk = 0.f;
  for (int r = 0; r < LCH; r++){
    sq += q[base + (size_t)r * HD_];
    sk += k[base + (size_t)r * HD_];
  }
  ql[((size_t)h * MLM + im) * HD_ + d] = sq * (1.f / 82.f);
  kl[((size_t)h * MLM + im) * HD_ + d] = sk * (1.f / 82.f);
}

// ---------------- a2 = softmax(ql @ kl^T) ----------------
__global__ __launch_bounds__(256) void a2_kernel(
    const float* __restrict__ ql, const float* __restrict__ kl,
    float* __restrict__ a2){
  const int im = blockIdx.x, h = blockIdx.y, t = threadIdx.x;
  __shared__ __align__(16) float qs[64];
  __shared__ float s4[4];
  if (t < 64) qs[t] = ql[((size_t)h * MLM + im) * HD_ + t];
  __syncthreads();
  const float4* kr4 = (const float4*)(kl + ((size_t)h * MLM + t) * HD_);
  const float4* qs4 = (const float4*)qs;
  float s = 0.f;
#pragma unroll
  for (int d4 = 0; d4 < 16; d4++){
    float4 kv = kr4[d4], qv = qs4[d4];
    s += qv.x*kv.x + qv.y*kv.y + qv.z*kv.z + qv.w*kv.w;
  }
  float mx = blockMax256(s, s4);
  float e = __expf(s - mx);
  float S = blockSum256(e, s4);
  a2[((size_t)h * MLM + im) * MLM + t] = e / S;
}

// ---------------- pinv scaling ----------------
__global__ void zero2_kernel(unsigned int* p){ if (threadIdx.x < 2) p[threadIdx.x] = 0u; }

__global__ __launch_bounds__(256) void pinv_scale_kernel(
    const float* __restrict__ a2, unsigned int* __restrict__ scal){
  const int h = blockIdx.x, j = threadIdx.x;
  const float* A = a2 + (size_t)h * MLM * MLM;
  float rs = 0.f, cs = 0.f;
  for (int t = 0; t < MLM; t++){
    rs += fabsf(A[(size_t)j * MLM + t]);
    cs += fabsf(A[(size_t)t * MLM + j]);
  }
  __shared__ float s4[4];
  float rmax = blockMax256(rs, s4);
  float cmax = blockMax256(cs, s4);
  if (j == 0){
    atomicMax(&scal[0], __float_as_uint(rmax));
    atomicMax(&scal[1], __float_as_uint(cmax));
  }
}

__global__ __launch_bounds__(256) void pinv_init_kernel(
    const float* __restrict__ a2, const unsigned int* __restrict__ scal,
    float* __restrict__ z){
  const int i = blockIdx.x, h = blockIdx.y, j = threadIdx.x;
  float inv = 1.f / (__uint_as_float(scal[0]) * __uint_as_float(scal[1]));
  z[((size_t)h * MLM + i) * MLM + j] = a2[((size_t)h * MLM + j) * MLM + i] * inv;
}

// ---------------- batched 256x256x256: C = c1 * (A @ (c0*I + sgn*B)) ----------------
__global__ __launch_bounds__(256) void bmm256_kernel(
    const float* __restrict__ Ab, const float* __restrict__ Bb,
    float* __restrict__ Cb, float c0, float sgn, float c1){
  const int h = blockIdx.z;
  const float* A = Ab + (size_t)h * 65536;
  const float* B = Bb + (size_t)h * 65536;
  float* C = Cb + (size_t)h * 65536;
  __shared__ float As[16][65];
  __shared__ float Bs[16][65];
  const int bm = blockIdx.x * 64, bn = blockIdx.y * 64;
  const int tid = threadIdx.y * 16 + threadIdx.x;
  float acc[4][4] = {};
  for (int k0 = 0; k0 < 256; k0 += 16){
#pragma unroll
    for (int r = 0; r < 4; r++){
      int e = tid + r * 256;
      int m = e >> 4, kk = e & 15;
      As[kk][m] = A[(size_t)(bm + m) * 256 + k0 + kk];
    }
#pragma unroll
    for (int r = 0; r < 4; r++){
      int e = tid + r * 256;
      int kk = e >> 6, n = e & 63;
      int gk = k0 + kk, gn = bn + n;
      float bv = sgn * B[(size_t)gk * 256 + gn];
      if (gk == gn) bv += c0;
      Bs[kk][n] = bv;
    }
    __syncthreads();
#pragma unroll
    for (int kk = 0; kk < 16; kk++){
      float a[4], b[4];
#pragma unroll
      for (int i = 0; i < 4; i++) a[i] = As[kk][threadIdx.y * 4 + i];
#pragma unroll
      for (int j = 0; j < 4; j++) b[j] = Bs[kk][threadIdx.x * 4 + j];
#pragma unroll
      for (int i = 0; i < 4; i++)
#pragma unroll
        for (int j = 0; j < 4; j++) acc[i][j] += a[i] * b[j];
    }
    __syncthreads();
  }
#pragma unroll
  for (int i = 0; i < 4; i++){
    int row = bm + threadIdx.y * 4 + i;
#pragma unroll
    for (int j = 0; j < 4; j++){
      int col = bn + threadIdx.x * 4 + j;
      C[(size_t)row * 256 + col] = c1 * acc[i][j];
    }
  }
}

// ---------------- t1 = softmax_n(ql @ k^T) @ v  (online softmax) ----------------
// grid (256, 8), block 64; k-row loads vectorized (float4)
__global__ __launch_bounds__(64) void a3v_kernel(
    const float* __restrict__ ql, const float* __restrict__ k,
    const float* __restrict__ v, float* __restrict__ t1){
  const int im = blockIdx.x, h = blockIdx.y, lane = threadIdx.x;
  __shared__ __align__(16) float qs[64];
  __shared__ float es[64];
  qs[lane] = ql[((size_t)h * MLM + im) * HD_ + lane];
  __syncthreads();
  const float* kh = k + (size_t)h * NP_ * HD_;
  const float* vh = v + (size_t)h * NP_ * HD_;
  const float4* qs4 = (const float4*)qs;
  float m = -3.0e38f, l = 0.f, acc = 0.f;
  for (int n0 = 0; n0 < NP_; n0 += 64){
    const float4* kr4 = (const float4*)(kh + (size_t)(n0 + lane) * HD_);
    float sx = 0.f, sy = 0.f, sz = 0.f, sw = 0.f;
#pragma unroll
    for (int d4 = 0; d4 < 16; d4++){
      float4 kv = kr4[d4], qv = qs4[d4];
      sx += qv.x*kv.x; sy += qv.y*kv.y; sz += qv.z*kv.z; sw += qv.w*kv.w;
    }
    float s = (sx + sy) + (sz + sw);
    float cm = waveMaxF(s);
    float mn = fmaxf(m, cm);
    float scale = __expf(m - mn);
    es[lane] = __expf(s - mn);
    __syncthreads();
    acc *= scale; l *= scale;
    float lsum = 0.f;
#pragma unroll 8
    for (int j = 0; j < 64; j++){
      float ej = es[j];
      lsum += ej;
      acc += ej * vh[(size_t)(n0 + j) * HD_ + lane];
    }
    l += lsum;
    m = mn;
    __syncthreads();
  }
  t1[((size_t)h * MLM + im) * HD_ + lane] = acc / l;
}

// ---------------- t2 = z @ t1 ----------------
__global__ __launch_bounds__(256) void zt1_kernel(
    const float* __restrict__ z, const float* __restrict__ t1,
    float* __restrict__ t2){
  const int h = blockIdx.y;
  const int t = threadIdx.x;
  const int d = t & 63, ri = t >> 6;
  const int im = blockIdx.x * 4 + ri;
  const float* zr = z + ((size_t)h * MLM + im) * MLM;
  const float* t1h = t1 + (size_t)h * MLM * HD_;
  float acc = 0.f;
#pragma unroll 8
  for (int kk = 0; kk < MLM; kk++) acc += zr[kk] * t1h[(size_t)kk * HD_ + d];
  t2[((size_t)h * MLM + im) * HD_ + d] = acc;
}

// ---------------- out tile: 32 tokens x 1 head per block ----------------
// grid (649, 8), block 256. Phase1 S=q@kl^T (LDS kl chunks), reg softmax,
// Phase2 O=P@t2 (LDS t2 chunks), Phase3 +conv33(v) from LDS v tile.
__global__ __launch_bounds__(256) void out_tile_kernel(
    const float* __restrict__ q, const float* __restrict__ kl,
    const float* __restrict__ t2, const float* __restrict__ v,
    const float* __restrict__ resw, float* __restrict__ outm){
  __shared__ float qs[32][68];
  __shared__ float buf[64][68];     // kl chunk -> t2 chunk -> v tile
  __shared__ float Ps[32][260];
  const int h = blockIdx.y;
  const int tile = blockIdx.x;
  const int n0 = PADR + tile * 32;
  const int t = threadIdx.x;
  const int tx = t & 15, ty = t >> 4;

  // stage q tile (32 x 64), zero-guarded past NP_
  {
    const float* qh = q + (size_t)h * NP_ * HD_;
    for (int idx = t; idx < 512; idx += 256){
      int row = idx >> 4, q4 = idx & 15;
      int n = n0 + row;
      float4 val = make_float4(0.f, 0.f, 0.f, 0.f);
      if (n < NP_) val = *(const float4*)(qh + (size_t)n * HD_ + q4 * 4);
      *(float4*)(&qs[row][q4 * 4]) = val;
    }
  }

  // phase 1: S[2 rows][16 cols], col c = m*64 + jj*16 + tx
  float s[2][16];
#pragma unroll
  for (int i = 0; i < 2; i++)
#pragma unroll
    for (int u = 0; u < 16; u++) s[i][u] = 0.f;
  const float* klh = kl + (size_t)h * MLM * HD_;
  for (int m = 0; m < 4; m++){
    __syncthreads();
    for (int idx = t; idx < 1024; idx += 256){
      int row = idx >> 4, q4 = idx & 15;
      *(float4*)(&buf[row][q4 * 4]) =
          *(const float4*)(klh + (size_t)(m * 64 + row) * HD_ + q4 * 4);
    }
    __syncthreads();
#pragma unroll
    for (int k4 = 0; k4 < 16; k4++){
      float4 q0 = *(const float4*)(&qs[2 * ty + 0][k4 * 4]);
      float4 q1 = *(const float4*)(&qs[2 * ty + 1][k4 * 4]);
#pragma unroll
      for (int jj = 0; jj < 4; jj++){
        float4 kv = *(const float4*)(&buf[tx + 16 * jj][k4 * 4]);
        s[0][m * 4 + jj] += q0.x*kv.x + q0.y*kv.y + q0.z*kv.z + q0.w*kv.w;
        s[1][m * 4 + jj] += q1.x*kv.x + q1.y*kv.y + q1.z*kv.z + q1.w*kv.w;
      }
    }
  }

  // register softmax per row (cols distributed over 16 tx lanes)
#pragma unroll
  for (int i = 0; i < 2; i++){
    float mx = -3.0e38f;
#pragma unroll
    for (int u = 0; u < 16; u++) mx = fmaxf(mx, s[i][u]);
#pragma unroll
    for (int o = 1; o < 16; o <<= 1) mx = fmaxf(mx, __shfl_xor(mx, o));
    float sum = 0.f;
#pragma unroll
    for (int u = 0; u < 16; u++){ s[i][u] = __expf(s[i][u] - mx); sum += s[i][u]; }
#pragma unroll
    for (int o = 1; o < 16; o <<= 1) sum += __shfl_xor(sum, o);
    float inv = 1.f / sum;
#pragma unroll
    for (int u = 0; u < 16; u++) s[i][u] *= inv;
  }
#pragma unroll
  for (int i = 0; i < 2; i++)
#pragma unroll
    for (int mm = 0; mm < 4; mm++)
#pragma unroll
      for (int jj = 0; jj < 4; jj++)
        Ps[2 * ty + i][mm * 64 + jj * 16 + tx] = s[i][mm * 4 + jj];

  // phase 2: O[2][4] at cols d = tx*4..tx*4+3
  float o_[2][4] = {};
  const float* t2h = t2 + (size_t)h * MLM * HD_;
  for (int kc = 0; kc < 4; kc++){
    __syncthreads();   // kc=0: also guards Ps writes / buf(kl) reads
    for (int idx = t; idx < 1024; idx += 256){
      int row = idx >> 4, q4 = idx & 15;
      *(float4*)(&buf[row][q4 * 4]) =
          *(const float4*)(t2h + (size_t)(kc * 64 + row) * HD_ + q4 * 4);
    }
    __syncthreads();
#pragma unroll
    for (int k4 = 0; k4 < 16; k4++){
      float4 p0 = *(const float4*)(&Ps[2 * ty + 0][kc * 64 + k4 * 4]);
      float4 p1 = *(const float4*)(&Ps[2 * ty + 1][kc * 64 + k4 * 4]);
      float pa[4] = {p0.x, p0.y, p0.z, p0.w};
      float pb[4] = {p1.x, p1.y, p1.z, p1.w};
#pragma unroll
      for (int i = 0; i < 4; i++){
        float4 tv = *(const float4*)(&buf[k4 * 4 + i][tx * 4]);
        o_[0][0] += pa[i] * tv.x; o_[0][1] += pa[i] * tv.y;
        o_[0][2] += pa[i] * tv.z; o_[0][3] += pa[i] * tv.w;
        o_[1][0] += pb[i] * tv.x; o_[1][1] += pb[i] * tv.y;
        o_[1][2] += pb[i] * tv.z; o_[1][3] += pb[i] * tv.w;
      }
    }
  }

  // phase 3: conv33 residual from LDS v tile (rows n0-16 .. n0+47)
  __syncthreads();
  {
    const float* vh = v + (size_t)h * NP_ * HD_;
    for (int idx = t; idx < 1024; idx += 256){
      int row = idx >> 4, q4 = idx & 15;
      int nn = n0 - 16 + row;   // >= 239 always
      float4 val = make_float4(0.f, 0.f, 0.f, 0.f);
      if (nn < NP_) val = *(const float4*)(vh + (size_t)nn * HD_ + q4 * 4);
      *(float4*)(&buf[row][q4 * 4]) = val;
    }
  }
  __syncthreads();
  float wreg[33];
  {
    const float* wr = resw + h * 33;
#pragma unroll
    for (int kk = 0; kk < 33; kk++) wreg[kk] = wr[kk];
  }
#pragma unroll
  for (int i = 0; i < 2; i++){
    float4 cacc = make_float4(0.f, 0.f, 0.f, 0.f);
    for (int kk = 0; kk < 33; kk++){
      float4 vv = *(const float4*)(&buf[2 * ty + i + kk][tx * 4]);
      float w = wreg[kk];
      cacc.x += vv.x * w; cacc.y += vv.y * w;
      cacc.z += vv.z * w; cacc.w += vv.w * w;
    }
    int nrow = tile * 32 + 2 * ty + i;
    if (nrow < NTOK){
      float4 res = make_float4(o_[i][0] + cacc.x, o_[i][1] + cacc.y,
                               o_[i][2] + cacc.z, o_[i][3] + cacc.w);
      *(float4*)(outm + (size_t)nrow * D_ + h * HD_ + tx * 4) = res;
    }
  }
}

// ---------------- h += out_m @ out_w + out_b ----------------
__global__ __launch_bounds__(256) void proj_kernel(
    const float* __restrict__ A, const float* __restrict__ B,
    const float* __restrict__ bias, float* __restrict__ h){
  __shared__ float As[16][65];
  __shared__ float Bs[16][65];
  const int bm = blockIdx.x * 64, bn = blockIdx.y * 64;
  const int tid = threadIdx.y * 16 + threadIdx.x;
  float acc[4][4] = {};
  for (int k0 = 0; k0 < D_; k0 += 16){
#pragma unroll
    for (int r = 0; r < 4; r++){
      int e = tid + r * 256;
      int m = e >> 4, kk = e & 15;
      int row = bm + m;
      As[kk][m] = (row < NTOK) ? A[(size_t)row * D_ + k0 + kk] : 0.f;
    }
#pragma unroll
    for (int r = 0; r < 4; r++){
      int e = tid + r * 256;
      int kk = e >> 6, n = e & 63;
      Bs[kk][n] = B[(size_t)(k0 + kk) * D_ + bn + n];
    }
    __syncthreads();
#pragma unroll
    for (int kk = 0; kk < 16; kk++){
      float a[4], b[4];
#pragma unroll
      for (int i = 0; i < 4; i++) a[i] = As[kk][threadIdx.y * 4 + i];
#pragma unroll
      for (int j = 0; j < 4; j++) b[j] = Bs[kk][threadIdx.x * 4 + j];
#pragma unroll
      for (int i = 0; i < 4; i++)
#pragma unroll
        for (int j = 0; j < 4; j++) acc[i][j] += a[i] * b[j];
    }
    __syncthreads();
  }
#pragma unroll
  for (int i = 0; i < 4; i++){
    int row = bm + threadIdx.y * 4 + i;
    if (row >= NTOK) continue;
#pragma unroll
    for (int j = 0; j < 4; j++){
      int col = bn + threadIdx.x * 4 + j;
      h[(size_t)row * D_ + col] += acc[i][j] + bias[col];
    }
  }
}

// ---------------- PPEG ----------------
__global__ __launch_bounds__(512) void ppeg_combine_kernel(
    const float* __restrict__ w7, const float* __restrict__ b7,
    const float* __restrict__ w5, const float* __restrict__ b5,
    const float* __restrict__ w3, const float* __restrict__ b3,
    float* __restrict__ wcomb, float* __restrict__ bcomb){
  const int c = threadIdx.x;
#pragma unroll
  for (int i = 0; i < 7; i++){
#pragma unroll
    for (int j = 0; j < 7; j++){
      int di = i - 3, dj = j - 3;
      float wv = w7[(size_t)c * 49 + i * 7 + j];
      if (di >= -2 && di <= 2 && dj >= -2 && dj <= 2)
        wv += w5[(size_t)c * 25 + (di + 2) * 5 + (dj + 2)];
      if (di >= -1 && di <= 1 && dj >= -1 && dj <= 1)
        wv += w3[(size_t)c * 9 + (di + 1) * 3 + (dj + 1)];
      if (di == 0 && dj == 0) wv += 1.f;
      wcomb[(size_t)(i * 7 + j) * 512 + c] = wv;
    }
  }
  bcomb[c] = b7[c] + b5[c] + b3[c];
}

__global__ __launch_bounds__(512) void ppeg_conv_kernel(
    const float* __restrict__ h, const float* __restrict__ wcomb,
    const float* __restrict__ bcomb, float* __restrict__ tmp){
  const int c = threadIdx.x;
  const int y = blockIdx.y;
  const int x0 = blockIdx.x * 8;
  float wc[49];
#pragma unroll
  for (int kk = 0; kk < 49; kk++) wc[kk] = wcomb[(size_t)kk * 512 + c];
  float acc[8];
  const float bv = bcomb[c];
#pragma unroll
  for (int p = 0; p < 8; p++) acc[p] = bv;
#pragma unroll
  for (int i = 0; i < 7; i++){
    const int yy = y + i - 3;
    if (yy < 0 || yy >= HHW) continue;
    const float* hrow = h + (size_t)(1 + yy * HHW) * D_ + c;
    float line[14];
#pragma unroll
    for (int j = 0; j < 14; j++){
      const int xx = x0 + j - 3;
      line[j] = (xx >= 0 && xx < HHW) ? hrow[(size_t)xx * D_] : 0.f;
    }
#pragma unroll
    for (int p = 0; p < 8; p++)
#pragma unroll
      for (int j = 0; j < 7; j++)
        acc[p] += line[p + j] * wc[i * 7 + j];
  }
#pragma unroll
  for (int p = 0; p < 8; p++)
    tmp[(size_t)(y * HHW + x0 + p) * D_ + c] = acc[p];
}

__global__ void ppeg_copy_kernel(const float* __restrict__ tmp, float* __restrict__ h){
  size_t idx = (size_t)blockIdx.x * 256 + threadIdx.x;
  if (idx < (size_t)NFEAT * D_) h[idx + D_] = tmp[idx];
}

// ---------------- final ----------------
__global__ __launch_bounds__(512) void final_kernel(
    const float* __restrict__ h, const float* __restrict__ w,
    const float* __restrict__ b, const float* __restrict__ fc3w,
    const float* __restrict__ fc3b, float* __restrict__ out){
  __shared__ float vec[512];
  __shared__ float s8[8];
  __shared__ float lg[4];
  const int t = threadIdx.x;
  float x = h[t];
  float v = waveSumF(x);
  if ((t & 63) == 0) s8[t >> 6] = v;
  __syncthreads();
  float sum = 0.f;
#pragma unroll
  for (int i = 0; i < 8; i++) sum += s8[i];
  float mu = sum * (1.f / 512.f);
  __syncthreads();
  float d = x - mu;
  v = waveSumF(d * d);
  if ((t & 63) == 0) s8[t >> 6] = v;
  __syncthreads();
  float var = 0.f;
#pragma unroll
  for (int i = 0; i < 8; i++) var += s8[i];
  var *= (1.f / 512.f);
  float rs = rsqrtf(var + 1e-5f);
  vec[t] = d * rs * w[t] + b[t];
  __syncthreads();
  if (t < 4){
    float acc = fc3b[t];
    for (int kk = 0; kk < 512; kk++) acc += vec[kk] * fc3w[kk * 4 + t];
    lg[t] = acc;
  }
  __syncthreads();
  if (t == 0){
    float m = fmaxf(fmaxf(lg[0], lg[1]), fmaxf(lg[2], lg[3]));
    float e[4], se = 0.f;
#pragma unroll
    for (int i = 0; i < 4; i++){ e[i] = __expf(lg[i] - m); se += e[i]; }
    int am = 0; float bm = lg[0];
#pragma unroll
    for (int i = 1; i < 4; i++) if (lg[i] > bm){ bm = lg[i]; am = i; }
#pragma unroll
    for (int i = 0; i < 4; i++){ out[i] = lg[i]; out[4 + i] = e[i] / se; }
    out[8] = (float)am;
  }
}

// ---------------------------------------------------------------------------
extern "C" void kernel_launch(void* const* d_in, const int* in_sizes, int n_in,
                              void* d_out, int out_size, void* d_ws, size_t ws_size,
                              hipStream_t stream) {
  const float* x       = (const float*)d_in[0];
  const float* fc1_w   = (const float*)d_in[1];
  const float* fc1_b   = (const float*)d_in[2];
  const float* cls_tok = (const float*)d_in[3];
  const float* l1_nw   = (const float*)d_in[4];
  const float* l1_nb   = (const float*)d_in[5];
  const float* l1_qkvw = (const float*)d_in[6];
  const float* l1_outw = (const float*)d_in[7];
  const float* l1_outb = (const float*)d_in[8];
  const float* l1_resw = (const float*)d_in[9];
  const float* ppeg_w7 = (const float*)d_in[10];
  const float* ppeg_b7 = (const float*)d_in[11];
  const float* ppeg_w5 = (const float*)d_in[12];
  const float* ppeg_b5 = (const float*)d_in[13];
  const float* ppeg_w3 = (const float*)d_in[14];
  const float* ppeg_b3 = (const float*)d_in[15];
  const float* l2_nw   = (const float*)d_in[16];
  const float* l2_nb   = (const float*)d_in[17];
  const float* l2_qkvw = (const float*)d_in[18];
  const float* l2_outw = (const float*)d_in[19];
  const float* l2_outb = (const float*)d_in[20];
  const float* l2_resw = (const float*)d_in[21];
  const float* norm_w  = (const float*)d_in[22];
  const float* norm_b  = (const float*)d_in[23];
  const float* fc3_w   = (const float*)d_in[24];
  const float* fc3_b   = (const float*)d_in[25];

  // workspace layout (floats)
  float* W = (float*)d_ws;
  size_t o = 0;
  float* hbuf = W + o; o += (size_t)NTOK * D_;
  float* xp   = W + o; o += (size_t)NP_ * D_;         // also out_m, ppeg tmp
  float* qb   = W + o; o += (size_t)NH_ * NP_ * HD_;
  float* kb   = W + o; o += (size_t)NH_ * NP_ * HD_;
  float* vb   = W + o; o += (size_t)NH_ * NP_ * HD_;
  float* qlb  = W + o; o += (size_t)NH_ * MLM * HD_;
  float* klb  = W + o; o += (size_t)NH_ * MLM * HD_;
  float* a2b  = W + o; o += (size_t)NH_ * MLM * MLM;
  float* z0   = W + o; o += (size_t)NH_ * MLM * MLM;
  float* z1   = W + o; o += (size_t)NH_ * MLM * MLM;
  float* ta   = W + o; o += (size_t)NH_ * MLM * MLM;
  float* tb   = W + o; o += (size_t)NH_ * MLM * MLM;
  float* tc   = W + o; o += (size_t)NH_ * MLM * MLM;
  float* t1b  = W + o; o += (size_t)NH_ * MLM * HD_;
  float* t2b  = W + o; o += (size_t)NH_ * MLM * HD_;
  unsigned int* scal = (unsigned int*)(W + o); o += 16;
  float* wcomb = W + o; o += 49 * 512;
  float* bcomb = W + o; o += 512;
  float* outm = xp;

  fc1_kernel<<<dim3(320, 8), dim3(16, 16), 0, stream>>>(x, fc1_w, fc1_b, hbuf);
  cls_kernel<<<2, 256, 0, stream>>>(cls_tok, hbuf);
  ppeg_combine_kernel<<<1, 512, 0, stream>>>(ppeg_w7, ppeg_b7, ppeg_w5, ppeg_b5,
                                             ppeg_w3, ppeg_b3, wcomb, bcomb);

  auto run_layer = [&](const float* nw, const float* nb, const float* qkvw,
                       const float* outw, const float* outb, const float* resw){
    ln_pad_kernel<<<NP_, 256, 0, stream>>>(hbuf, nw, nb, xp);
    qkv_kernel<<<dim3(328, 24), dim3(16, 16), 0, stream>>>(xp, qkvw, qb, kb, vb);
    landmark_kernel<<<dim3(256, 8), 64, 0, stream>>>(qb, kb, qlb, klb);
    a2_kernel<<<dim3(256, 8), 256, 0, stream>>>(qlb, klb, a2b);
    zero2_kernel<<<1, 64, 0, stream>>>(scal);
    pinv_scale_kernel<<<8, 256, 0, stream>>>(a2b, scal);
    pinv_init_kernel<<<dim3(256, 8), 256, 0, stream>>>(a2b, scal, z0);
    float* zc = z0; float* za = z1;
    for (int it = 0; it < 6; it++){
      bmm256_kernel<<<dim3(4, 4, 8), dim3(16, 16), 0, stream>>>(a2b, zc, ta, 0.f, 1.f, 1.f);
      bmm256_kernel<<<dim3(4, 4, 8), dim3(16, 16), 0, stream>>>(ta, ta, tb, 7.f, -1.f, 1.f);
      bmm256_kernel<<<dim3(4, 4, 8), dim3(16, 16), 0, stream>>>(ta, tb, tc, 15.f, -1.f, 1.f);
      bmm256_kernel<<<dim3(4, 4, 8), dim3(16, 16), 0, stream>>>(zc, tc, za, 13.f, -1.f, 0.25f);
      float* tswap = zc; zc = za; za = tswap;
    }
    a3v_kernel<<<dim3(256, 8), 64, 0, stream>>>(qlb, kb, vb, t1b);
    zt1_kernel<<<dim3(64, 8), 256, 0, stream>>>(zc, t1b, t2b);
    out_tile_kernel<<<dim3(649, 8), 256, 0, stream>>>(qb, klb, t2b, vb, resw, outm);
    proj_kernel<<<dim3(325, 8), dim3(16, 16), 0, stream>>>(outm, outw, outb, hbuf);
  };

  run_layer(l1_nw, l1_nb, l1_qkvw, l1_outw, l1_outb, l1_resw);
  ppeg_conv_kernel<<<dim3(HHW / 8, HHW), 512, 0, stream>>>(hbuf, wcomb, bcomb, xp);
  ppeg_copy_kernel<<<(NFEAT * D_ + 255) / 256, 256, 0, stream>>>(xp, hbuf);
  run_layer(l2_nw, l2_nb, l2_qkvw, l2_outw, l2_outb, l2_resw);
  final_kernel<<<1, 512, 0, stream>>>(hbuf, norm_w, norm_b, fc3_w, fc3_b, (float*)d_out);
}

// Round 4
// 5545.789 us; speedup vs baseline: 2.3432x; 1.4927x over previous
//
#include <hip/hip_runtime.h>

// ---------------------------------------------------------------------------
// TransMIL forward on MI355X.
//   r0: 12995 us baseline (all-fp32, classic 64x64 tiled GEMMs).
//   r1: 10182 us — PPEG collapsed to one combined 7x7 depthwise conv.
//   r2:  8278 us — out_kernel rewritten as fused 32-token tile kernel.
//   r3: a3v rewritten as split-K flash attention (64-landmark x 512-token
//       chunk blocks, LDS-tiled, online softmax) + combine kernel.
//       Partials aliased into xp (dead between qkv and out_tile).
// ---------------------------------------------------------------------------

constexpr int D_    = 512;
constexpr int E_    = 1024;
constexpr int NTOK  = 20737;
constexpr int NP_   = 20992;   // padded seq len (255 zero rows at FRONT)
constexpr int NH_   = 8;
constexpr int HD_   = 64;
constexpr int MLM   = 256;     // landmarks
constexpr int LCH   = 82;      // tokens per landmark
constexpr int HHW   = 144;
constexpr int NFEAT = 20736;   // 144*144
constexpr int PADR  = 255;
constexpr int NCH   = 41;      // a3v N-chunks
constexpr int CHTOK = 512;     // tokens per chunk (8 subchunks of 64)

// ---------------- reduction helpers ----------------
__device__ __forceinline__ float waveMaxF(float v){
#pragma unroll
  for (int o = 32; o > 0; o >>= 1) v = fmaxf(v, __shfl_xor(v, o));
  return v;
}
__device__ __forceinline__ float waveSumF(float v){
#pragma unroll
  for (int o = 32; o > 0; o >>= 1) v += __shfl_xor(v, o);
  return v;
}
__device__ __forceinline__ float blockMax256(float v, float* sbuf){
  v = waveMaxF(v);
  if ((threadIdx.x & 63) == 0) sbuf[threadIdx.x >> 6] = v;
  __syncthreads();
  float r = fmaxf(fmaxf(sbuf[0], sbuf[1]), fmaxf(sbuf[2], sbuf[3]));
  __syncthreads();
  return r;
}
__device__ __forceinline__ float blockSum256(float v, float* sbuf){
  v = waveSumF(v);
  if ((threadIdx.x & 63) == 0) sbuf[threadIdx.x >> 6] = v;
  __syncthreads();
  float r = sbuf[0] + sbuf[1] + sbuf[2] + sbuf[3];
  __syncthreads();
  return r;
}

// ---------------- 1. fc1: relu(maxpool2(x) @ w + b) -> h rows ----------------
__global__ __launch_bounds__(256) void fc1_kernel(
    const float* __restrict__ x, const float* __restrict__ w,
    const float* __restrict__ bias, float* __restrict__ h){
  __shared__ float As[16][65];
  __shared__ float Bs[16][65];
  const int bm = blockIdx.x * 64, bn = blockIdx.y * 64;
  const int tid = threadIdx.y * 16 + threadIdx.x;
  float acc[4][4] = {};
  for (int k0 = 0; k0 < E_; k0 += 16){
#pragma unroll
    for (int r = 0; r < 4; r++){
      int e = tid + r * 256;
      int m = e >> 4, kk = e & 15;
      size_t row = (size_t)(bm + m) * 2;
      float v0 = x[row * E_ + k0 + kk];
      float v1 = x[(row + 1) * E_ + k0 + kk];
      As[kk][m] = fmaxf(v0, v1);
    }
#pragma unroll
    for (int r = 0; r < 4; r++){
      int e = tid + r * 256;
      int kk = e >> 6, n = e & 63;
      Bs[kk][n] = w[(size_t)(k0 + kk) * D_ + bn + n];
    }
    __syncthreads();
#pragma unroll
    for (int kk = 0; kk < 16; kk++){
      float a[4], b[4];
#pragma unroll
      for (int i = 0; i < 4; i++) a[i] = As[kk][threadIdx.y * 4 + i];
#pragma unroll
      for (int j = 0; j < 4; j++) b[j] = Bs[kk][threadIdx.x * 4 + j];
#pragma unroll
      for (int i = 0; i < 4; i++)
#pragma unroll
        for (int j = 0; j < 4; j++) acc[i][j] += a[i] * b[j];
    }
    __syncthreads();
  }
#pragma unroll
  for (int i = 0; i < 4; i++){
    int row = bm + threadIdx.y * 4 + i;
#pragma unroll
    for (int j = 0; j < 4; j++){
      int col = bn + threadIdx.x * 4 + j;
      float v = fmaxf(acc[i][j] + bias[col], 0.f);
      h[(size_t)(1 + row) * D_ + col] = v;
      if (row < 256) h[(size_t)(20481 + row) * D_ + col] = v;
    }
  }
}

__global__ void cls_kernel(const float* __restrict__ cls, float* __restrict__ h){
  int c = blockIdx.x * 256 + threadIdx.x;
  if (c < D_) h[c] = cls[c];
}

// ---------------- layernorm -> zero-padded xp ----------------
__global__ __launch_bounds__(256) void ln_pad_kernel(
    const float* __restrict__ h, const float* __restrict__ w,
    const float* __restrict__ b, float* __restrict__ xp){
  const int r = blockIdx.x;
  const int t = threadIdx.x;
  if (r < PADR){
    xp[(size_t)r * D_ + t] = 0.f;
    xp[(size_t)r * D_ + 256 + t] = 0.f;
    return;
  }
  __shared__ float s4[4];
  const float* x = h + (size_t)(r - PADR) * D_;
  float a0 = x[t], a1 = x[t + 256];
  float mu = blockSum256(a0 + a1, s4) * (1.f / 512.f);
  float d0 = a0 - mu, d1 = a1 - mu;
  float var = blockSum256(d0 * d0 + d1 * d1, s4) * (1.f / 512.f);
  float rs = rsqrtf(var + 1e-5f);
  xp[(size_t)r * D_ + t]       = d0 * rs * w[t] + b[t];
  xp[(size_t)r * D_ + 256 + t] = d1 * rs * w[t + 256] + b[t + 256];
}

// ---------------- qkv GEMM ----------------
__global__ __launch_bounds__(256) void qkv_kernel(
    const float* __restrict__ A, const float* __restrict__ B,
    float* __restrict__ q, float* __restrict__ k, float* __restrict__ v){
  __shared__ float As[16][65];
  __shared__ float Bs[16][65];
  const int bm = blockIdx.x * 64, bn = blockIdx.y * 64;
  const int tid = threadIdx.y * 16 + threadIdx.x;
  float acc[4][4] = {};
  for (int k0 = 0; k0 < D_; k0 += 16){
#pragma unroll
    for (int r = 0; r < 4; r++){
      int e = tid + r * 256;
      int m = e >> 4, kk = e & 15;
      As[kk][m] = A[(size_t)(bm + m) * D_ + k0 + kk];
    }
#pragma unroll
    for (int r = 0; r < 4; r++){
      int e = tid + r * 256;
      int kk = e >> 6, n = e & 63;
      Bs[kk][n] = B[(size_t)(k0 + kk) * 1536 + bn + n];
    }
    __syncthreads();
#pragma unroll
    for (int kk = 0; kk < 16; kk++){
      float a[4], b[4];
#pragma unroll
      for (int i = 0; i < 4; i++) a[i] = As[kk][threadIdx.y * 4 + i];
#pragma unroll
      for (int j = 0; j < 4; j++) b[j] = Bs[kk][threadIdx.x * 4 + j];
#pragma unroll
      for (int i = 0; i < 4; i++)
#pragma unroll
        for (int j = 0; j < 4; j++) acc[i][j] += a[i] * b[j];
    }
    __syncthreads();
  }
#pragma unroll
  for (int i = 0; i < 4; i++){
    int row = bm + threadIdx.y * 4 + i;
#pragma unroll
    for (int j = 0; j < 4; j++){
      int col = bn + threadIdx.x * 4 + j;
      int which = col >> 9;
      int hh = (col >> 6) & 7;
      int d = col & 63;
      float val = acc[i][j];
      float* dst;
      if (which == 0){ dst = q; val *= 0.125f; }
      else if (which == 1) dst = k;
      else dst = v;
      dst[((size_t)hh * NP_ + row) * HD_ + d] = val;
    }
  }
}

// ---------------- landmarks ----------------
__global__ __launch_bounds__(64) void landmark_kernel(
    const float* __restrict__ q, const float* __restrict__ k,
    float* __restrict__ ql, float* __restrict__ kl){
  const int im = blockIdx.x, h = blockIdx.y, d = threadIdx.x;
  size_t base = ((size_t)h * NP_ + (size_t)im * LCH) * HD_ + d;
  float sq = 0.f, sk = 0.f;
  for (int r = 0; r < LCH; r++){
    sq += q[base + (size_t)r * HD_];
    sk += k[base + (size_t)r * HD_];
  }
  ql[((size_t)h * MLM + im) * HD_ + d] = sq * (1.f / 82.f);
  kl[((size_t)h * MLM + im) * HD_ + d] = sk * (1.f / 82.f);
}

// ---------------- a2 = softmax(ql @ kl^T) ----------------
__global__ __launch_bounds__(256) void a2_kernel(
    const float* __restrict__ ql, const float* __restrict__ kl,
    float* __restrict__ a2){
  const int im = blockIdx.x, h = blockIdx.y, t = threadIdx.x;
  __shared__ __align__(16) float qs[64];
  __shared__ float s4[4];
  if (t < 64) qs[t] = ql[((size_t)h * MLM + im) * HD_ + t];
  __syncthreads();
  const float4* kr4 = (const float4*)(kl + ((size_t)h * MLM + t) * HD_);
  const float4* qs4 = (const float4*)qs;
  float s = 0.f;
#pragma unroll
  for (int d4 = 0; d4 < 16; d4++){
    float4 kv = kr4[d4], qv = qs4[d4];
    s += qv.x*kv.x + qv.y*kv.y + qv.z*kv.z + qv.w*kv.w;
  }
  float mx = blockMax256(s, s4);
  float e = __expf(s - mx);
  float S = blockSum256(e, s4);
  a2[((size_t)h * MLM + im) * MLM + t] = e / S;
}

// ---------------- pinv scaling ----------------
__global__ void zero2_kernel(unsigned int* p){ if (threadIdx.x < 2) p[threadIdx.x] = 0u; }

__global__ __launch_bounds__(256) void pinv_scale_kernel(
    const float* __restrict__ a2, unsigned int* __restrict__ scal){
  const int h = blockIdx.x, j = threadIdx.x;
  const float* A = a2 + (size_t)h * MLM * MLM;
  float rs = 0.f, cs = 0.f;
  for (int t = 0; t < MLM; t++){
    rs += fabsf(A[(size_t)j * MLM + t]);
    cs += fabsf(A[(size_t)t * MLM + j]);
  }
  __shared__ float s4[4];
  float rmax = blockMax256(rs, s4);
  float cmax = blockMax256(cs, s4);
  if (j == 0){
    atomicMax(&scal[0], __float_as_uint(rmax));
    atomicMax(&scal[1], __float_as_uint(cmax));
  }
}

__global__ __launch_bounds__(256) void pinv_init_kernel(
    const float* __restrict__ a2, const unsigned int* __restrict__ scal,
    float* __restrict__ z){
  const int i = blockIdx.x, h = blockIdx.y, j = threadIdx.x;
  float inv = 1.f / (__uint_as_float(scal[0]) * __uint_as_float(scal[1]));
  z[((size_t)h * MLM + i) * MLM + j] = a2[((size_t)h * MLM + j) * MLM + i] * inv;
}

// ---------------- batched 256x256x256: C = c1 * (A @ (c0*I + sgn*B)) ----------------
__global__ __launch_bounds__(256) void bmm256_kernel(
    const float* __restrict__ Ab, const float* __restrict__ Bb,
    float* __restrict__ Cb, float c0, float sgn, float c1){
  const int h = blockIdx.z;
  const float* A = Ab + (size_t)h * 65536;
  const float* B = Bb + (size_t)h * 65536;
  float* C = Cb + (size_t)h * 65536;
  __shared__ float As[16][65];
  __shared__ float Bs[16][65];
  const int bm = blockIdx.x * 64, bn = blockIdx.y * 64;
  const int tid = threadIdx.y * 16 + threadIdx.x;
  float acc[4][4] = {};
  for (int k0 = 0; k0 < 256; k0 += 16){
#pragma unroll
    for (int r = 0; r < 4; r++){
      int e = tid + r * 256;
      int m = e >> 4, kk = e & 15;
      As[kk][m] = A[(size_t)(bm + m) * 256 + k0 + kk];
    }
#pragma unroll
    for (int r = 0; r < 4; r++){
      int e = tid + r * 256;
      int kk = e >> 6, n = e & 63;
      int gk = k0 + kk, gn = bn + n;
      float bv = sgn * B[(size_t)gk * 256 + gn];
      if (gk == gn) bv += c0;
      Bs[kk][n] = bv;
    }
    __syncthreads();
#pragma unroll
    for (int kk = 0; kk < 16; kk++){
      float a[4], b[4];
#pragma unroll
      for (int i = 0; i < 4; i++) a[i] = As[kk][threadIdx.y * 4 + i];
#pragma unroll
      for (int j = 0; j < 4; j++) b[j] = Bs[kk][threadIdx.x * 4 + j];
#pragma unroll
      for (int i = 0; i < 4; i++)
#pragma unroll
        for (int j = 0; j < 4; j++) acc[i][j] += a[i] * b[j];
    }
    __syncthreads();
  }
#pragma unroll
  for (int i = 0; i < 4; i++){
    int row = bm + threadIdx.y * 4 + i;
#pragma unroll
    for (int j = 0; j < 4; j++){
      int col = bn + threadIdx.x * 4 + j;
      C[(size_t)row * 256 + col] = c1 * acc[i][j];
    }
  }
}

// ---------------- a3v split-K flash: partials per (lm-tile, head, chunk) ----
// grid (4, 8, 41), block 256 (4 waves). 64 landmarks x 512 tokens per block.
// Per 64-token subchunk: stage K,V in LDS; S in regs (4x4/thread); online
// softmax per row (16-lane shfl); P -> LDS (reuse K buf); PV accumulate.
__global__ __launch_bounds__(256) void a3v_part_kernel(
    const float* __restrict__ ql, const float* __restrict__ k,
    const float* __restrict__ v, float* __restrict__ pacc,
    float* __restrict__ pml){
  __shared__ float qs[64][68];
  __shared__ float kb[64][68];   // K subchunk, then P
  __shared__ float vb[64][68];
  const int lt = blockIdx.x, h = blockIdx.y, ch = blockIdx.z;
  const int t = threadIdx.x, tx = t & 15, ty = t >> 4;
  const float* qlh = ql + ((size_t)h * MLM + lt * 64) * HD_;
  for (int idx = t; idx < 1024; idx += 256){
    int row = idx >> 4, q4 = idx & 15;
    *(float4*)(&qs[row][q4 * 4]) = *(const float4*)(qlh + (size_t)row * HD_ + q4 * 4);
  }
  const float* kh = k + ((size_t)h * NP_ + ch * CHTOK) * HD_;
  const float* vh = v + ((size_t)h * NP_ + ch * CHTOK) * HD_;
  float o_[4][4] = {};
  float mrow[4], lrow[4];
#pragma unroll
  for (int i = 0; i < 4; i++){ mrow[i] = -3.0e38f; lrow[i] = 0.f; }
  for (int sc = 0; sc < 8; sc++){
    __syncthreads();
    for (int idx = t; idx < 1024; idx += 256){
      int row = idx >> 4, q4 = idx & 15;
      *(float4*)(&kb[row][q4 * 4]) = *(const float4*)(kh + (size_t)(sc * 64 + row) * HD_ + q4 * 4);
      *(float4*)(&vb[row][q4 * 4]) = *(const float4*)(vh + (size_t)(sc * 64 + row) * HD_ + q4 * 4);
    }
    __syncthreads();
    // S[4 rows][4 cols]; row = ty + 16*i, col = jj*16 + tx
    float s[4][4] = {};
#pragma unroll
    for (int k4 = 0; k4 < 16; k4++){
      float4 qv[4], kv[4];
#pragma unroll
      for (int i = 0; i < 4; i++) qv[i] = *(const float4*)(&qs[ty + 16 * i][k4 * 4]);
#pragma unroll
      for (int jj = 0; jj < 4; jj++) kv[jj] = *(const float4*)(&kb[jj * 16 + tx][k4 * 4]);
#pragma unroll
      for (int i = 0; i < 4; i++)
#pragma unroll
        for (int jj = 0; jj < 4; jj++)
          s[i][jj] += qv[i].x*kv[jj].x + qv[i].y*kv[jj].y + qv[i].z*kv[jj].z + qv[i].w*kv[jj].w;
    }
    __syncthreads();   // done reading kb; safe to overwrite with P
    // online softmax update per row; write P into kb
#pragma unroll
    for (int i = 0; i < 4; i++){
      float cm = fmaxf(fmaxf(s[i][0], s[i][1]), fmaxf(s[i][2], s[i][3]));
#pragma unroll
      for (int o = 1; o < 16; o <<= 1) cm = fmaxf(cm, __shfl_xor(cm, o));
      float mn = fmaxf(mrow[i], cm);
      float scale = __expf(mrow[i] - mn);
      float ls = 0.f;
#pragma unroll
      for (int jj = 0; jj < 4; jj++){ s[i][jj] = __expf(s[i][jj] - mn); ls += s[i][jj]; }
#pragma unroll
      for (int o = 1; o < 16; o <<= 1) ls += __shfl_xor(ls, o);
      lrow[i] = lrow[i] * scale + ls;
      mrow[i] = mn;
#pragma unroll
      for (int e = 0; e < 4; e++) o_[i][e] *= scale;
#pragma unroll
      for (int jj = 0; jj < 4; jj++) kb[ty + 16 * i][jj * 16 + tx] = s[i][jj];
    }
    __syncthreads();
    // PV: O[row][d], d = tx*4+e
#pragma unroll
    for (int c4 = 0; c4 < 16; c4++){
      float4 pv[4], vv[4];
#pragma unroll
      for (int i = 0; i < 4; i++) pv[i] = *(const float4*)(&kb[ty + 16 * i][c4 * 4]);
#pragma unroll
      for (int e = 0; e < 4; e++) vv[e] = *(const float4*)(&vb[c4 * 4 + e][tx * 4]);
#pragma unroll
      for (int i = 0; i < 4; i++){
        o_[i][0] += pv[i].x*vv[0].x + pv[i].y*vv[1].x + pv[i].z*vv[2].x + pv[i].w*vv[3].x;
        o_[i][1] += pv[i].x*vv[0].y + pv[i].y*vv[1].y + pv[i].z*vv[2].y + pv[i].w*vv[3].y;
        o_[i][2] += pv[i].x*vv[0].z + pv[i].y*vv[1].z + pv[i].z*vv[2].z + pv[i].w*vv[3].z;
        o_[i][3] += pv[i].x*vv[0].w + pv[i].y*vv[1].w + pv[i].z*vv[2].w + pv[i].w*vv[3].w;
      }
    }
  }
#pragma unroll
  for (int i = 0; i < 4; i++){
    int im = lt * 64 + ty + 16 * i;
    size_t base = ((size_t)h * NCH + ch) * MLM + im;
    float4 val = make_float4(o_[i][0], o_[i][1], o_[i][2], o_[i][3]);
    *(float4*)(pacc + base * HD_ + tx * 4) = val;
    if (tx == 0){
      pml[base * 2]     = mrow[i];
      pml[base * 2 + 1] = lrow[i];
    }
  }
}

// merge NCH chunk partials per (h, im): log-sum-exp combine. grid (256,8), block 64.
__global__ __launch_bounds__(64) void a3v_combine_kernel(
    const float* __restrict__ pacc, const float* __restrict__ pml,
    float* __restrict__ t1){
  const int im = blockIdx.x, h = blockIdx.y, lane = threadIdx.x;
  float M = -3.0e38f;
  for (int c = 0; c < NCH; c++)
    M = fmaxf(M, pml[(((size_t)h * NCH + c) * MLM + im) * 2]);
  float accv = 0.f, L = 0.f;
  for (int c = 0; c < NCH; c++){
    size_t base = ((size_t)h * NCH + c) * MLM + im;
    float mc = pml[base * 2], lc = pml[base * 2 + 1];
    float w = __expf(mc - M);
    accv += w * pacc[base * HD_ + lane];
    L += w * lc;
  }
  t1[((size_t)h * MLM + im) * HD_ + lane] = accv / L;
}

// ---------------- t2 = z @ t1 ----------------
__global__ __launch_bounds__(256) void zt1_kernel(
    const float* __restrict__ z, const float* __restrict__ t1,
    float* __restrict__ t2){
  const int h = blockIdx.y;
  const int t = threadIdx.x;
  const int d = t & 63, ri = t >> 6;
  const int im = blockIdx.x * 4 + ri;
  const float* zr = z + ((size_t)h * MLM + im) * MLM;
  const float* t1h = t1 + (size_t)h * MLM * HD_;
  float acc = 0.f;
#pragma unroll 8
  for (int kk = 0; kk < MLM; kk++) acc += zr[kk] * t1h[(size_t)kk * HD_ + d];
  t2[((size_t)h * MLM + im) * HD_ + d] = acc;
}

// ---------------- out tile: 32 tokens x 1 head per block ----------------
__global__ __launch_bounds__(256) void out_tile_kernel(
    const float* __restrict__ q, const float* __restrict__ kl,
    const float* __restrict__ t2, const float* __restrict__ v,
    const float* __restrict__ resw, float* __restrict__ outm){
  __shared__ float qs[32][68];
  __shared__ float buf[64][68];
  __shared__ float Ps[32][260];
  const int h = blockIdx.y;
  const int tile = blockIdx.x;
  const int n0 = PADR + tile * 32;
  const int t = threadIdx.x;
  const int tx = t & 15, ty = t >> 4;
  {
    const float* qh = q + (size_t)h * NP_ * HD_;
    for (int idx = t; idx < 512; idx += 256){
      int row = idx >> 4, q4 = idx & 15;
      int n = n0 + row;
      float4 val = make_float4(0.f, 0.f, 0.f, 0.f);
      if (n < NP_) val = *(const float4*)(qh + (size_t)n * HD_ + q4 * 4);
      *(float4*)(&qs[row][q4 * 4]) = val;
    }
  }
  float s[2][16];
#pragma unroll
  for (int i = 0; i < 2; i++)
#pragma unroll
    for (int u = 0; u < 16; u++) s[i][u] = 0.f;
  const float* klh = kl + (size_t)h * MLM * HD_;
  for (int m = 0; m < 4; m++){
    __syncthreads();
    for (int idx = t; idx < 1024; idx += 256){
      int row = idx >> 4, q4 = idx & 15;
      *(float4*)(&buf[row][q4 * 4]) =
          *(const float4*)(klh + (size_t)(m * 64 + row) * HD_ + q4 * 4);
    }
    __syncthreads();
#pragma unroll
    for (int k4 = 0; k4 < 16; k4++){
      float4 q0 = *(const float4*)(&qs[2 * ty + 0][k4 * 4]);
      float4 q1 = *(const float4*)(&qs[2 * ty + 1][k4 * 4]);
#pragma unroll
      for (int jj = 0; jj < 4; jj++){
        float4 kv = *(const float4*)(&buf[tx + 16 * jj][k4 * 4]);
        s[0][m * 4 + jj] += q0.x*kv.x + q0.y*kv.y + q0.z*kv.z + q0.w*kv.w;
        s[1][m * 4 + jj] += q1.x*kv.x + q1.y*kv.y + q1.z*kv.z + q1.w*kv.w;
      }
    }
  }
#pragma unroll
  for (int i = 0; i < 2; i++){
    float mx = -3.0e38f;
#pragma unroll
    for (int u = 0; u < 16; u++) mx = fmaxf(mx, s[i][u]);
#pragma unroll
    for (int o = 1; o < 16; o <<= 1) mx = fmaxf(mx, __shfl_xor(mx, o));
    float sum = 0.f;
#pragma unroll
    for (int u = 0; u < 16; u++){ s[i][u] = __expf(s[i][u] - mx); sum += s[i][u]; }
#pragma unroll
    for (int o = 1; o < 16; o <<= 1) sum += __shfl_xor(sum, o);
    float inv = 1.f / sum;
#pragma unroll
    for (int u = 0; u < 16; u++) s[i][u] *= inv;
  }
#pragma unroll
  for (int i = 0; i < 2; i++)
#pragma unroll
    for (int mm = 0; mm < 4; mm++)
#pragma unroll
      for (int jj = 0; jj < 4; jj++)
        Ps[2 * ty + i][mm * 64 + jj * 16 + tx] = s[i][mm * 4 + jj];

  float o_[2][4] = {};
  const float* t2h = t2 + (size_t)h * MLM * HD_;
  for (int kc = 0; kc < 4; kc++){
    __syncthreads();
    for (int idx = t; idx < 1024; idx += 256){
      int row = idx >> 4, q4 = idx & 15;
      *(float4*)(&buf[row][q4 * 4]) =
          *(const float4*)(t2h + (size_t)(kc * 64 + row) * HD_ + q4 * 4);
    }
    __syncthreads();
#pragma unroll
    for (int k4 = 0; k4 < 16; k4++){
      float4 p0 = *(const float4*)(&Ps[2 * ty + 0][kc * 64 + k4 * 4]);
      float4 p1 = *(const float4*)(&Ps[2 * ty + 1][kc * 64 + k4 * 4]);
      float pa[4] = {p0.x, p0.y, p0.z, p0.w};
      float pb[4] = {p1.x, p1.y, p1.z, p1.w};
#pragma unroll
      for (int i = 0; i < 4; i++){
        float4 tv = *(const float4*)(&buf[k4 * 4 + i][tx * 4]);
        o_[0][0] += pa[i] * tv.x; o_[0][1] += pa[i] * tv.y;
        o_[0][2] += pa[i] * tv.z; o_[0][3] += pa[i] * tv.w;
        o_[1][0] += pb[i] * tv.x; o_[1][1] += pb[i] * tv.y;
        o_[1][2] += pb[i] * tv.z; o_[1][3] += pb[i] * tv.w;
      }
    }
  }
  __syncthreads();
  {
    const float* vh = v + (size_t)h * NP_ * HD_;
    for (int idx = t; idx < 1024; idx += 256){
      int row = idx >> 4, q4 = idx & 15;
      int nn = n0 - 16 + row;
      float4 val = make_float4(0.f, 0.f, 0.f, 0.f);
      if (nn < NP_) val = *(const float4*)(vh + (size_t)nn * HD_ + q4 * 4);
      *(float4*)(&buf[row][q4 * 4]) = val;
    }
  }
  __syncthreads();
  float wreg[33];
  {
    const float* wr = resw + h * 33;
#pragma unroll
    for (int kk = 0; kk < 33; kk++) wreg[kk] = wr[kk];
  }
#pragma unroll
  for (int i = 0; i < 2; i++){
    float4 cacc = make_float4(0.f, 0.f, 0.f, 0.f);
    for (int kk = 0; kk < 33; kk++){
      float4 vv = *(const float4*)(&buf[2 * ty + i + kk][tx * 4]);
      float w = wreg[kk];
      cacc.x += vv.x * w; cacc.y += vv.y * w;
      cacc.z += vv.z * w; cacc.w += vv.w * w;
    }
    int nrow = tile * 32 + 2 * ty + i;
    if (nrow < NTOK){
      float4 res = make_float4(o_[i][0] + cacc.x, o_[i][1] + cacc.y,
                               o_[i][2] + cacc.z, o_[i][3] + cacc.w);
      *(float4*)(outm + (size_t)nrow * D_ + h * HD_ + tx * 4) = res;
    }
  }
}

// ---------------- h += out_m @ out_w + out_b ----------------
__global__ __launch_bounds__(256) void proj_kernel(
    const float* __restrict__ A, const float* __restrict__ B,
    const float* __restrict__ bias, float* __restrict__ h){
  __shared__ float As[16][65];
  __shared__ float Bs[16][65];
  const int bm = blockIdx.x * 64, bn = blockIdx.y * 64;
  const int tid = threadIdx.y * 16 + threadIdx.x;
  float acc[4][4] = {};
  for (int k0 = 0; k0 < D_; k0 += 16){
#pragma unroll
    for (int r = 0; r < 4; r++){
      int e = tid + r * 256;
      int m = e >> 4, kk = e & 15;
      int row = bm + m;
      As[kk][m] = (row < NTOK) ? A[(size_t)row * D_ + k0 + kk] : 0.f;
    }
#pragma unroll
    for (int r = 0; r < 4; r++){
      int e = tid + r * 256;
      int kk = e >> 6, n = e & 63;
      Bs[kk][n] = B[(size_t)(k0 + kk) * D_ + bn + n];
    }
    __syncthreads();
#pragma unroll
    for (int kk = 0; kk < 16; kk++){
      float a[4], b[4];
#pragma unroll
      for (int i = 0; i < 4; i++) a[i] = As[kk][threadIdx.y * 4 + i];
#pragma unroll
      for (int j = 0; j < 4; j++) b[j] = Bs[kk][threadIdx.x * 4 + j];
#pragma unroll
      for (int i = 0; i < 4; i++)
#pragma unroll
        for (int j = 0; j < 4; j++) acc[i][j] += a[i] * b[j];
    }
    __syncthreads();
  }
#pragma unroll
  for (int i = 0; i < 4; i++){
    int row = bm + threadIdx.y * 4 + i;
    if (row >= NTOK) continue;
#pragma unroll
    for (int j = 0; j < 4; j++){
      int col = bn + threadIdx.x * 4 + j;
      h[(size_t)row * D_ + col] += acc[i][j] + bias[col];
    }
  }
}

// ---------------- PPEG ----------------
__global__ __launch_bounds__(512) void ppeg_combine_kernel(
    const float* __restrict__ w7, const float* __restrict__ b7,
    const float* __restrict__ w5, const float* __restrict__ b5,
    const float* __restrict__ w3, const float* __restrict__ b3,
    float* __restrict__ wcomb, float* __restrict__ bcomb){
  const int c = threadIdx.x;
#pragma unroll
  for (int i = 0; i < 7; i++){
#pragma unroll
    for (int j = 0; j < 7; j++){
      int di = i - 3, dj = j - 3;
      float wv = w7[(size_t)c * 49 + i * 7 + j];
      if (di >= -2 && di <= 2 && dj >= -2 && dj <= 2)
        wv += w5[(size_t)c * 25 + (di + 2) * 5 + (dj + 2)];
      if (di >= -1 && di <= 1 && dj >= -1 && dj <= 1)
        wv += w3[(size_t)c * 9 + (di + 1) * 3 + (dj + 1)];
      if (di == 0 && dj == 0) wv += 1.f;
      wcomb[(size_t)(i * 7 + j) * 512 + c] = wv;
    }
  }
  bcomb[c] = b7[c] + b5[c] + b3[c];
}

__global__ __launch_bounds__(512) void ppeg_conv_kernel(
    const float* __restrict__ h, const float* __restrict__ wcomb,
    const float* __restrict__ bcomb, float* __restrict__ tmp){
  const int c = threadIdx.x;
  const int y = blockIdx.y;
  const int x0 = blockIdx.x * 8;
  float wc[49];
#pragma unroll
  for (int kk = 0; kk < 49; kk++) wc[kk] = wcomb[(size_t)kk * 512 + c];
  float acc[8];
  const float bv = bcomb[c];
#pragma unroll
  for (int p = 0; p < 8; p++) acc[p] = bv;
#pragma unroll
  for (int i = 0; i < 7; i++){
    const int yy = y + i - 3;
    if (yy < 0 || yy >= HHW) continue;
    const float* hrow = h + (size_t)(1 + yy * HHW) * D_ + c;
    float line[14];
#pragma unroll
    for (int j = 0; j < 14; j++){
      const int xx = x0 + j - 3;
      line[j] = (xx >= 0 && xx < HHW) ? hrow[(size_t)xx * D_] : 0.f;
    }
#pragma unroll
    for (int p = 0; p < 8; p++)
#pragma unroll
      for (int j = 0; j < 7; j++)
        acc[p] += line[p + j] * wc[i * 7 + j];
  }
#pragma unroll
  for (int p = 0; p < 8; p++)
    tmp[(size_t)(y * HHW + x0 + p) * D_ + c] = acc[p];
}

__global__ void ppeg_copy_kernel(const float* __restrict__ tmp, float* __restrict__ h){
  size_t idx = (size_t)blockIdx.x * 256 + threadIdx.x;
  if (idx < (size_t)NFEAT * D_) h[idx + D_] = tmp[idx];
}

// ---------------- final ----------------
__global__ __launch_bounds__(512) void final_kernel(
    const float* __restrict__ h, const float* __restrict__ w,
    const float* __restrict__ b, const float* __restrict__ fc3w,
    const float* __restrict__ fc3b, float* __restrict__ out){
  __shared__ float vec[512];
  __shared__ float s8[8];
  __shared__ float lg[4];
  const int t = threadIdx.x;
  float x = h[t];
  float v = waveSumF(x);
  if ((t & 63) == 0) s8[t >> 6] = v;
  __syncthreads();
  float sum = 0.f;
#pragma unroll
  for (int i = 0; i < 8; i++) sum += s8[i];
  float mu = sum * (1.f / 512.f);
  __syncthreads();
  float d = x - mu;
  v = waveSumF(d * d);
  if ((t & 63) == 0) s8[t >> 6] = v;
  __syncthreads();
  float var = 0.f;
#pragma unroll
  for (int i = 0; i < 8; i++) var += s8[i];
  var *= (1.f / 512.f);
  float rs = rsqrtf(var + 1e-5f);
  vec[t] = d * rs * w[t] + b[t];
  __syncthreads();
  if (t < 4){
    float acc = fc3b[t];
    for (int kk = 0; kk < 512; kk++) acc += vec[kk] * fc3w[kk * 4 + t];
    lg[t] = acc;
  }
  __syncthreads();
  if (t == 0){
    float m = fmaxf(fmaxf(lg[0], lg[1]), fmaxf(lg[2], lg[3]));
    float e[4], se = 0.f;
#pragma unroll
    for (int i = 0; i < 4; i++){ e[i] = __expf(lg[i] - m); se += e[i]; }
    int am = 0; float bm = lg[0];
#pragma unroll
    for (int i = 1; i < 4; i++) if (lg[i] > bm){ bm = lg[i]; am = i; }
#pragma unroll
    for (int i = 0; i < 4; i++){ out[i] = lg[i]; out[4 + i] = e[i] / se; }
    out[8] = (float)am;
  }
}

// ---------------------------------------------------------------------------
extern "C" void kernel_launch(void* const* d_in, const int* in_sizes, int n_in,
                              void* d_out, int out_size, void* d_ws, size_t ws_size,
                              hipStream_t stream) {
  const float* x       = (const float*)d_in[0];
  const float* fc1_w   = (const float*)d_in[1];
  const float* fc1_b   = (const float*)d_in[2];
  const float* cls_tok = (const float*)d_in[3];
  const float* l1_nw   = (const float*)d_in[4];
  const float* l1_nb   = (const float*)d_in[5];
  const float* l1_qkvw = (const float*)d_in[6];
  const float* l1_outw = (const float*)d_in[7];
  const float* l1_outb = (const float*)d_in[8];
  const float* l1_resw = (const float*)d_in[9];
  const float* ppeg_w7 = (const float*)d_in[10];
  const float* ppeg_b7 = (const float*)d_in[11];
  const float* ppeg_w5 = (const float*)d_in[12];
  const float* ppeg_b5 = (const float*)d_in[13];
  const float* ppeg_w3 = (const float*)d_in[14];
  const float* ppeg_b3 = (const float*)d_in[15];
  const float* l2_nw   = (const float*)d_in[16];
  const float* l2_nb   = (const float*)d_in[17];
  const float* l2_qkvw = (const float*)d_in[18];
  const float* l2_outw = (const float*)d_in[19];
  const float* l2_outb = (const float*)d_in[20];
  const float* l2_resw = (const float*)d_in[21];
  const float* norm_w  = (const float*)d_in[22];
  const float* norm_b  = (const float*)d_in[23];
  const float* fc3_w   = (const float*)d_in[24];
  const float* fc3_b   = (const float*)d_in[25];

  // workspace layout (floats)
  float* W = (float*)d_ws;
  size_t o = 0;
  float* hbuf = W + o; o += (size_t)NTOK * D_;
  float* xp   = W + o; o += (size_t)NP_ * D_;   // also a3v partials, out_m, ppeg tmp
  float* qb   = W + o; o += (size_t)NH_ * NP_ * HD_;
  float* kb   = W + o; o += (size_t)NH_ * NP_ * HD_;
  float* vb   = W + o; o += (size_t)NH_ * NP_ * HD_;
  float* qlb  = W + o; o += (size_t)NH_ * MLM * HD_;
  float* klb  = W + o; o += (size_t)NH_ * MLM * HD_;
  float* a2b  = W + o; o += (size_t)NH_ * MLM * MLM;
  float* z0   = W + o; o += (size_t)NH_ * MLM * MLM;
  float* z1   = W + o; o += (size_t)NH_ * MLM * MLM;
  float* ta   = W + o; o += (size_t)NH_ * MLM * MLM;
  float* tb   = W + o; o += (size_t)NH_ * MLM * MLM;
  float* tc   = W + o; o += (size_t)NH_ * MLM * MLM;
  float* t1b  = W + o; o += (size_t)NH_ * MLM * HD_;
  float* t2b  = W + o; o += (size_t)NH_ * MLM * HD_;
  unsigned int* scal = (unsigned int*)(W + o); o += 16;
  float* wcomb = W + o; o += 49 * 512;
  float* bcomb = W + o; o += 512;
  float* outm = xp;
  // a3v partials aliased into xp (dead between qkv and out_tile)
  float* pacc = xp;                                         // 8*41*256*64
  float* pml  = xp + (size_t)NH_ * NCH * MLM * HD_;         // 8*41*256*2

  fc1_kernel<<<dim3(320, 8), dim3(16, 16), 0, stream>>>(x, fc1_w, fc1_b, hbuf);
  cls_kernel<<<2, 256, 0, stream>>>(cls_tok, hbuf);
  ppeg_combine_kernel<<<1, 512, 0, stream>>>(ppeg_w7, ppeg_b7, ppeg_w5, ppeg_b5,
                                             ppeg_w3, ppeg_b3, wcomb, bcomb);

  auto run_layer = [&](const float* nw, const float* nb, const float* qkvw,
                       const float* outw, const float* outb, const float* resw){
    ln_pad_kernel<<<NP_, 256, 0, stream>>>(hbuf, nw, nb, xp);
    qkv_kernel<<<dim3(328, 24), dim3(16, 16), 0, stream>>>(xp, qkvw, qb, kb, vb);
    landmark_kernel<<<dim3(256, 8), 64, 0, stream>>>(qb, kb, qlb, klb);
    a2_kernel<<<dim3(256, 8), 256, 0, stream>>>(qlb, klb, a2b);
    zero2_kernel<<<1, 64, 0, stream>>>(scal);
    pinv_scale_kernel<<<8, 256, 0, stream>>>(a2b, scal);
    pinv_init_kernel<<<dim3(256, 8), 256, 0, stream>>>(a2b, scal, z0);
    float* zc = z0; float* za = z1;
    for (int it = 0; it < 6; it++){
      bmm256_kernel<<<dim3(4, 4, 8), dim3(16, 16), 0, stream>>>(a2b, zc, ta, 0.f, 1.f, 1.f);
      bmm256_kernel<<<dim3(4, 4, 8), dim3(16, 16), 0, stream>>>(ta, ta, tb, 7.f, -1.f, 1.f);
      bmm256_kernel<<<dim3(4, 4, 8), dim3(16, 16), 0, stream>>>(ta, tb, tc, 15.f, -1.f, 1.f);
      bmm256_kernel<<<dim3(4, 4, 8), dim3(16, 16), 0, stream>>>(zc, tc, za, 13.f, -1.f, 0.25f);
      float* tswap = zc; zc = za; za = tswap;
    }
    // a3v split-K flash (partials in xp), combine, then zt1
    a3v_part_kernel<<<dim3(4, 8, NCH), 256, 0, stream>>>(qlb, kb, vb, pacc, pml);
    a3v_combine_kernel<<<dim3(256, 8), 64, 0, stream>>>(pacc, pml, t1b);
    zt1_kernel<<<dim3(64, 8), 256, 0, stream>>>(zc, t1b, t2b);
    out_tile_kernel<<<dim3(649, 8), 256, 0, stream>>>(qb, klb, t2b, vb, resw, outm);
    proj_kernel<<<dim3(325, 8), dim3(16, 16), 0, stream>>>(outm, outw, outb, hbuf);
  };

  run_layer(l1_nw, l1_nb, l1_qkvw, l1_outw, l1_outb, l1_resw);
  ppeg_conv_kernel<<<dim3(HHW / 8, HHW), 512, 0, stream>>>(hbuf, wcomb, bcomb, xp);
  ppeg_copy_kernel<<<(NFEAT * D_ + 255) / 256, 256, 0, stream>>>(xp, hbuf);
  run_layer(l2_nw, l2_nb, l2_qkvw, l2_outw, l2_outb, l2_resw);
  final_kernel<<<1, 512, 0, stream>>>(hbuf, norm_w, norm_b, fc3_w, fc3_b, (float*)d_out);
}

// Round 5
// 3722.905 us; speedup vs baseline: 3.4905x; 1.4896x over previous
//
#include <hip/hip_runtime.h>

// ---------------------------------------------------------------------------
// TransMIL forward on MI355X.
//   r0: 12995 us baseline (all-fp32, classic 64x64 tiled GEMMs).
//   r1: 10182 us — PPEG collapsed to one combined 7x7 depthwise conv.
//   r2:  8278 us — out_kernel rewritten as fused 32-token tile kernel.
//   r3:  5546 us — a3v rewritten as split-K flash attention.
//   r4: fc1/qkv/proj GEMMs -> bf16 MFMA (16x16x32), 64x64 tiles, B^T weights
//       pre-transposed+converted; LN/maxpool/out_tile write bf16 directly.
// ---------------------------------------------------------------------------

constexpr int D_    = 512;
constexpr int E_    = 1024;
constexpr int NTOK  = 20737;
constexpr int NP_   = 20992;   // padded seq len (255 zero rows at FRONT)
constexpr int NH_   = 8;
constexpr int HD_   = 64;
constexpr int MLM   = 256;     // landmarks
constexpr int LCH   = 82;      // tokens per landmark
constexpr int HHW   = 144;
constexpr int NFEAT = 20736;   // 144*144
constexpr int PADR  = 255;
constexpr int NCH   = 41;      // a3v N-chunks
constexpr int CHTOK = 512;     // tokens per chunk (8 subchunks of 64)

typedef __attribute__((ext_vector_type(8))) short bf16x8;
typedef __attribute__((ext_vector_type(4))) float f32x4;

__device__ __forceinline__ unsigned short f2bf(float f){
  unsigned int u = __float_as_uint(f);
  unsigned int r = u + 0x7fffu + ((u >> 16) & 1u);
  return (unsigned short)(r >> 16);
}

// ---------------- reduction helpers ----------------
__device__ __forceinline__ float waveMaxF(float v){
#pragma unroll
  for (int o = 32; o > 0; o >>= 1) v = fmaxf(v, __shfl_xor(v, o));
  return v;
}
__device__ __forceinline__ float waveSumF(float v){
#pragma unroll
  for (int o = 32; o > 0; o >>= 1) v += __shfl_xor(v, o);
  return v;
}
__device__ __forceinline__ float blockMax256(float v, float* sbuf){
  v = waveMaxF(v);
  if ((threadIdx.x & 63) == 0) sbuf[threadIdx.x >> 6] = v;
  __syncthreads();
  float r = fmaxf(fmaxf(sbuf[0], sbuf[1]), fmaxf(sbuf[2], sbuf[3]));
  __syncthreads();
  return r;
}
__device__ __forceinline__ float blockSum256(float v, float* sbuf){
  v = waveSumF(v);
  if ((threadIdx.x & 63) == 0) sbuf[threadIdx.x >> 6] = v;
  __syncthreads();
  float r = sbuf[0] + sbuf[1] + sbuf[2] + sbuf[3];
  __syncthreads();
  return r;
}

// ---------------- weight prep: W[K][N] fp32 -> Wt[N][K] bf16 ----------------
// grid (K/32, N/32), block (32,8)
__global__ __launch_bounds__(256) void wtrans_kernel(
    const float* __restrict__ W, unsigned short* __restrict__ Wt, int K, int N){
  __shared__ float tile[32][33];
  const int kb = blockIdx.x * 32, nb = blockIdx.y * 32;
  const int tx = threadIdx.x, ty = threadIdx.y;
  for (int i = ty; i < 32; i += 8) tile[i][tx] = W[(size_t)(kb + i) * N + nb + tx];
  __syncthreads();
  for (int i = ty; i < 32; i += 8)
    Wt[(size_t)(nb + i) * K + kb + tx] = f2bf(tile[tx][i]);
}

// ---------------- maxpool2 + bf16: Ah[m][e] = bf16(max(x[2m][e],x[2m+1][e])) ---
// grid 20480, block 256 (4 elems/thread)
__global__ __launch_bounds__(256) void pool_bf16_kernel(
    const float* __restrict__ x, unsigned short* __restrict__ Ah){
  size_t idx4 = ((size_t)blockIdx.x * 256 + threadIdx.x) * 4;
  size_t m = idx4 >> 10, e = idx4 & 1023;
  float4 a = *(const float4*)(x + (m * 2) * E_ + e);
  float4 b = *(const float4*)(x + (m * 2 + 1) * E_ + e);
  unsigned long long pk =
      (unsigned long long)f2bf(fmaxf(a.x, b.x))
    | ((unsigned long long)f2bf(fmaxf(a.y, b.y)) << 16)
    | ((unsigned long long)f2bf(fmaxf(a.z, b.z)) << 32)
    | ((unsigned long long)f2bf(fmaxf(a.w, b.w)) << 48);
  *(unsigned long long*)(Ah + idx4) = pk;
}

// ---------------- MFMA 64x64 tile core (bf16 in, fp32 acc) ----------------
// A [arows][K] bf16 row-major; Bt [N][K] bf16 (B transposed). Block 256.
__device__ __forceinline__ void mfma_tile64(
    const unsigned short* __restrict__ A, int arows, int bm,
    const unsigned short* __restrict__ Bt, int bn, int K,
    f32x4 acc[2][2], unsigned short* As, unsigned short* Bs){
  const int t = threadIdx.x;
  const int lane = t & 63, wave = t >> 6;
  const int wr = wave >> 1, wc = wave & 1;
  const int m16 = lane & 15, quad = lane >> 4;
  const int srow = t >> 2, scol = (t & 3) * 8;
  for (int kc = 0; kc < K; kc += 32){
    {
      int ga = bm + srow;
      ulonglong2 av = {0ull, 0ull};
      if (ga < arows) av = *(const ulonglong2*)(A + (size_t)ga * K + kc + scol);
      *(ulonglong2*)(As + srow * 40 + scol) = av;
      ulonglong2 bv = *(const ulonglong2*)(Bt + (size_t)(bn + srow) * K + kc + scol);
      *(ulonglong2*)(Bs + srow * 40 + scol) = bv;
    }
    __syncthreads();
    bf16x8 a0 = *(const bf16x8*)(As + (wr * 32 + m16) * 40 + quad * 8);
    bf16x8 a1 = *(const bf16x8*)(As + (wr * 32 + 16 + m16) * 40 + quad * 8);
    bf16x8 b0 = *(const bf16x8*)(Bs + (wc * 32 + m16) * 40 + quad * 8);
    bf16x8 b1 = *(const bf16x8*)(Bs + (wc * 32 + 16 + m16) * 40 + quad * 8);
    acc[0][0] = __builtin_amdgcn_mfma_f32_16x16x32_bf16(a0, b0, acc[0][0], 0, 0, 0);
    acc[0][1] = __builtin_amdgcn_mfma_f32_16x16x32_bf16(a0, b1, acc[0][1], 0, 0, 0);
    acc[1][0] = __builtin_amdgcn_mfma_f32_16x16x32_bf16(a1, b0, acc[1][0], 0, 0, 0);
    acc[1][1] = __builtin_amdgcn_mfma_f32_16x16x32_bf16(a1, b1, acc[1][1], 0, 0, 0);
    __syncthreads();
  }
}

// ---------------- fc1: relu(Ah @ fc1_wt^T + b) -> h rows (MFMA) ----------------
// grid (320, 8)
__global__ __launch_bounds__(256) void fc1_mfma_kernel(
    const unsigned short* __restrict__ Ah, const unsigned short* __restrict__ Bt,
    const float* __restrict__ bias, float* __restrict__ h){
  __shared__ unsigned short As[64 * 40], Bs[64 * 40];
  f32x4 z4 = {0.f, 0.f, 0.f, 0.f};
  f32x4 acc[2][2] = {{z4, z4}, {z4, z4}};
  const int bm = blockIdx.x * 64, bn = blockIdx.y * 64;
  mfma_tile64(Ah, 20480, bm, Bt, bn, E_, acc, As, Bs);
  const int lane = threadIdx.x & 63, wave = threadIdx.x >> 6;
  const int wr = wave >> 1, wc = wave & 1;
  const int m16 = lane & 15, quad = lane >> 4;
#pragma unroll
  for (int mi = 0; mi < 2; mi++)
#pragma unroll
    for (int ni = 0; ni < 2; ni++){
      int col = bn + wc * 32 + ni * 16 + m16;
      float bv = bias[col];
#pragma unroll
      for (int r = 0; r < 4; r++){
        int row = bm + wr * 32 + mi * 16 + quad * 4 + r;
        float vv = fmaxf(acc[mi][ni][r] + bv, 0.f);
        h[(size_t)(1 + row) * D_ + col] = vv;
        if (row < 256) h[(size_t)(20481 + row) * D_ + col] = vv;
      }
    }
}

__global__ void cls_kernel(const float* __restrict__ cls, float* __restrict__ h){
  int c = blockIdx.x * 256 + threadIdx.x;
  if (c < D_) h[c] = cls[c];
}

// ---------------- layernorm -> zero-padded bf16 xph ----------------
__global__ __launch_bounds__(256) void ln_pad_kernel(
    const float* __restrict__ h, const float* __restrict__ w,
    const float* __restrict__ b, unsigned short* __restrict__ xph){
  const int r = blockIdx.x;
  const int t = threadIdx.x;
  if (r < PADR){
    xph[(size_t)r * D_ + t] = 0;
    xph[(size_t)r * D_ + 256 + t] = 0;
    return;
  }
  __shared__ float s4[4];
  const float* x = h + (size_t)(r - PADR) * D_;
  float a0 = x[t], a1 = x[t + 256];
  float mu = blockSum256(a0 + a1, s4) * (1.f / 512.f);
  float d0 = a0 - mu, d1 = a1 - mu;
  float var = blockSum256(d0 * d0 + d1 * d1, s4) * (1.f / 512.f);
  float rs = rsqrtf(var + 1e-5f);
  xph[(size_t)r * D_ + t]       = f2bf(d0 * rs * w[t] + b[t]);
  xph[(size_t)r * D_ + 256 + t] = f2bf(d1 * rs * w[t + 256] + b[t + 256]);
}

// ---------------- qkv MFMA: xph @ qkv_wt^T -> q/k/v head-major ----------------
// grid (328, 24)
__global__ __launch_bounds__(256) void qkv_mfma_kernel(
    const unsigned short* __restrict__ A, const unsigned short* __restrict__ Bt,
    float* __restrict__ q, float* __restrict__ k, float* __restrict__ v){
  __shared__ unsigned short As[64 * 40], Bs[64 * 40];
  f32x4 z4 = {0.f, 0.f, 0.f, 0.f};
  f32x4 acc[2][2] = {{z4, z4}, {z4, z4}};
  const int bm = blockIdx.x * 64, bn = blockIdx.y * 64;
  mfma_tile64(A, NP_, bm, Bt, bn, D_, acc, As, Bs);
  const int lane = threadIdx.x & 63, wave = threadIdx.x >> 6;
  const int wr = wave >> 1, wc = wave & 1;
  const int m16 = lane & 15, quad = lane >> 4;
#pragma unroll
  for (int mi = 0; mi < 2; mi++)
#pragma unroll
    for (int ni = 0; ni < 2; ni++){
      int col = bn + wc * 32 + ni * 16 + m16;
      int which = col >> 9, hh = (col >> 6) & 7, d = col & 63;
      float* dst; float sc = 1.f;
      if (which == 0){ dst = q; sc = 0.125f; }
      else if (which == 1) dst = k;
      else dst = v;
      size_t cbase = (size_t)hh * NP_ * HD_ + d;
#pragma unroll
      for (int r = 0; r < 4; r++){
        int row = bm + wr * 32 + mi * 16 + quad * 4 + r;
        dst[cbase + (size_t)row * HD_] = acc[mi][ni][r] * sc;
      }
    }
}

// ---------------- landmarks ----------------
__global__ __launch_bounds__(64) void landmark_kernel(
    const float* __restrict__ q, const float* __restrict__ k,
    float* __restrict__ ql, float* __restrict__ kl){
  const int im = blockIdx.x, h = blockIdx.y, d = threadIdx.x;
  size_t base = ((size_t)h * NP_ + (size_t)im * LCH) * HD_ + d;
  float sq = 0.f, sk = 0.f;
  for (int r = 0; r < LCH; r++){
    sq += q[base + (size_t)r * HD_];
    sk += k[base + (size_t)r * HD_];
  }
  ql[((size_t)h * MLM + im) * HD_ + d] = sq * (1.f / 82.f);
  kl[((size_t)h * MLM + im) * HD_ + d] = sk * (1.f / 82.f);
}

// ---------------- a2 = softmax(ql @ kl^T) ----------------
__global__ __launch_bounds__(256) void a2_kernel(
    const float* __restrict__ ql, const float* __restrict__ kl,
    float* __restrict__ a2){
  const int im = blockIdx.x, h = blockIdx.y, t = threadIdx.x;
  __shared__ __align__(16) float qs[64];
  __shared__ float s4[4];
  if (t < 64) qs[t] = ql[((size_t)h * MLM + im) * HD_ + t];
  __syncthreads();
  const float4* kr4 = (const float4*)(kl + ((size_t)h * MLM + t) * HD_);
  const float4* qs4 = (const float4*)qs;
  float s = 0.f;
#pragma unroll
  for (int d4 = 0; d4 < 16; d4++){
    float4 kv = kr4[d4], qv = qs4[d4];
    s += qv.x*kv.x + qv.y*kv.y + qv.z*kv.z + qv.w*kv.w;
  }
  float mx = blockMax256(s, s4);
  float e = __expf(s - mx);
  float S = blockSum256(e, s4);
  a2[((size_t)h * MLM + im) * MLM + t] = e / S;
}

// ---------------- pinv scaling ----------------
__global__ void zero2_kernel(unsigned int* p){ if (threadIdx.x < 2) p[threadIdx.x] = 0u; }

__global__ __launch_bounds__(256) void pinv_scale_kernel(
    const float* __restrict__ a2, unsigned int* __restrict__ scal){
  const int h = blockIdx.x, j = threadIdx.x;
  const float* A = a2 + (size_t)h * MLM * MLM;
  float rs = 0.f, cs = 0.f;
  for (int t = 0; t < MLM; t++){
    rs += fabsf(A[(size_t)j * MLM + t]);
    cs += fabsf(A[(size_t)t * MLM + j]);
  }
  __shared__ float s4[4];
  float rmax = blockMax256(rs, s4);
  float cmax = blockMax256(cs, s4);
  if (j == 0){
    atomicMax(&scal[0], __float_as_uint(rmax));
    atomicMax(&scal[1], __float_as_uint(cmax));
  }
}

__global__ __launch_bounds__(256) void pinv_init_kernel(
    const float* __restrict__ a2, const unsigned int* __restrict__ scal,
    float* __restrict__ z){
  const int i = blockIdx.x, h = blockIdx.y, j = threadIdx.x;
  float inv = 1.f / (__uint_as_float(scal[0]) * __uint_as_float(scal[1]));
  z[((size_t)h * MLM + i) * MLM + j] = a2[((size_t)h * MLM + j) * MLM + i] * inv;
}

// ---------------- batched 256x256x256: C = c1 * (A @ (c0*I + sgn*B)) ----------------
__global__ __launch_bounds__(256) void bmm256_kernel(
    const float* __restrict__ Ab, const float* __restrict__ Bb,
    float* __restrict__ Cb, float c0, float sgn, float c1){
  const int h = blockIdx.z;
  const float* A = Ab + (size_t)h * 65536;
  const float* B = Bb + (size_t)h * 65536;
  float* C = Cb + (size_t)h * 65536;
  __shared__ float As[16][65];
  __shared__ float Bs[16][65];
  const int bm = blockIdx.x * 64, bn = blockIdx.y * 64;
  const int tid = threadIdx.y * 16 + threadIdx.x;
  float acc[4][4] = {};
  for (int k0 = 0; k0 < 256; k0 += 16){
#pragma unroll
    for (int r = 0; r < 4; r++){
      int e = tid + r * 256;
      int m = e >> 4, kk = e & 15;
      As[kk][m] = A[(size_t)(bm + m) * 256 + k0 + kk];
    }
#pragma unroll
    for (int r = 0; r < 4; r++){
      int e = tid + r * 256;
      int kk = e >> 6, n = e & 63;
      int gk = k0 + kk, gn = bn + n;
      float bv = sgn * B[(size_t)gk * 256 + gn];
      if (gk == gn) bv += c0;
      Bs[kk][n] = bv;
    }
    __syncthreads();
#pragma unroll
    for (int kk = 0; kk < 16; kk++){
      float a[4], b[4];
#pragma unroll
      for (int i = 0; i < 4; i++) a[i] = As[kk][threadIdx.y * 4 + i];
#pragma unroll
      for (int j = 0; j < 4; j++) b[j] = Bs[kk][threadIdx.x * 4 + j];
#pragma unroll
      for (int i = 0; i < 4; i++)
#pragma unroll
        for (int j = 0; j < 4; j++) acc[i][j] += a[i] * b[j];
    }
    __syncthreads();
  }
#pragma unroll
  for (int i = 0; i < 4; i++){
    int row = bm + threadIdx.y * 4 + i;
#pragma unroll
    for (int j = 0; j < 4; j++){
      int col = bn + threadIdx.x * 4 + j;
      C[(size_t)row * 256 + col] = c1 * acc[i][j];
    }
  }
}

// ---------------- a3v split-K flash ----------------
__global__ __launch_bounds__(256) void a3v_part_kernel(
    const float* __restrict__ ql, const float* __restrict__ k,
    const float* __restrict__ v, float* __restrict__ pacc,
    float* __restrict__ pml){
  __shared__ float qs[64][68];
  __shared__ float kb[64][68];
  __shared__ float vb[64][68];
  const int lt = blockIdx.x, h = blockIdx.y, ch = blockIdx.z;
  const int t = threadIdx.x, tx = t & 15, ty = t >> 4;
  const float* qlh = ql + ((size_t)h * MLM + lt * 64) * HD_;
  for (int idx = t; idx < 1024; idx += 256){
    int row = idx >> 4, q4 = idx & 15;
    *(float4*)(&qs[row][q4 * 4]) = *(const float4*)(qlh + (size_t)row * HD_ + q4 * 4);
  }
  const float* kh = k + ((size_t)h * NP_ + ch * CHTOK) * HD_;
  const float* vh = v + ((size_t)h * NP_ + ch * CHTOK) * HD_;
  float o_[4][4] = {};
  float mrow[4], lrow[4];
#pragma unroll
  for (int i = 0; i < 4; i++){ mrow[i] = -3.0e38f; lrow[i] = 0.f; }
  for (int sc = 0; sc < 8; sc++){
    __syncthreads();
    for (int idx = t; idx < 1024; idx += 256){
      int row = idx >> 4, q4 = idx & 15;
      *(float4*)(&kb[row][q4 * 4]) = *(const float4*)(kh + (size_t)(sc * 64 + row) * HD_ + q4 * 4);
      *(float4*)(&vb[row][q4 * 4]) = *(const float4*)(vh + (size_t)(sc * 64 + row) * HD_ + q4 * 4);
    }
    __syncthreads();
    float s[4][4] = {};
#pragma unroll
    for (int k4 = 0; k4 < 16; k4++){
      float4 qv[4], kv[4];
#pragma unroll
      for (int i = 0; i < 4; i++) qv[i] = *(const float4*)(&qs[ty + 16 * i][k4 * 4]);
#pragma unroll
      for (int jj = 0; jj < 4; jj++) kv[jj] = *(const float4*)(&kb[jj * 16 + tx][k4 * 4]);
#pragma unroll
      for (int i = 0; i < 4; i++)
#pragma unroll
        for (int jj = 0; jj < 4; jj++)
          s[i][jj] += qv[i].x*kv[jj].x + qv[i].y*kv[jj].y + qv[i].z*kv[jj].z + qv[i].w*kv[jj].w;
    }
    __syncthreads();
#pragma unroll
    for (int i = 0; i < 4; i++){
      float cm = fmaxf(fmaxf(s[i][0], s[i][1]), fmaxf(s[i][2], s[i][3]));
#pragma unroll
      for (int o = 1; o < 16; o <<= 1) cm = fmaxf(cm, __shfl_xor(cm, o));
      float mn = fmaxf(mrow[i], cm);
      float scale = __expf(mrow[i] - mn);
      float ls = 0.f;
#pragma unroll
      for (int jj = 0; jj < 4; jj++){ s[i][jj] = __expf(s[i][jj] - mn); ls += s[i][jj]; }
#pragma unroll
      for (int o = 1; o < 16; o <<= 1) ls += __shfl_xor(ls, o);
      lrow[i] = lrow[i] * scale + ls;
      mrow[i] = mn;
#pragma unroll
      for (int e = 0; e < 4; e++) o_[i][e] *= scale;
#pragma unroll
      for (int jj = 0; jj < 4; jj++) kb[ty + 16 * i][jj * 16 + tx] = s[i][jj];
    }
    __syncthreads();
#pragma unroll
    for (int c4 = 0; c4 < 16; c4++){
      float4 pv[4], vv[4];
#pragma unroll
      for (int i = 0; i < 4; i++) pv[i] = *(const float4*)(&kb[ty + 16 * i][c4 * 4]);
#pragma unroll
      for (int e = 0; e < 4; e++) vv[e] = *(const float4*)(&vb[c4 * 4 + e][tx * 4]);
#pragma unroll
      for (int i = 0; i < 4; i++){
        o_[i][0] += pv[i].x*vv[0].x + pv[i].y*vv[1].x + pv[i].z*vv[2].x + pv[i].w*vv[3].x;
        o_[i][1] += pv[i].x*vv[0].y + pv[i].y*vv[1].y + pv[i].z*vv[2].y + pv[i].w*vv[3].y;
        o_[i][2] += pv[i].x*vv[0].z + pv[i].y*vv[1].z + pv[i].z*vv[2].z + pv[i].w*vv[3].z;
        o_[i][3] += pv[i].x*vv[0].w + pv[i].y*vv[1].w + pv[i].z*vv[2].w + pv[i].w*vv[3].w;
      }
    }
  }
#pragma unroll
  for (int i = 0; i < 4; i++){
    int im = lt * 64 + ty + 16 * i;
    size_t base = ((size_t)h * NCH + ch) * MLM + im;
    float4 val = make_float4(o_[i][0], o_[i][1], o_[i][2], o_[i][3]);
    *(float4*)(pacc + base * HD_ + tx * 4) = val;
    if (tx == 0){
      pml[base * 2]     = mrow[i];
      pml[base * 2 + 1] = lrow[i];
    }
  }
}

__global__ __launch_bounds__(64) void a3v_combine_kernel(
    const float* __restrict__ pacc, const float* __restrict__ pml,
    float* __restrict__ t1){
  const int im = blockIdx.x, h = blockIdx.y, lane = threadIdx.x;
  float M = -3.0e38f;
  for (int c = 0; c < NCH; c++)
    M = fmaxf(M, pml[(((size_t)h * NCH + c) * MLM + im) * 2]);
  float accv = 0.f, L = 0.f;
  for (int c = 0; c < NCH; c++){
    size_t base = ((size_t)h * NCH + c) * MLM + im;
    float mc = pml[base * 2], lc = pml[base * 2 + 1];
    float w = __expf(mc - M);
    accv += w * pacc[base * HD_ + lane];
    L += w * lc;
  }
  t1[((size_t)h * MLM + im) * HD_ + lane] = accv / L;
}

// ---------------- t2 = z @ t1 ----------------
__global__ __launch_bounds__(256) void zt1_kernel(
    const float* __restrict__ z, const float* __restrict__ t1,
    float* __restrict__ t2){
  const int h = blockIdx.y;
  const int t = threadIdx.x;
  const int d = t & 63, ri = t >> 6;
  const int im = blockIdx.x * 4 + ri;
  const float* zr = z + ((size_t)h * MLM + im) * MLM;
  const float* t1h = t1 + (size_t)h * MLM * HD_;
  float acc = 0.f;
#pragma unroll 8
  for (int kk = 0; kk < MLM; kk++) acc += zr[kk] * t1h[(size_t)kk * HD_ + d];
  t2[((size_t)h * MLM + im) * HD_ + d] = acc;
}

// ---------------- out tile: 32 tokens x 1 head per block -> bf16 outh ----------
__global__ __launch_bounds__(256) void out_tile_kernel(
    const float* __restrict__ q, const float* __restrict__ kl,
    const float* __restrict__ t2, const float* __restrict__ v,
    const float* __restrict__ resw, unsigned short* __restrict__ outh){
  __shared__ float qs[32][68];
  __shared__ float buf[64][68];
  __shared__ float Ps[32][260];
  const int h = blockIdx.y;
  const int tile = blockIdx.x;
  const int n0 = PADR + tile * 32;
  const int t = threadIdx.x;
  const int tx = t & 15, ty = t >> 4;
  {
    const float* qh = q + (size_t)h * NP_ * HD_;
    for (int idx = t; idx < 512; idx += 256){
      int row = idx >> 4, q4 = idx & 15;
      int n = n0 + row;
      float4 val = make_float4(0.f, 0.f, 0.f, 0.f);
      if (n < NP_) val = *(const float4*)(qh + (size_t)n * HD_ + q4 * 4);
      *(float4*)(&qs[row][q4 * 4]) = val;
    }
  }
  float s[2][16];
#pragma unroll
  for (int i = 0; i < 2; i++)
#pragma unroll
    for (int u = 0; u < 16; u++) s[i][u] = 0.f;
  const float* klh = kl + (size_t)h * MLM * HD_;
  for (int m = 0; m < 4; m++){
    __syncthreads();
    for (int idx = t; idx < 1024; idx += 256){
      int row = idx >> 4, q4 = idx & 15;
      *(float4*)(&buf[row][q4 * 4]) =
          *(const float4*)(klh + (size_t)(m * 64 + row) * HD_ + q4 * 4);
    }
    __syncthreads();
#pragma unroll
    for (int k4 = 0; k4 < 16; k4++){
      float4 q0 = *(const float4*)(&qs[2 * ty + 0][k4 * 4]);
      float4 q1 = *(const float4*)(&qs[2 * ty + 1][k4 * 4]);
#pragma unroll
      for (int jj = 0; jj < 4; jj++){
        float4 kv = *(const float4*)(&buf[tx + 16 * jj][k4 * 4]);
        s[0][m * 4 + jj] += q0.x*kv.x + q0.y*kv.y + q0.z*kv.z + q0.w*kv.w;
        s[1][m * 4 + jj] += q1.x*kv.x + q1.y*kv.y + q1.z*kv.z + q1.w*kv.w;
      }
    }
  }
#pragma unroll
  for (int i = 0; i < 2; i++){
    float mx = -3.0e38f;
#pragma unroll
    for (int u = 0; u < 16; u++) mx = fmaxf(mx, s[i][u]);
#pragma unroll
    for (int o = 1; o < 16; o <<= 1) mx = fmaxf(mx, __shfl_xor(mx, o));
    float sum = 0.f;
#pragma unroll
    for (int u = 0; u < 16; u++){ s[i][u] = __expf(s[i][u] - mx); sum += s[i][u]; }
#pragma unroll
    for (int o = 1; o < 16; o <<= 1) sum += __shfl_xor(sum, o);
    float inv = 1.f / sum;
#pragma unroll
    for (int u = 0; u < 16; u++) s[i][u] *= inv;
  }
#pragma unroll
  for (int i = 0; i < 2; i++)
#pragma unroll
    for (int mm = 0; mm < 4; mm++)
#pragma unroll
      for (int jj = 0; jj < 4; jj++)
        Ps[2 * ty + i][mm * 64 + jj * 16 + tx] = s[i][mm * 4 + jj];

  float o_[2][4] = {};
  const float* t2h = t2 + (size_t)h * MLM * HD_;
  for (int kc = 0; kc < 4; kc++){
    __syncthreads();
    for (int idx = t; idx < 1024; idx += 256){
      int row = idx >> 4, q4 = idx & 15;
      *(float4*)(&buf[row][q4 * 4]) =
          *(const float4*)(t2h + (size_t)(kc * 64 + row) * HD_ + q4 * 4);
    }
    __syncthreads();
#pragma unroll
    for (int k4 = 0; k4 < 16; k4++){
      float4 p0 = *(const float4*)(&Ps[2 * ty + 0][kc * 64 + k4 * 4]);
      float4 p1 = *(const float4*)(&Ps[2 * ty + 1][kc * 64 + k4 * 4]);
      float pa[4] = {p0.x, p0.y, p0.z, p0.w};
      float pb[4] = {p1.x, p1.y, p1.z, p1.w};
#pragma unroll
      for (int i = 0; i < 4; i++){
        float4 tv = *(const float4*)(&buf[k4 * 4 + i][tx * 4]);
        o_[0][0] += pa[i] * tv.x; o_[0][1] += pa[i] * tv.y;
        o_[0][2] += pa[i] * tv.z; o_[0][3] += pa[i] * tv.w;
        o_[1][0] += pb[i] * tv.x; o_[1][1] += pb[i] * tv.y;
        o_[1][2] += pb[i] * tv.z; o_[1][3] += pb[i] * tv.w;
      }
    }
  }
  __syncthreads();
  {
    const float* vh = v + (size_t)h * NP_ * HD_;
    for (int idx = t; idx < 1024; idx += 256){
      int row = idx >> 4, q4 = idx & 15;
      int nn = n0 - 16 + row;
      float4 val = make_float4(0.f, 0.f, 0.f, 0.f);
      if (nn < NP_) val = *(const float4*)(vh + (size_t)nn * HD_ + q4 * 4);
      *(float4*)(&buf[row][q4 * 4]) = val;
    }
  }
  __syncthreads();
  float wreg[33];
  {
    const float* wr = resw + h * 33;
#pragma unroll
    for (int kk = 0; kk < 33; kk++) wreg[kk] = wr[kk];
  }
#pragma unroll
  for (int i = 0; i < 2; i++){
    float4 cacc = make_float4(0.f, 0.f, 0.f, 0.f);
    for (int kk = 0; kk < 33; kk++){
      float4 vv = *(const float4*)(&buf[2 * ty + i + kk][tx * 4]);
      float w = wreg[kk];
      cacc.x += vv.x * w; cacc.y += vv.y * w;
      cacc.z += vv.z * w; cacc.w += vv.w * w;
    }
    int nrow = tile * 32 + 2 * ty + i;
    if (nrow < NTOK){
      unsigned long long pk =
          (unsigned long long)f2bf(o_[i][0] + cacc.x)
        | ((unsigned long long)f2bf(o_[i][1] + cacc.y) << 16)
        | ((unsigned long long)f2bf(o_[i][2] + cacc.z) << 32)
        | ((unsigned long long)f2bf(o_[i][3] + cacc.w) << 48);
      *(unsigned long long*)(outh + (size_t)nrow * D_ + h * HD_ + tx * 4) = pk;
    }
  }
}

// ---------------- proj MFMA: h += outh @ out_wt^T + bias ----------------
// grid (325, 8)
__global__ __launch_bounds__(256) void proj_mfma_kernel(
    const unsigned short* __restrict__ A, const unsigned short* __restrict__ Bt,
    const float* __restrict__ bias, float* __restrict__ h){
  __shared__ unsigned short As[64 * 40], Bs[64 * 40];
  f32x4 z4 = {0.f, 0.f, 0.f, 0.f};
  f32x4 acc[2][2] = {{z4, z4}, {z4, z4}};
  const int bm = blockIdx.x * 64, bn = blockIdx.y * 64;
  mfma_tile64(A, NTOK, bm, Bt, bn, D_, acc, As, Bs);
  const int lane = threadIdx.x & 63, wave = threadIdx.x >> 6;
  const int wr = wave >> 1, wc = wave & 1;
  const int m16 = lane & 15, quad = lane >> 4;
#pragma unroll
  for (int mi = 0; mi < 2; mi++)
#pragma unroll
    for (int ni = 0; ni < 2; ni++){
      int col = bn + wc * 32 + ni * 16 + m16;
      float bv = bias[col];
#pragma unroll
      for (int r = 0; r < 4; r++){
        int row = bm + wr * 32 + mi * 16 + quad * 4 + r;
        if (row < NTOK) h[(size_t)row * D_ + col] += acc[mi][ni][r] + bv;
      }
    }
}

// ---------------- PPEG ----------------
__global__ __launch_bounds__(512) void ppeg_combine_kernel(
    const float* __restrict__ w7, const float* __restrict__ b7,
    const float* __restrict__ w5, const float* __restrict__ b5,
    const float* __restrict__ w3, const float* __restrict__ b3,
    float* __restrict__ wcomb, float* __restrict__ bcomb){
  const int c = threadIdx.x;
#pragma unroll
  for (int i = 0; i < 7; i++){
#pragma unroll
    for (int j = 0; j < 7; j++){
      int di = i - 3, dj = j - 3;
      float wv = w7[(size_t)c * 49 + i * 7 + j];
      if (di >= -2 && di <= 2 && dj >= -2 && dj <= 2)
        wv += w5[(size_t)c * 25 + (di + 2) * 5 + (dj + 2)];
      if (di >= -1 && di <= 1 && dj >= -1 && dj <= 1)
        wv += w3[(size_t)c * 9 + (di + 1) * 3 + (dj + 1)];
      if (di == 0 && dj == 0) wv += 1.f;
      wcomb[(size_t)(i * 7 + j) * 512 + c] = wv;
    }
  }
  bcomb[c] = b7[c] + b5[c] + b3[c];
}

__global__ __launch_bounds__(512) void ppeg_conv_kernel(
    const float* __restrict__ h, const float* __restrict__ wcomb,
    const float* __restrict__ bcomb, float* __restrict__ tmp){
  const int c = threadIdx.x;
  const int y = blockIdx.y;
  const int x0 = blockIdx.x * 8;
  float wc[49];
#pragma unroll
  for (int kk = 0; kk < 49; kk++) wc[kk] = wcomb[(size_t)kk * 512 + c];
  float acc[8];
  const float bv = bcomb[c];
#pragma unroll
  for (int p = 0; p < 8; p++) acc[p] = bv;
#pragma unroll
  for (int i = 0; i < 7; i++){
    const int yy = y + i - 3;
    if (yy < 0 || yy >= HHW) continue;
    const float* hrow = h + (size_t)(1 + yy * HHW) * D_ + c;
    float line[14];
#pragma unroll
    for (int j = 0; j < 14; j++){
      const int xx = x0 + j - 3;
      line[j] = (xx >= 0 && xx < HHW) ? hrow[(size_t)xx * D_] : 0.f;
    }
#pragma unroll
    for (int p = 0; p < 8; p++)
#pragma unroll
      for (int j = 0; j < 7; j++)
        acc[p] += line[p + j] * wc[i * 7 + j];
  }
#pragma unroll
  for (int p = 0; p < 8; p++)
    tmp[(size_t)(y * HHW + x0 + p) * D_ + c] = acc[p];
}

__global__ void ppeg_copy_kernel(const float* __restrict__ tmp, float* __restrict__ h){
  size_t idx = (size_t)blockIdx.x * 256 + threadIdx.x;
  if (idx < (size_t)NFEAT * D_) h[idx + D_] = tmp[idx];
}

// ---------------- final ----------------
__global__ __launch_bounds__(512) void final_kernel(
    const float* __restrict__ h, const float* __restrict__ w,
    const float* __restrict__ b, const float* __restrict__ fc3w,
    const float* __restrict__ fc3b, float* __restrict__ out){
  __shared__ float vec[512];
  __shared__ float s8[8];
  __shared__ float lg[4];
  const int t = threadIdx.x;
  float x = h[t];
  float v = waveSumF(x);
  if ((t & 63) == 0) s8[t >> 6] = v;
  __syncthreads();
  float sum = 0.f;
#pragma unroll
  for (int i = 0; i < 8; i++) sum += s8[i];
  float mu = sum * (1.f / 512.f);
  __syncthreads();
  float d = x - mu;
  v = waveSumF(d * d);
  if ((t & 63) == 0) s8[t >> 6] = v;
  __syncthreads();
  float var = 0.f;
#pragma unroll
  for (int i = 0; i < 8; i++) var += s8[i];
  var *= (1.f / 512.f);
  float rs = rsqrtf(var + 1e-5f);
  vec[t] = d * rs * w[t] + b[t];
  __syncthreads();
  if (t < 4){
    float acc = fc3b[t];
    for (int kk = 0; kk < 512; kk++) acc += vec[kk] * fc3w[kk * 4 + t];
    lg[t] = acc;
  }
  __syncthreads();
  if (t == 0){
    float m = fmaxf(fmaxf(lg[0], lg[1]), fmaxf(lg[2], lg[3]));
    float e[4], se = 0.f;
#pragma unroll
    for (int i = 0; i < 4; i++){ e[i] = __expf(lg[i] - m); se += e[i]; }
    int am = 0; float bm = lg[0];
#pragma unroll
    for (int i = 1; i < 4; i++) if (lg[i] > bm){ bm = lg[i]; am = i; }
#pragma unroll
    for (int i = 0; i < 4; i++){ out[i] = lg[i]; out[4 + i] = e[i] / se; }
    out[8] = (float)am;
  }
}

// ---------------------------------------------------------------------------
extern "C" void kernel_launch(void* const* d_in, const int* in_sizes, int n_in,
                              void* d_out, int out_size, void* d_ws, size_t ws_size,
                              hipStream_t stream) {
  const float* x       = (const float*)d_in[0];
  const float* fc1_w   = (const float*)d_in[1];
  const float* fc1_b   = (const float*)d_in[2];
  const float* cls_tok = (const float*)d_in[3];
  const float* l1_nw   = (const float*)d_in[4];
  const float* l1_nb   = (const float*)d_in[5];
  const float* l1_qkvw = (const float*)d_in[6];
  const float* l1_outw = (const float*)d_in[7];
  const float* l1_outb = (const float*)d_in[8];
  const float* l1_resw = (const float*)d_in[9];
  const float* ppeg_w7 = (const float*)d_in[10];
  const float* ppeg_b7 = (const float*)d_in[11];
  const float* ppeg_w5 = (const float*)d_in[12];
  const float* ppeg_b5 = (const float*)d_in[13];
  const float* ppeg_w3 = (const float*)d_in[14];
  const float* ppeg_b3 = (const float*)d_in[15];
  const float* l2_nw   = (const float*)d_in[16];
  const float* l2_nb   = (const float*)d_in[17];
  const float* l2_qkvw = (const float*)d_in[18];
  const float* l2_outw = (const float*)d_in[19];
  const float* l2_outb = (const float*)d_in[20];
  const float* l2_resw = (const float*)d_in[21];
  const float* norm_w  = (const float*)d_in[22];
  const float* norm_b  = (const float*)d_in[23];
  const float* fc3_w   = (const float*)d_in[24];
  const float* fc3_b   = (const float*)d_in[25];

  // workspace layout (float units)
  float* W = (float*)d_ws;
  size_t o = 0;
  float* hbuf = W + o; o += (size_t)NTOK * D_;
  float* xp   = W + o; o += (size_t)NP_ * D_;   // xph / pacc+pml / outh / ppeg tmp
  float* qb   = W + o; o += (size_t)NH_ * NP_ * HD_;   // also Ah (pooled bf16) pre-layer
  float* kb   = W + o; o += (size_t)NH_ * NP_ * HD_;
  float* vb   = W + o; o += (size_t)NH_ * NP_ * HD_;
  float* qlb  = W + o; o += (size_t)NH_ * MLM * HD_;
  float* klb  = W + o; o += (size_t)NH_ * MLM * HD_;
  float* a2b  = W + o; o += (size_t)NH_ * MLM * MLM;
  float* z0   = W + o; o += (size_t)NH_ * MLM * MLM;
  float* z1   = W + o; o += (size_t)NH_ * MLM * MLM;
  float* ta   = W + o; o += (size_t)NH_ * MLM * MLM;
  float* tb   = W + o; o += (size_t)NH_ * MLM * MLM;
  float* tc   = W + o; o += (size_t)NH_ * MLM * MLM;
  float* t1b  = W + o; o += (size_t)NH_ * MLM * HD_;
  float* t2b  = W + o; o += (size_t)NH_ * MLM * HD_;
  unsigned int* scal = (unsigned int*)(W + o); o += 16;
  float* wcomb = W + o; o += 49 * 512;
  float* bcomb = W + o; o += 512;
  unsigned short* fc1_wt  = (unsigned short*)(W + o); o += (size_t)D_ * E_ / 2;      // [512][1024]
  unsigned short* qkv_wt1 = (unsigned short*)(W + o); o += (size_t)1536 * D_ / 2;    // [1536][512]
  unsigned short* qkv_wt2 = (unsigned short*)(W + o); o += (size_t)1536 * D_ / 2;
  unsigned short* out_wt1 = (unsigned short*)(W + o); o += (size_t)D_ * D_ / 2;      // [512][512]
  unsigned short* out_wt2 = (unsigned short*)(W + o); o += (size_t)D_ * D_ / 2;

  // time-multiplexed aliases inside xp region (sequential uses within a layer):
  unsigned short* xph = (unsigned short*)xp;                 // LN out bf16 [NP_][512]
  float* pacc = xp;                                          // a3v partials
  float* pml  = xp + (size_t)NH_ * NCH * MLM * HD_;
  unsigned short* outh = (unsigned short*)xp;                // attn out bf16 [NTOK][512]
  unsigned short* Ah = (unsigned short*)qb;                  // pooled x bf16 [20480][1024]

  // ---- weight prep (once per launch) ----
  wtrans_kernel<<<dim3(E_ / 32, D_ / 32), dim3(32, 8), 0, stream>>>(fc1_w, fc1_wt, E_, D_);
  wtrans_kernel<<<dim3(D_ / 32, 1536 / 32), dim3(32, 8), 0, stream>>>(l1_qkvw, qkv_wt1, D_, 1536);
  wtrans_kernel<<<dim3(D_ / 32, 1536 / 32), dim3(32, 8), 0, stream>>>(l2_qkvw, qkv_wt2, D_, 1536);
  wtrans_kernel<<<dim3(D_ / 32, D_ / 32), dim3(32, 8), 0, stream>>>(l1_outw, out_wt1, D_, D_);
  wtrans_kernel<<<dim3(D_ / 32, D_ / 32), dim3(32, 8), 0, stream>>>(l2_outw, out_wt2, D_, D_);
  ppeg_combine_kernel<<<1, 512, 0, stream>>>(ppeg_w7, ppeg_b7, ppeg_w5, ppeg_b5,
                                             ppeg_w3, ppeg_b3, wcomb, bcomb);

  // ---- fc1 (maxpool -> bf16 -> MFMA) ----
  pool_bf16_kernel<<<20480, 256, 0, stream>>>(x, Ah);
  fc1_mfma_kernel<<<dim3(320, 8), 256, 0, stream>>>(Ah, fc1_wt, fc1_b, hbuf);
  cls_kernel<<<2, 256, 0, stream>>>(cls_tok, hbuf);

  auto run_layer = [&](const float* nw, const float* nb,
                       const unsigned short* qkvwt, const unsigned short* outwt,
                       const float* outb, const float* resw){
    ln_pad_kernel<<<NP_, 256, 0, stream>>>(hbuf, nw, nb, xph);
    qkv_mfma_kernel<<<dim3(328, 24), 256, 0, stream>>>(xph, qkvwt, qb, kb, vb);
    landmark_kernel<<<dim3(256, 8), 64, 0, stream>>>(qb, kb, qlb, klb);
    a2_kernel<<<dim3(256, 8), 256, 0, stream>>>(qlb, klb, a2b);
    zero2_kernel<<<1, 64, 0, stream>>>(scal);
    pinv_scale_kernel<<<8, 256, 0, stream>>>(a2b, scal);
    pinv_init_kernel<<<dim3(256, 8), 256, 0, stream>>>(a2b, scal, z0);
    float* zc = z0; float* za = z1;
    for (int it = 0; it < 6; it++){
      bmm256_kernel<<<dim3(4, 4, 8), dim3(16, 16), 0, stream>>>(a2b, zc, ta, 0.f, 1.f, 1.f);
      bmm256_kernel<<<dim3(4, 4, 8), dim3(16, 16), 0, stream>>>(ta, ta, tb, 7.f, -1.f, 1.f);
      bmm256_kernel<<<dim3(4, 4, 8), dim3(16, 16), 0, stream>>>(ta, tb, tc, 15.f, -1.f, 1.f);
      bmm256_kernel<<<dim3(4, 4, 8), dim3(16, 16), 0, stream>>>(zc, tc, za, 13.f, -1.f, 0.25f);
      float* tswap = zc; zc = za; za = tswap;
    }
    a3v_part_kernel<<<dim3(4, 8, NCH), 256, 0, stream>>>(qlb, kb, vb, pacc, pml);
    a3v_combine_kernel<<<dim3(256, 8), 64, 0, stream>>>(pacc, pml, t1b);
    zt1_kernel<<<dim3(64, 8), 256, 0, stream>>>(zc, t1b, t2b);
    out_tile_kernel<<<dim3(649, 8), 256, 0, stream>>>(qb, klb, t2b, vb, resw, outh);
    proj_mfma_kernel<<<dim3(325, 8), 256, 0, stream>>>(outh, outwt, outb, hbuf);
  };

  run_layer(l1_nw, l1_nb, qkv_wt1, out_wt1, l1_outb, l1_resw);
  ppeg_conv_kernel<<<dim3(HHW / 8, HHW), 512, 0, stream>>>(hbuf, wcomb, bcomb, xp);
  ppeg_copy_kernel<<<(NFEAT * D_ + 255) / 256, 256, 0, stream>>>(xp, hbuf);
  run_layer(l2_nw, l2_nb, qkv_wt2, out_wt2, l2_outb, l2_resw);
  final_kernel<<<1, 512, 0, stream>>>(hbuf, norm_w, norm_b, fc3_w, fc3_b, (float*)d_out);
}

// Round 6
// 3025.141 us; speedup vs baseline: 4.2956x; 1.2307x over previous
//
#include <hip/hip_runtime.h>

// ---------------------------------------------------------------------------
// TransMIL forward on MI355X.
//   r0: 12995 us baseline (all-fp32, classic 64x64 tiled GEMMs).
//   r1: 10182 us — PPEG collapsed to one combined 7x7 depthwise conv.
//   r2:  8278 us — out_kernel rewritten as fused 32-token tile kernel.
//   r3:  5546 us — a3v rewritten as split-K flash attention.
//   r4:  3723 us — fc1/qkv/proj GEMMs -> bf16 MFMA (16x16x32).
//   r5: a3v_part -> bf16 MFMA flash (K/V stored bf16, V transposed in LDS,
//       online softmax in MFMA C-layout registers, P via LDS as A-operand).
// ---------------------------------------------------------------------------

constexpr int D_    = 512;
constexpr int E_    = 1024;
constexpr int NTOK  = 20737;
constexpr int NP_   = 20992;   // padded seq len (255 zero rows at FRONT)
constexpr int NH_   = 8;
constexpr int HD_   = 64;
constexpr int MLM   = 256;     // landmarks
constexpr int LCH   = 82;      // tokens per landmark
constexpr int HHW   = 144;
constexpr int NFEAT = 20736;   // 144*144
constexpr int PADR  = 255;
constexpr int NCH   = 41;      // a3v N-chunks
constexpr int CHTOK = 512;     // tokens per chunk (8 subchunks of 64)

typedef __attribute__((ext_vector_type(8))) short bf16x8;
typedef __attribute__((ext_vector_type(4))) float f32x4;

__device__ __forceinline__ unsigned short f2bf(float f){
  unsigned int u = __float_as_uint(f);
  unsigned int r = u + 0x7fffu + ((u >> 16) & 1u);
  return (unsigned short)(r >> 16);
}
__device__ __forceinline__ float bfu(unsigned short u){
  return __uint_as_float((unsigned int)u << 16);
}

// ---------------- reduction helpers ----------------
__device__ __forceinline__ float waveMaxF(float v){
#pragma unroll
  for (int o = 32; o > 0; o >>= 1) v = fmaxf(v, __shfl_xor(v, o));
  return v;
}
__device__ __forceinline__ float waveSumF(float v){
#pragma unroll
  for (int o = 32; o > 0; o >>= 1) v += __shfl_xor(v, o);
  return v;
}
__device__ __forceinline__ float blockMax256(float v, float* sbuf){
  v = waveMaxF(v);
  if ((threadIdx.x & 63) == 0) sbuf[threadIdx.x >> 6] = v;
  __syncthreads();
  float r = fmaxf(fmaxf(sbuf[0], sbuf[1]), fmaxf(sbuf[2], sbuf[3]));
  __syncthreads();
  return r;
}
__device__ __forceinline__ float blockSum256(float v, float* sbuf){
  v = waveSumF(v);
  if ((threadIdx.x & 63) == 0) sbuf[threadIdx.x >> 6] = v;
  __syncthreads();
  float r = sbuf[0] + sbuf[1] + sbuf[2] + sbuf[3];
  __syncthreads();
  return r;
}

// ---------------- weight prep: W[K][N] fp32 -> Wt[N][K] bf16 ----------------
__global__ __launch_bounds__(256) void wtrans_kernel(
    const float* __restrict__ W, unsigned short* __restrict__ Wt, int K, int N){
  __shared__ float tile[32][33];
  const int kb = blockIdx.x * 32, nb = blockIdx.y * 32;
  const int tx = threadIdx.x, ty = threadIdx.y;
  for (int i = ty; i < 32; i += 8) tile[i][tx] = W[(size_t)(kb + i) * N + nb + tx];
  __syncthreads();
  for (int i = ty; i < 32; i += 8)
    Wt[(size_t)(nb + i) * K + kb + tx] = f2bf(tile[tx][i]);
}

// ---------------- maxpool2 + bf16 ----------------
__global__ __launch_bounds__(256) void pool_bf16_kernel(
    const float* __restrict__ x, unsigned short* __restrict__ Ah){
  size_t idx4 = ((size_t)blockIdx.x * 256 + threadIdx.x) * 4;
  size_t m = idx4 >> 10, e = idx4 & 1023;
  float4 a = *(const float4*)(x + (m * 2) * E_ + e);
  float4 b = *(const float4*)(x + (m * 2 + 1) * E_ + e);
  unsigned long long pk =
      (unsigned long long)f2bf(fmaxf(a.x, b.x))
    | ((unsigned long long)f2bf(fmaxf(a.y, b.y)) << 16)
    | ((unsigned long long)f2bf(fmaxf(a.z, b.z)) << 32)
    | ((unsigned long long)f2bf(fmaxf(a.w, b.w)) << 48);
  *(unsigned long long*)(Ah + idx4) = pk;
}

// ---------------- MFMA 64x64 tile core (bf16 in, fp32 acc) ----------------
__device__ __forceinline__ void mfma_tile64(
    const unsigned short* __restrict__ A, int arows, int bm,
    const unsigned short* __restrict__ Bt, int bn, int K,
    f32x4 acc[2][2], unsigned short* As, unsigned short* Bs){
  const int t = threadIdx.x;
  const int lane = t & 63, wave = t >> 6;
  const int wr = wave >> 1, wc = wave & 1;
  const int m16 = lane & 15, quad = lane >> 4;
  const int srow = t >> 2, scol = (t & 3) * 8;
  for (int kc = 0; kc < K; kc += 32){
    {
      int ga = bm + srow;
      ulonglong2 av = {0ull, 0ull};
      if (ga < arows) av = *(const ulonglong2*)(A + (size_t)ga * K + kc + scol);
      *(ulonglong2*)(As + srow * 40 + scol) = av;
      ulonglong2 bv = *(const ulonglong2*)(Bt + (size_t)(bn + srow) * K + kc + scol);
      *(ulonglong2*)(Bs + srow * 40 + scol) = bv;
    }
    __syncthreads();
    bf16x8 a0 = *(const bf16x8*)(As + (wr * 32 + m16) * 40 + quad * 8);
    bf16x8 a1 = *(const bf16x8*)(As + (wr * 32 + 16 + m16) * 40 + quad * 8);
    bf16x8 b0 = *(const bf16x8*)(Bs + (wc * 32 + m16) * 40 + quad * 8);
    bf16x8 b1 = *(const bf16x8*)(Bs + (wc * 32 + 16 + m16) * 40 + quad * 8);
    acc[0][0] = __builtin_amdgcn_mfma_f32_16x16x32_bf16(a0, b0, acc[0][0], 0, 0, 0);
    acc[0][1] = __builtin_amdgcn_mfma_f32_16x16x32_bf16(a0, b1, acc[0][1], 0, 0, 0);
    acc[1][0] = __builtin_amdgcn_mfma_f32_16x16x32_bf16(a1, b0, acc[1][0], 0, 0, 0);
    acc[1][1] = __builtin_amdgcn_mfma_f32_16x16x32_bf16(a1, b1, acc[1][1], 0, 0, 0);
    __syncthreads();
  }
}

// ---------------- fc1 ----------------
__global__ __launch_bounds__(256) void fc1_mfma_kernel(
    const unsigned short* __restrict__ Ah, const unsigned short* __restrict__ Bt,
    const float* __restrict__ bias, float* __restrict__ h){
  __shared__ unsigned short As[64 * 40], Bs[64 * 40];
  f32x4 z4 = {0.f, 0.f, 0.f, 0.f};
  f32x4 acc[2][2] = {{z4, z4}, {z4, z4}};
  const int bm = blockIdx.x * 64, bn = blockIdx.y * 64;
  mfma_tile64(Ah, 20480, bm, Bt, bn, E_, acc, As, Bs);
  const int lane = threadIdx.x & 63, wave = threadIdx.x >> 6;
  const int wr = wave >> 1, wc = wave & 1;
  const int m16 = lane & 15, quad = lane >> 4;
#pragma unroll
  for (int mi = 0; mi < 2; mi++)
#pragma unroll
    for (int ni = 0; ni < 2; ni++){
      int col = bn + wc * 32 + ni * 16 + m16;
      float bv = bias[col];
#pragma unroll
      for (int r = 0; r < 4; r++){
        int row = bm + wr * 32 + mi * 16 + quad * 4 + r;
        float vv = fmaxf(acc[mi][ni][r] + bv, 0.f);
        h[(size_t)(1 + row) * D_ + col] = vv;
        if (row < 256) h[(size_t)(20481 + row) * D_ + col] = vv;
      }
    }
}

__global__ void cls_kernel(const float* __restrict__ cls, float* __restrict__ h){
  int c = blockIdx.x * 256 + threadIdx.x;
  if (c < D_) h[c] = cls[c];
}

// ---------------- layernorm -> zero-padded bf16 xph ----------------
__global__ __launch_bounds__(256) void ln_pad_kernel(
    const float* __restrict__ h, const float* __restrict__ w,
    const float* __restrict__ b, unsigned short* __restrict__ xph){
  const int r = blockIdx.x;
  const int t = threadIdx.x;
  if (r < PADR){
    xph[(size_t)r * D_ + t] = 0;
    xph[(size_t)r * D_ + 256 + t] = 0;
    return;
  }
  __shared__ float s4[4];
  const float* x = h + (size_t)(r - PADR) * D_;
  float a0 = x[t], a1 = x[t + 256];
  float mu = blockSum256(a0 + a1, s4) * (1.f / 512.f);
  float d0 = a0 - mu, d1 = a1 - mu;
  float var = blockSum256(d0 * d0 + d1 * d1, s4) * (1.f / 512.f);
  float rs = rsqrtf(var + 1e-5f);
  xph[(size_t)r * D_ + t]       = f2bf(d0 * rs * w[t] + b[t]);
  xph[(size_t)r * D_ + 256 + t] = f2bf(d1 * rs * w[t + 256] + b[t + 256]);
}

// ---------------- qkv MFMA: q fp32, k/v bf16 head-major ----------------
__global__ __launch_bounds__(256) void qkv_mfma_kernel(
    const unsigned short* __restrict__ A, const unsigned short* __restrict__ Bt,
    float* __restrict__ q, unsigned short* __restrict__ k16,
    unsigned short* __restrict__ v16){
  __shared__ unsigned short As[64 * 40], Bs[64 * 40];
  f32x4 z4 = {0.f, 0.f, 0.f, 0.f};
  f32x4 acc[2][2] = {{z4, z4}, {z4, z4}};
  const int bm = blockIdx.x * 64, bn = blockIdx.y * 64;
  mfma_tile64(A, NP_, bm, Bt, bn, D_, acc, As, Bs);
  const int lane = threadIdx.x & 63, wave = threadIdx.x >> 6;
  const int wr = wave >> 1, wc = wave & 1;
  const int m16 = lane & 15, quad = lane >> 4;
#pragma unroll
  for (int mi = 0; mi < 2; mi++)
#pragma unroll
    for (int ni = 0; ni < 2; ni++){
      int col = bn + wc * 32 + ni * 16 + m16;
      int which = col >> 9, hh = (col >> 6) & 7, d = col & 63;
      size_t cbase = (size_t)hh * NP_ * HD_ + d;
#pragma unroll
      for (int r = 0; r < 4; r++){
        int row = bm + wr * 32 + mi * 16 + quad * 4 + r;
        float val = acc[mi][ni][r];
        if (which == 0)      q[cbase + (size_t)row * HD_] = val * 0.125f;
        else if (which == 1) k16[cbase + (size_t)row * HD_] = f2bf(val);
        else                 v16[cbase + (size_t)row * HD_] = f2bf(val);
      }
    }
}

// ---------------- landmarks: q fp32 + k bf16 -> ql/kl fp32, qlh bf16 ----------
__global__ __launch_bounds__(64) void landmark_kernel(
    const float* __restrict__ q, const unsigned short* __restrict__ k16,
    float* __restrict__ ql, float* __restrict__ kl,
    unsigned short* __restrict__ qlh){
  const int im = blockIdx.x, h = blockIdx.y, d = threadIdx.x;
  size_t base = ((size_t)h * NP_ + (size_t)im * LCH) * HD_ + d;
  float sq = 0.f, sk = 0.f;
  for (int r = 0; r < LCH; r++){
    sq += q[base + (size_t)r * HD_];
    sk += bfu(k16[base + (size_t)r * HD_]);
  }
  float qm = sq * (1.f / 82.f);
  ql[((size_t)h * MLM + im) * HD_ + d] = qm;
  qlh[((size_t)h * MLM + im) * HD_ + d] = f2bf(qm);
  kl[((size_t)h * MLM + im) * HD_ + d] = sk * (1.f / 82.f);
}

// ---------------- a2 = softmax(ql @ kl^T) ----------------
__global__ __launch_bounds__(256) void a2_kernel(
    const float* __restrict__ ql, const float* __restrict__ kl,
    float* __restrict__ a2){
  const int im = blockIdx.x, h = blockIdx.y, t = threadIdx.x;
  __shared__ __align__(16) float qs[64];
  __shared__ float s4[4];
  if (t < 64) qs[t] = ql[((size_t)h * MLM + im) * HD_ + t];
  __syncthreads();
  const float4* kr4 = (const float4*)(kl + ((size_t)h * MLM + t) * HD_);
  const float4* qs4 = (const float4*)qs;
  float s = 0.f;
#pragma unroll
  for (int d4 = 0; d4 < 16; d4++){
    float4 kv = kr4[d4], qv = qs4[d4];
    s += qv.x*kv.x + qv.y*kv.y + qv.z*kv.z + qv.w*kv.w;
  }
  float mx = blockMax256(s, s4);
  float e = __expf(s - mx);
  float S = blockSum256(e, s4);
  a2[((size_t)h * MLM + im) * MLM + t] = e / S;
}

// ---------------- pinv scaling ----------------
__global__ void zero2_kernel(unsigned int* p){ if (threadIdx.x < 2) p[threadIdx.x] = 0u; }

__global__ __launch_bounds__(256) void pinv_scale_kernel(
    const float* __restrict__ a2, unsigned int* __restrict__ scal){
  const int h = blockIdx.x, j = threadIdx.x;
  const float* A = a2 + (size_t)h * MLM * MLM;
  float rs = 0.f, cs = 0.f;
  for (int t = 0; t < MLM; t++){
    rs += fabsf(A[(size_t)j * MLM + t]);
    cs += fabsf(A[(size_t)t * MLM + j]);
  }
  __shared__ float s4[4];
  float rmax = blockMax256(rs, s4);
  float cmax = blockMax256(cs, s4);
  if (j == 0){
    atomicMax(&scal[0], __float_as_uint(rmax));
    atomicMax(&scal[1], __float_as_uint(cmax));
  }
}

__global__ __launch_bounds__(256) void pinv_init_kernel(
    const float* __restrict__ a2, const unsigned int* __restrict__ scal,
    float* __restrict__ z){
  const int i = blockIdx.x, h = blockIdx.y, j = threadIdx.x;
  float inv = 1.f / (__uint_as_float(scal[0]) * __uint_as_float(scal[1]));
  z[((size_t)h * MLM + i) * MLM + j] = a2[((size_t)h * MLM + j) * MLM + i] * inv;
}

// ---------------- batched 256x256x256 fp32 ----------------
__global__ __launch_bounds__(256) void bmm256_kernel(
    const float* __restrict__ Ab, const float* __restrict__ Bb,
    float* __restrict__ Cb, float c0, float sgn, float c1){
  const int h = blockIdx.z;
  const float* A = Ab + (size_t)h * 65536;
  const float* B = Bb + (size_t)h * 65536;
  float* C = Cb + (size_t)h * 65536;
  __shared__ float As[16][65];
  __shared__ float Bs[16][65];
  const int bm = blockIdx.x * 64, bn = blockIdx.y * 64;
  const int tid = threadIdx.y * 16 + threadIdx.x;
  float acc[4][4] = {};
  for (int k0 = 0; k0 < 256; k0 += 16){
#pragma unroll
    for (int r = 0; r < 4; r++){
      int e = tid + r * 256;
      int m = e >> 4, kk = e & 15;
      As[kk][m] = A[(size_t)(bm + m) * 256 + k0 + kk];
    }
#pragma unroll
    for (int r = 0; r < 4; r++){
      int e = tid + r * 256;
      int kk = e >> 6, n = e & 63;
      int gk = k0 + kk, gn = bn + n;
      float bv = sgn * B[(size_t)gk * 256 + gn];
      if (gk == gn) bv += c0;
      Bs[kk][n] = bv;
    }
    __syncthreads();
#pragma unroll
    for (int kk = 0; kk < 16; kk++){
      float a[4], b[4];
#pragma unroll
      for (int i = 0; i < 4; i++) a[i] = As[kk][threadIdx.y * 4 + i];
#pragma unroll
      for (int j = 0; j < 4; j++) b[j] = Bs[kk][threadIdx.x * 4 + j];
#pragma unroll
      for (int i = 0; i < 4; i++)
#pragma unroll
        for (int j = 0; j < 4; j++) acc[i][j] += a[i] * b[j];
    }
    __syncthreads();
  }
#pragma unroll
  for (int i = 0; i < 4; i++){
    int row = bm + threadIdx.y * 4 + i;
#pragma unroll
    for (int j = 0; j < 4; j++){
      int col = bn + threadIdx.x * 4 + j;
      C[(size_t)row * 256 + col] = c1 * acc[i][j];
    }
  }
}

// ---------------- a3v split-K flash, bf16 MFMA ----------------
// grid (4, 8, 41), block 256 (4 waves). Wave w owns landmark rows w*16..+15.
// Per 64-token subchunk: stage K rows + V^T in LDS (bf16); S = ql@K^T via
// mfma (bt-convention); online softmax in C-layout regs (row=quad*4+r,
// 16-lane shfl per quad); P->LDS bf16 (reuse K buf) as A-operand; PV via
// mfma with Bt=V^T. O accumulates in C-layout (same rows as S -> rescale ok).
__global__ __launch_bounds__(256) void a3v_part_kernel(
    const unsigned short* __restrict__ qlh, const unsigned short* __restrict__ k16,
    const unsigned short* __restrict__ v16, float* __restrict__ pacc,
    float* __restrict__ pml){
  __shared__ __align__(16) unsigned short qs16[64 * 72];
  __shared__ __align__(16) unsigned short kb16[64 * 72];   // K, then P
  __shared__ __align__(16) unsigned short vt16[64 * 72];   // V^T [d][n]
  const int lt = blockIdx.x, h = blockIdx.y, ch = blockIdx.z;
  const int t = threadIdx.x;
  const int lane = t & 63, w = t >> 6;
  const int m16 = lane & 15, quad = lane >> 4;

  const unsigned short* qg = qlh + ((size_t)h * MLM + lt * 64) * HD_;
  for (int idx = t; idx < 512; idx += 256){
    int row = idx >> 3, off = (idx & 7) * 8;
    *(uint4*)(qs16 + row * 72 + off) = *(const uint4*)(qg + (size_t)row * HD_ + off);
  }
  f32x4 z4 = {0.f, 0.f, 0.f, 0.f};
  f32x4 acc_o[4] = {z4, z4, z4, z4};
  float mreg[4], lreg[4];
#pragma unroll
  for (int r = 0; r < 4; r++){ mreg[r] = -3.0e38f; lreg[r] = 0.f; }
  const unsigned short* kg = k16 + ((size_t)h * NP_ + ch * CHTOK) * HD_;
  const unsigned short* vg = v16 + ((size_t)h * NP_ + ch * CHTOK) * HD_;

  for (int sc = 0; sc < 8; sc++){
    __syncthreads();
    for (int idx = t; idx < 512; idx += 256){
      int row = idx >> 3, off = (idx & 7) * 8;
      *(uint4*)(kb16 + row * 72 + off) =
          *(const uint4*)(kg + (size_t)(sc * 64 + row) * HD_ + off);
      uint4 pv = *(const uint4*)(vg + (size_t)(sc * 64 + row) * HD_ + off);
      unsigned int uu[4] = {pv.x, pv.y, pv.z, pv.w};
#pragma unroll
      for (int j = 0; j < 4; j++){
        vt16[(off + 2 * j)     * 72 + row] = (unsigned short)(uu[j] & 0xffffu);
        vt16[(off + 2 * j + 1) * 72 + row] = (unsigned short)(uu[j] >> 16);
      }
    }
    __syncthreads();
    // S = ql @ K^T  (M=16/wave, N=64, K=64)
    f32x4 acc_s[4] = {z4, z4, z4, z4};
#pragma unroll
    for (int kc = 0; kc < 64; kc += 32){
      bf16x8 a = *(const bf16x8*)(qs16 + (w * 16 + m16) * 72 + kc + quad * 8);
#pragma unroll
      for (int ni = 0; ni < 4; ni++){
        bf16x8 b = *(const bf16x8*)(kb16 + (ni * 16 + m16) * 72 + kc + quad * 8);
        acc_s[ni] = __builtin_amdgcn_mfma_f32_16x16x32_bf16(a, b, acc_s[ni], 0, 0, 0);
      }
    }
    __syncthreads();   // all waves done reading kb16 as K
    // online softmax per row (row = quad*4 + r), cols spread over 16 lanes x 4 ni
#pragma unroll
    for (int r = 0; r < 4; r++){
      float cm = fmaxf(fmaxf(acc_s[0][r], acc_s[1][r]), fmaxf(acc_s[2][r], acc_s[3][r]));
#pragma unroll
      for (int o = 1; o < 16; o <<= 1) cm = fmaxf(cm, __shfl_xor(cm, o));
      float mn = fmaxf(mreg[r], cm);
      float scl = __expf(mreg[r] - mn);
      float p0 = __expf(acc_s[0][r] - mn), p1 = __expf(acc_s[1][r] - mn);
      float p2 = __expf(acc_s[2][r] - mn), p3 = __expf(acc_s[3][r] - mn);
      float ls = (p0 + p1) + (p2 + p3);
#pragma unroll
      for (int o = 1; o < 16; o <<= 1) ls += __shfl_xor(ls, o);
      lreg[r] = lreg[r] * scl + ls;
      mreg[r] = mn;
      acc_o[0][r] *= scl; acc_o[1][r] *= scl;
      acc_o[2][r] *= scl; acc_o[3][r] *= scl;
      int prow = (w * 16 + quad * 4 + r) * 72 + m16;
      kb16[prow + 0]  = f2bf(p0);
      kb16[prow + 16] = f2bf(p1);
      kb16[prow + 32] = f2bf(p2);
      kb16[prow + 48] = f2bf(p3);
    }
    __syncthreads();
    // O += P @ V  (A = P rows of this wave, Bt = V^T)
#pragma unroll
    for (int kc = 0; kc < 64; kc += 32){
      bf16x8 a = *(const bf16x8*)(kb16 + (w * 16 + m16) * 72 + kc + quad * 8);
#pragma unroll
      for (int ni = 0; ni < 4; ni++){
        bf16x8 b = *(const bf16x8*)(vt16 + (ni * 16 + m16) * 72 + kc + quad * 8);
        acc_o[ni] = __builtin_amdgcn_mfma_f32_16x16x32_bf16(a, b, acc_o[ni], 0, 0, 0);
      }
    }
  }
#pragma unroll
  for (int r = 0; r < 4; r++){
    int im = lt * 64 + w * 16 + quad * 4 + r;
    size_t base = ((size_t)h * NCH + ch) * MLM + im;
#pragma unroll
    for (int ni = 0; ni < 4; ni++)
      pacc[base * HD_ + ni * 16 + m16] = acc_o[ni][r];
    if (m16 == 0){
      pml[base * 2]     = mreg[r];
      pml[base * 2 + 1] = lreg[r];
    }
  }
}

__global__ __launch_bounds__(64) void a3v_combine_kernel(
    const float* __restrict__ pacc, const float* __restrict__ pml,
    float* __restrict__ t1){
  const int im = blockIdx.x, h = blockIdx.y, lane = threadIdx.x;
  float M = -3.0e38f;
  for (int c = 0; c < NCH; c++)
    M = fmaxf(M, pml[(((size_t)h * NCH + c) * MLM + im) * 2]);
  float accv = 0.f, L = 0.f;
  for (int c = 0; c < NCH; c++){
    size_t base = ((size_t)h * NCH + c) * MLM + im;
    float mc = pml[base * 2], lc = pml[base * 2 + 1];
    float w = __expf(mc - M);
    accv += w * pacc[base * HD_ + lane];
    L += w * lc;
  }
  t1[((size_t)h * MLM + im) * HD_ + lane] = accv / L;
}

// ---------------- t2 = z @ t1 ----------------
__global__ __launch_bounds__(256) void zt1_kernel(
    const float* __restrict__ z, const float* __restrict__ t1,
    float* __restrict__ t2){
  const int h = blockIdx.y;
  const int t = threadIdx.x;
  const int d = t & 63, ri = t >> 6;
  const int im = blockIdx.x * 4 + ri;
  const float* zr = z + ((size_t)h * MLM + im) * MLM;
  const float* t1h = t1 + (size_t)h * MLM * HD_;
  float acc = 0.f;
#pragma unroll 8
  for (int kk = 0; kk < MLM; kk++) acc += zr[kk] * t1h[(size_t)kk * HD_ + d];
  t2[((size_t)h * MLM + im) * HD_ + d] = acc;
}

// ---------------- out tile: 32 tokens x 1 head per block -> bf16 outh ----------
__global__ __launch_bounds__(256) void out_tile_kernel(
    const float* __restrict__ q, const float* __restrict__ kl,
    const float* __restrict__ t2, const unsigned short* __restrict__ v16,
    const float* __restrict__ resw, unsigned short* __restrict__ outh){
  __shared__ float qs[32][68];
  __shared__ float buf[64][68];
  __shared__ float Ps[32][260];
  const int h = blockIdx.y;
  const int tile = blockIdx.x;
  const int n0 = PADR + tile * 32;
  const int t = threadIdx.x;
  const int tx = t & 15, ty = t >> 4;
  {
    const float* qh = q + (size_t)h * NP_ * HD_;
    for (int idx = t; idx < 512; idx += 256){
      int row = idx >> 4, q4 = idx & 15;
      int n = n0 + row;
      float4 val = make_float4(0.f, 0.f, 0.f, 0.f);
      if (n < NP_) val = *(const float4*)(qh + (size_t)n * HD_ + q4 * 4);
      *(float4*)(&qs[row][q4 * 4]) = val;
    }
  }
  float s[2][16];
#pragma unroll
  for (int i = 0; i < 2; i++)
#pragma unroll
    for (int u = 0; u < 16; u++) s[i][u] = 0.f;
  const float* klh = kl + (size_t)h * MLM * HD_;
  for (int m = 0; m < 4; m++){
    __syncthreads();
    for (int idx = t; idx < 1024; idx += 256){
      int row = idx >> 4, q4 = idx & 15;
      *(float4*)(&buf[row][q4 * 4]) =
          *(const float4*)(klh + (size_t)(m * 64 + row) * HD_ + q4 * 4);
    }
    __syncthreads();
#pragma unroll
    for (int k4 = 0; k4 < 16; k4++){
      float4 q0 = *(const float4*)(&qs[2 * ty + 0][k4 * 4]);
      float4 q1 = *(const float4*)(&qs[2 * ty + 1][k4 * 4]);
#pragma unroll
      for (int jj = 0; jj < 4; jj++){
        float4 kv = *(const float4*)(&buf[tx + 16 * jj][k4 * 4]);
        s[0][m * 4 + jj] += q0.x*kv.x + q0.y*kv.y + q0.z*kv.z + q0.w*kv.w;
        s[1][m * 4 + jj] += q1.x*kv.x + q1.y*kv.y + q1.z*kv.z + q1.w*kv.w;
      }
    }
  }
#pragma unroll
  for (int i = 0; i < 2; i++){
    float mx = -3.0e38f;
#pragma unroll
    for (int u = 0; u < 16; u++) mx = fmaxf(mx, s[i][u]);
#pragma unroll
    for (int o = 1; o < 16; o <<= 1) mx = fmaxf(mx, __shfl_xor(mx, o));
    float sum = 0.f;
#pragma unroll
    for (int u = 0; u < 16; u++){ s[i][u] = __expf(s[i][u] - mx); sum += s[i][u]; }
#pragma unroll
    for (int o = 1; o < 16; o <<= 1) sum += __shfl_xor(sum, o);
    float inv = 1.f / sum;
#pragma unroll
    for (int u = 0; u < 16; u++) s[i][u] *= inv;
  }
#pragma unroll
  for (int i = 0; i < 2; i++)
#pragma unroll
    for (int mm = 0; mm < 4; mm++)
#pragma unroll
      for (int jj = 0; jj < 4; jj++)
        Ps[2 * ty + i][mm * 64 + jj * 16 + tx] = s[i][mm * 4 + jj];

  float o_[2][4] = {};
  const float* t2h = t2 + (size_t)h * MLM * HD_;
  for (int kc = 0; kc < 4; kc++){
    __syncthreads();
    for (int idx = t; idx < 1024; idx += 256){
      int row = idx >> 4, q4 = idx & 15;
      *(float4*)(&buf[row][q4 * 4]) =
          *(const float4*)(t2h + (size_t)(kc * 64 + row) * HD_ + q4 * 4);
    }
    __syncthreads();
#pragma unroll
    for (int k4 = 0; k4 < 16; k4++){
      float4 p0 = *(const float4*)(&Ps[2 * ty + 0][kc * 64 + k4 * 4]);
      float4 p1 = *(const float4*)(&Ps[2 * ty + 1][kc * 64 + k4 * 4]);
      float pa[4] = {p0.x, p0.y, p0.z, p0.w};
      float pb[4] = {p1.x, p1.y, p1.z, p1.w};
#pragma unroll
      for (int i = 0; i < 4; i++){
        float4 tv = *(const float4*)(&buf[k4 * 4 + i][tx * 4]);
        o_[0][0] += pa[i] * tv.x; o_[0][1] += pa[i] * tv.y;
        o_[0][2] += pa[i] * tv.z; o_[0][3] += pa[i] * tv.w;
        o_[1][0] += pb[i] * tv.x; o_[1][1] += pb[i] * tv.y;
        o_[1][2] += pb[i] * tv.z; o_[1][3] += pb[i] * tv.w;
      }
    }
  }
  __syncthreads();
  {
    const unsigned short* vh = v16 + (size_t)h * NP_ * HD_;
    for (int idx = t; idx < 512; idx += 256){
      int row = idx >> 3, d0 = (idx & 7) * 8;
      int nn = n0 - 16 + row;
      if (nn < NP_){
        uint4 pk = *(const uint4*)(vh + (size_t)nn * HD_ + d0);
        unsigned int uu[4] = {pk.x, pk.y, pk.z, pk.w};
#pragma unroll
        for (int j = 0; j < 4; j++){
          buf[row][d0 + 2 * j]     = __uint_as_float(uu[j] << 16);
          buf[row][d0 + 2 * j + 1] = __uint_as_float(uu[j] & 0xffff0000u);
        }
      } else {
#pragma unroll
        for (int j = 0; j < 8; j++) buf[row][d0 + j] = 0.f;
      }
    }
  }
  __syncthreads();
  float wreg[33];
  {
    const float* wr = resw + h * 33;
#pragma unroll
    for (int kk = 0; kk < 33; kk++) wreg[kk] = wr[kk];
  }
#pragma unroll
  for (int i = 0; i < 2; i++){
    float4 cacc = make_float4(0.f, 0.f, 0.f, 0.f);
    for (int kk = 0; kk < 33; kk++){
      float4 vv = *(const float4*)(&buf[2 * ty + i + kk][tx * 4]);
      float w = wreg[kk];
      cacc.x += vv.x * w; cacc.y += vv.y * w;
      cacc.z += vv.z * w; cacc.w += vv.w * w;
    }
    int nrow = tile * 32 + 2 * ty + i;
    if (nrow < NTOK){
      unsigned long long pk =
          (unsigned long long)f2bf(o_[i][0] + cacc.x)
        | ((unsigned long long)f2bf(o_[i][1] + cacc.y) << 16)
        | ((unsigned long long)f2bf(o_[i][2] + cacc.z) << 32)
        | ((unsigned long long)f2bf(o_[i][3] + cacc.w) << 48);
      *(unsigned long long*)(outh + (size_t)nrow * D_ + h * HD_ + tx * 4) = pk;
    }
  }
}

// ---------------- proj MFMA: h += outh @ out_wt^T + bias ----------------
__global__ __launch_bounds__(256) void proj_mfma_kernel(
    const unsigned short* __restrict__ A, const unsigned short* __restrict__ Bt,
    const float* __restrict__ bias, float* __restrict__ h){
  __shared__ unsigned short As[64 * 40], Bs[64 * 40];
  f32x4 z4 = {0.f, 0.f, 0.f, 0.f};
  f32x4 acc[2][2] = {{z4, z4}, {z4, z4}};
  const int bm = blockIdx.x * 64, bn = blockIdx.y * 64;
  mfma_tile64(A, NTOK, bm, Bt, bn, D_, acc, As, Bs);
  const int lane = threadIdx.x & 63, wave = threadIdx.x >> 6;
  const int wr = wave >> 1, wc = wave & 1;
  const int m16 = lane & 15, quad = lane >> 4;
#pragma unroll
  for (int mi = 0; mi < 2; mi++)
#pragma unroll
    for (int ni = 0; ni < 2; ni++){
      int col = bn + wc * 32 + ni * 16 + m16;
      float bv = bias[col];
#pragma unroll
      for (int r = 0; r < 4; r++){
        int row = bm + wr * 32 + mi * 16 + quad * 4 + r;
        if (row < NTOK) h[(size_t)row * D_ + col] += acc[mi][ni][r] + bv;
      }
    }
}

// ---------------- PPEG ----------------
__global__ __launch_bounds__(512) void ppeg_combine_kernel(
    const float* __restrict__ w7, const float* __restrict__ b7,
    const float* __restrict__ w5, const float* __restrict__ b5,
    const float* __restrict__ w3, const float* __restrict__ b3,
    float* __restrict__ wcomb, float* __restrict__ bcomb){
  const int c = threadIdx.x;
#pragma unroll
  for (int i = 0; i < 7; i++){
#pragma unroll
    for (int j = 0; j < 7; j++){
      int di = i - 3, dj = j - 3;
      float wv = w7[(size_t)c * 49 + i * 7 + j];
      if (di >= -2 && di <= 2 && dj >= -2 && dj <= 2)
        wv += w5[(size_t)c * 25 + (di + 2) * 5 + (dj + 2)];
      if (di >= -1 && di <= 1 && dj >= -1 && dj <= 1)
        wv += w3[(size_t)c * 9 + (di + 1) * 3 + (dj + 1)];
      if (di == 0 && dj == 0) wv += 1.f;
      wcomb[(size_t)(i * 7 + j) * 512 + c] = wv;
    }
  }
  bcomb[c] = b7[c] + b5[c] + b3[c];
}

__global__ __launch_bounds__(512) void ppeg_conv_kernel(
    const float* __restrict__ h, const float* __restrict__ wcomb,
    const float* __restrict__ bcomb, float* __restrict__ tmp){
  const int c = threadIdx.x;
  const int y = blockIdx.y;
  const int x0 = blockIdx.x * 8;
  float wc[49];
#pragma unroll
  for (int kk = 0; kk < 49; kk++) wc[kk] = wcomb[(size_t)kk * 512 + c];
  float acc[8];
  const float bv = bcomb[c];
#pragma unroll
  for (int p = 0; p < 8; p++) acc[p] = bv;
#pragma unroll
  for (int i = 0; i < 7; i++){
    const int yy = y + i - 3;
    if (yy < 0 || yy >= HHW) continue;
    const float* hrow = h + (size_t)(1 + yy * HHW) * D_ + c;
    float line[14];
#pragma unroll
    for (int j = 0; j < 14; j++){
      const int xx = x0 + j - 3;
      line[j] = (xx >= 0 && xx < HHW) ? hrow[(size_t)xx * D_] : 0.f;
    }
#pragma unroll
    for (int p = 0; p < 8; p++)
#pragma unroll
      for (int j = 0; j < 7; j++)
        acc[p] += line[p + j] * wc[i * 7 + j];
  }
#pragma unroll
  for (int p = 0; p < 8; p++)
    tmp[(size_t)(y * HHW + x0 + p) * D_ + c] = acc[p];
}

__global__ void ppeg_copy_kernel(const float* __restrict__ tmp, float* __restrict__ h){
  size_t idx = (size_t)blockIdx.x * 256 + threadIdx.x;
  if (idx < (size_t)NFEAT * D_) h[idx + D_] = tmp[idx];
}

// ---------------- final ----------------
__global__ __launch_bounds__(512) void final_kernel(
    const float* __restrict__ h, const float* __restrict__ w,
    const float* __restrict__ b, const float* __restrict__ fc3w,
    const float* __restrict__ fc3b, float* __restrict__ out){
  __shared__ float vec[512];
  __shared__ float s8[8];
  __shared__ float lg[4];
  const int t = threadIdx.x;
  float x = h[t];
  float v = waveSumF(x);
  if ((t & 63) == 0) s8[t >> 6] = v;
  __syncthreads();
  float sum = 0.f;
#pragma unroll
  for (int i = 0; i < 8; i++) sum += s8[i];
  float mu = sum * (1.f / 512.f);
  __syncthreads();
  float d = x - mu;
  v = waveSumF(d * d);
  if ((t & 63) == 0) s8[t >> 6] = v;
  __syncthreads();
  float var = 0.f;
#pragma unroll
  for (int i = 0; i < 8; i++) var += s8[i];
  var *= (1.f / 512.f);
  float rs = rsqrtf(var + 1e-5f);
  vec[t] = d * rs * w[t] + b[t];
  __syncthreads();
  if (t < 4){
    float acc = fc3b[t];
    for (int kk = 0; kk < 512; kk++) acc += vec[kk] * fc3w[kk * 4 + t];
    lg[t] = acc;
  }
  __syncthreads();
  if (t == 0){
    float m = fmaxf(fmaxf(lg[0], lg[1]), fmaxf(lg[2], lg[3]));
    float e[4], se = 0.f;
#pragma unroll
    for (int i = 0; i < 4; i++){ e[i] = __expf(lg[i] - m); se += e[i]; }
    int am = 0; float bm = lg[0];
#pragma unroll
    for (int i = 1; i < 4; i++) if (lg[i] > bm){ bm = lg[i]; am = i; }
#pragma unroll
    for (int i = 0; i < 4; i++){ out[i] = lg[i]; out[4 + i] = e[i] / se; }
    out[8] = (float)am;
  }
}

// ---------------------------------------------------------------------------
extern "C" void kernel_launch(void* const* d_in, const int* in_sizes, int n_in,
                              void* d_out, int out_size, void* d_ws, size_t ws_size,
                              hipStream_t stream) {
  const float* x       = (const float*)d_in[0];
  const float* fc1_w   = (const float*)d_in[1];
  const float* fc1_b   = (const float*)d_in[2];
  const float* cls_tok = (const float*)d_in[3];
  const float* l1_nw   = (const float*)d_in[4];
  const float* l1_nb   = (const float*)d_in[5];
  const float* l1_qkvw = (const float*)d_in[6];
  const float* l1_outw = (const float*)d_in[7];
  const float* l1_outb = (const float*)d_in[8];
  const float* l1_resw = (const float*)d_in[9];
  const float* ppeg_w7 = (const float*)d_in[10];
  const float* ppeg_b7 = (const float*)d_in[11];
  const float* ppeg_w5 = (const float*)d_in[12];
  const float* ppeg_b5 = (const float*)d_in[13];
  const float* ppeg_w3 = (const float*)d_in[14];
  const float* ppeg_b3 = (const float*)d_in[15];
  const float* l2_nw   = (const float*)d_in[16];
  const float* l2_nb   = (const float*)d_in[17];
  const float* l2_qkvw = (const float*)d_in[18];
  const float* l2_outw = (const float*)d_in[19];
  const float* l2_outb = (const float*)d_in[20];
  const float* l2_resw = (const float*)d_in[21];
  const float* norm_w  = (const float*)d_in[22];
  const float* norm_b  = (const float*)d_in[23];
  const float* fc3_w   = (const float*)d_in[24];
  const float* fc3_b   = (const float*)d_in[25];

  // workspace layout (float units)
  float* W = (float*)d_ws;
  size_t o = 0;
  float* hbuf = W + o; o += (size_t)NTOK * D_;
  float* xp   = W + o; o += (size_t)NP_ * D_;   // xph / pacc+pml / outh / ppeg tmp
  float* qb   = W + o; o += (size_t)NH_ * NP_ * HD_;   // fp32 q; also Ah pre-layer
  float* kb   = W + o; o += (size_t)NH_ * NP_ * HD_;   // used as bf16 k
  float* vb   = W + o; o += (size_t)NH_ * NP_ * HD_;   // used as bf16 v
  float* qlb  = W + o; o += (size_t)NH_ * MLM * HD_;
  float* klb  = W + o; o += (size_t)NH_ * MLM * HD_;
  float* a2b  = W + o; o += (size_t)NH_ * MLM * MLM;
  float* z0   = W + o; o += (size_t)NH_ * MLM * MLM;
  float* z1   = W + o; o += (size_t)NH_ * MLM * MLM;
  float* ta   = W + o; o += (size_t)NH_ * MLM * MLM;
  float* tb   = W + o; o += (size_t)NH_ * MLM * MLM;
  float* tc   = W + o; o += (size_t)NH_ * MLM * MLM;
  float* t1b  = W + o; o += (size_t)NH_ * MLM * HD_;
  float* t2b  = W + o; o += (size_t)NH_ * MLM * HD_;
  unsigned int* scal = (unsigned int*)(W + o); o += 16;
  float* wcomb = W + o; o += 49 * 512;
  float* bcomb = W + o; o += 512;
  unsigned short* fc1_wt  = (unsigned short*)(W + o); o += (size_t)D_ * E_ / 2;
  unsigned short* qkv_wt1 = (unsigned short*)(W + o); o += (size_t)1536 * D_ / 2;
  unsigned short* qkv_wt2 = (unsigned short*)(W + o); o += (size_t)1536 * D_ / 2;
  unsigned short* out_wt1 = (unsigned short*)(W + o); o += (size_t)D_ * D_ / 2;
  unsigned short* out_wt2 = (unsigned short*)(W + o); o += (size_t)D_ * D_ / 2;
  unsigned short* qlh = (unsigned short*)(W + o); o += (size_t)NH_ * MLM * HD_ / 2;

  unsigned short* xph = (unsigned short*)xp;
  float* pacc = xp;
  float* pml  = xp + (size_t)NH_ * NCH * MLM * HD_;
  unsigned short* outh = (unsigned short*)xp;
  unsigned short* Ah = (unsigned short*)qb;
  unsigned short* k16 = (unsigned short*)kb;
  unsigned short* v16 = (unsigned short*)vb;

  // ---- weight prep (once per launch) ----
  wtrans_kernel<<<dim3(E_ / 32, D_ / 32), dim3(32, 8), 0, stream>>>(fc1_w, fc1_wt, E_, D_);
  wtrans_kernel<<<dim3(D_ / 32, 1536 / 32), dim3(32, 8), 0, stream>>>(l1_qkvw, qkv_wt1, D_, 1536);
  wtrans_kernel<<<dim3(D_ / 32, 1536 / 32), dim3(32, 8), 0, stream>>>(l2_qkvw, qkv_wt2, D_, 1536);
  wtrans_kernel<<<dim3(D_ / 32, D_ / 32), dim3(32, 8), 0, stream>>>(l1_outw, out_wt1, D_, D_);
  wtrans_kernel<<<dim3(D_ / 32, D_ / 32), dim3(32, 8), 0, stream>>>(l2_outw, out_wt2, D_, D_);
  ppeg_combine_kernel<<<1, 512, 0, stream>>>(ppeg_w7, ppeg_b7, ppeg_w5, ppeg_b5,
                                             ppeg_w3, ppeg_b3, wcomb, bcomb);

  // ---- fc1 (maxpool -> bf16 -> MFMA) ----
  pool_bf16_kernel<<<20480, 256, 0, stream>>>(x, Ah);
  fc1_mfma_kernel<<<dim3(320, 8), 256, 0, stream>>>(Ah, fc1_wt, fc1_b, hbuf);
  cls_kernel<<<2, 256, 0, stream>>>(cls_tok, hbuf);

  auto run_layer = [&](const float* nw, const float* nb,
                       const unsigned short* qkvwt, const unsigned short* outwt,
                       const float* outb, const float* resw){
    ln_pad_kernel<<<NP_, 256, 0, stream>>>(hbuf, nw, nb, xph);
    qkv_mfma_kernel<<<dim3(328, 24), 256, 0, stream>>>(xph, qkvwt, qb, k16, v16);
    landmark_kernel<<<dim3(256, 8), 64, 0, stream>>>(qb, k16, qlb, klb, qlh);
    a2_kernel<<<dim3(256, 8), 256, 0, stream>>>(qlb, klb, a2b);
    zero2_kernel<<<1, 64, 0, stream>>>(scal);
    pinv_scale_kernel<<<8, 256, 0, stream>>>(a2b, scal);
    pinv_init_kernel<<<dim3(256, 8), 256, 0, stream>>>(a2b, scal, z0);
    float* zc = z0; float* za = z1;
    for (int it = 0; it < 6; it++){
      bmm256_kernel<<<dim3(4, 4, 8), dim3(16, 16), 0, stream>>>(a2b, zc, ta, 0.f, 1.f, 1.f);
      bmm256_kernel<<<dim3(4, 4, 8), dim3(16, 16), 0, stream>>>(ta, ta, tb, 7.f, -1.f, 1.f);
      bmm256_kernel<<<dim3(4, 4, 8), dim3(16, 16), 0, stream>>>(ta, tb, tc, 15.f, -1.f, 1.f);
      bmm256_kernel<<<dim3(4, 4, 8), dim3(16, 16), 0, stream>>>(zc, tc, za, 13.f, -1.f, 0.25f);
      float* tswap = zc; zc = za; za = tswap;
    }
    a3v_part_kernel<<<dim3(4, 8, NCH), 256, 0, stream>>>(qlh, k16, v16, pacc, pml);
    a3v_combine_kernel<<<dim3(256, 8), 64, 0, stream>>>(pacc, pml, t1b);
    zt1_kernel<<<dim3(64, 8), 256, 0, stream>>>(zc, t1b, t2b);
    out_tile_kernel<<<dim3(649, 8), 256, 0, stream>>>(qb, klb, t2b, v16, resw, outh);
    proj_mfma_kernel<<<dim3(325, 8), 256, 0, stream>>>(outh, outwt, outb, hbuf);
  };

  run_layer(l1_nw, l1_nb, qkv_wt1, out_wt1, l1_outb, l1_resw);
  ppeg_conv_kernel<<<dim3(HHW / 8, HHW), 512, 0, stream>>>(hbuf, wcomb, bcomb, xp);
  ppeg_copy_kernel<<<(NFEAT * D_ + 255) / 256, 256, 0, stream>>>(xp, hbuf);
  run_layer(l2_nw, l2_nb, qkv_wt2, out_wt2, l2_outb, l2_resw);
  final_kernel<<<1, 512, 0, stream>>>(hbuf, norm_w, norm_b, fc3_w, fc3_b, (float*)d_out);
}

// Round 7
// 1735.362 us; speedup vs baseline: 7.4883x; 1.7432x over previous
//
#include <hip/hip_runtime.h>

// ---------------------------------------------------------------------------
// TransMIL forward on MI355X.
//   r0: 12995 us baseline (all-fp32, classic 64x64 tiled GEMMs).
//   r1: 10182 us — PPEG collapsed to one combined 7x7 depthwise conv.
//   r2:  8278 us — out_kernel rewritten as fused 32-token tile kernel.
//   r3:  5546 us — a3v rewritten as split-K flash attention.
//   r4:  3723 us — fc1/qkv/proj GEMMs -> bf16 MFMA (16x16x32).
//   r5:  3025 us — a3v_part -> bf16 MFMA flash.
//   r6: out_tile -> bf16 MFMA (64-token tiles, t2 transposed bf16, q bf16);
//       bmm256 -> split-bf16 (hi/lo) MFMA, ~fp32 accuracy at MFMA rate.
// ---------------------------------------------------------------------------

constexpr int D_    = 512;
constexpr int E_    = 1024;
constexpr int NTOK  = 20737;
constexpr int NP_   = 20992;   // padded seq len (255 zero rows at FRONT)
constexpr int NH_   = 8;
constexpr int HD_   = 64;
constexpr int MLM   = 256;     // landmarks
constexpr int LCH   = 82;      // tokens per landmark
constexpr int HHW   = 144;
constexpr int NFEAT = 20736;   // 144*144
constexpr int PADR  = 255;
constexpr int NCH   = 41;      // a3v N-chunks
constexpr int CHTOK = 512;     // tokens per chunk (8 subchunks of 64)

typedef __attribute__((ext_vector_type(8))) short bf16x8;
typedef __attribute__((ext_vector_type(4))) float f32x4;

__device__ __forceinline__ unsigned short f2bf(float f){
  unsigned int u = __float_as_uint(f);
  unsigned int r = u + 0x7fffu + ((u >> 16) & 1u);
  return (unsigned short)(r >> 16);
}
__device__ __forceinline__ float bfu(unsigned short u){
  return __uint_as_float((unsigned int)u << 16);
}

// ---------------- reduction helpers ----------------
__device__ __forceinline__ float waveMaxF(float v){
#pragma unroll
  for (int o = 32; o > 0; o >>= 1) v = fmaxf(v, __shfl_xor(v, o));
  return v;
}
__device__ __forceinline__ float waveSumF(float v){
#pragma unroll
  for (int o = 32; o > 0; o >>= 1) v += __shfl_xor(v, o);
  return v;
}
__device__ __forceinline__ float blockMax256(float v, float* sbuf){
  v = waveMaxF(v);
  if ((threadIdx.x & 63) == 0) sbuf[threadIdx.x >> 6] = v;
  __syncthreads();
  float r = fmaxf(fmaxf(sbuf[0], sbuf[1]), fmaxf(sbuf[2], sbuf[3]));
  __syncthreads();
  return r;
}
__device__ __forceinline__ float blockSum256(float v, float* sbuf){
  v = waveSumF(v);
  if ((threadIdx.x & 63) == 0) sbuf[threadIdx.x >> 6] = v;
  __syncthreads();
  float r = sbuf[0] + sbuf[1] + sbuf[2] + sbuf[3];
  __syncthreads();
  return r;
}

// ---------------- weight prep: W[K][N] fp32 -> Wt[N][K] bf16 ----------------
__global__ __launch_bounds__(256) void wtrans_kernel(
    const float* __restrict__ W, unsigned short* __restrict__ Wt, int K, int N){
  __shared__ float tile[32][33];
  const int kb = blockIdx.x * 32, nb = blockIdx.y * 32;
  const int tx = threadIdx.x, ty = threadIdx.y;
  for (int i = ty; i < 32; i += 8) tile[i][tx] = W[(size_t)(kb + i) * N + nb + tx];
  __syncthreads();
  for (int i = ty; i < 32; i += 8)
    Wt[(size_t)(nb + i) * K + kb + tx] = f2bf(tile[tx][i]);
}

// ---------------- maxpool2 + bf16 ----------------
__global__ __launch_bounds__(256) void pool_bf16_kernel(
    const float* __restrict__ x, unsigned short* __restrict__ Ah){
  size_t idx4 = ((size_t)blockIdx.x * 256 + threadIdx.x) * 4;
  size_t m = idx4 >> 10, e = idx4 & 1023;
  float4 a = *(const float4*)(x + (m * 2) * E_ + e);
  float4 b = *(const float4*)(x + (m * 2 + 1) * E_ + e);
  unsigned long long pk =
      (unsigned long long)f2bf(fmaxf(a.x, b.x))
    | ((unsigned long long)f2bf(fmaxf(a.y, b.y)) << 16)
    | ((unsigned long long)f2bf(fmaxf(a.z, b.z)) << 32)
    | ((unsigned long long)f2bf(fmaxf(a.w, b.w)) << 48);
  *(unsigned long long*)(Ah + idx4) = pk;
}

// ---------------- MFMA 64x64 tile core (bf16 in, fp32 acc) ----------------
__device__ __forceinline__ void mfma_tile64(
    const unsigned short* __restrict__ A, int arows, int bm,
    const unsigned short* __restrict__ Bt, int bn, int K,
    f32x4 acc[2][2], unsigned short* As, unsigned short* Bs){
  const int t = threadIdx.x;
  const int lane = t & 63, wave = t >> 6;
  const int wr = wave >> 1, wc = wave & 1;
  const int m16 = lane & 15, quad = lane >> 4;
  const int srow = t >> 2, scol = (t & 3) * 8;
  for (int kc = 0; kc < K; kc += 32){
    {
      int ga = bm + srow;
      ulonglong2 av = {0ull, 0ull};
      if (ga < arows) av = *(const ulonglong2*)(A + (size_t)ga * K + kc + scol);
      *(ulonglong2*)(As + srow * 40 + scol) = av;
      ulonglong2 bv = *(const ulonglong2*)(Bt + (size_t)(bn + srow) * K + kc + scol);
      *(ulonglong2*)(Bs + srow * 40 + scol) = bv;
    }
    __syncthreads();
    bf16x8 a0 = *(const bf16x8*)(As + (wr * 32 + m16) * 40 + quad * 8);
    bf16x8 a1 = *(const bf16x8*)(As + (wr * 32 + 16 + m16) * 40 + quad * 8);
    bf16x8 b0 = *(const bf16x8*)(Bs + (wc * 32 + m16) * 40 + quad * 8);
    bf16x8 b1 = *(const bf16x8*)(Bs + (wc * 32 + 16 + m16) * 40 + quad * 8);
    acc[0][0] = __builtin_amdgcn_mfma_f32_16x16x32_bf16(a0, b0, acc[0][0], 0, 0, 0);
    acc[0][1] = __builtin_amdgcn_mfma_f32_16x16x32_bf16(a0, b1, acc[0][1], 0, 0, 0);
    acc[1][0] = __builtin_amdgcn_mfma_f32_16x16x32_bf16(a1, b0, acc[1][0], 0, 0, 0);
    acc[1][1] = __builtin_amdgcn_mfma_f32_16x16x32_bf16(a1, b1, acc[1][1], 0, 0, 0);
    __syncthreads();
  }
}

// ---------------- fc1 ----------------
__global__ __launch_bounds__(256) void fc1_mfma_kernel(
    const unsigned short* __restrict__ Ah, const unsigned short* __restrict__ Bt,
    const float* __restrict__ bias, float* __restrict__ h){
  __shared__ unsigned short As[64 * 40], Bs[64 * 40];
  f32x4 z4 = {0.f, 0.f, 0.f, 0.f};
  f32x4 acc[2][2] = {{z4, z4}, {z4, z4}};
  const int bm = blockIdx.x * 64, bn = blockIdx.y * 64;
  mfma_tile64(Ah, 20480, bm, Bt, bn, E_, acc, As, Bs);
  const int lane = threadIdx.x & 63, wave = threadIdx.x >> 6;
  const int wr = wave >> 1, wc = wave & 1;
  const int m16 = lane & 15, quad = lane >> 4;
#pragma unroll
  for (int mi = 0; mi < 2; mi++)
#pragma unroll
    for (int ni = 0; ni < 2; ni++){
      int col = bn + wc * 32 + ni * 16 + m16;
      float bv = bias[col];
#pragma unroll
      for (int r = 0; r < 4; r++){
        int row = bm + wr * 32 + mi * 16 + quad * 4 + r;
        float vv = fmaxf(acc[mi][ni][r] + bv, 0.f);
        h[(size_t)(1 + row) * D_ + col] = vv;
        if (row < 256) h[(size_t)(20481 + row) * D_ + col] = vv;
      }
    }
}

__global__ void cls_kernel(const float* __restrict__ cls, float* __restrict__ h){
  int c = blockIdx.x * 256 + threadIdx.x;
  if (c < D_) h[c] = cls[c];
}

// ---------------- layernorm -> zero-padded bf16 xph ----------------
__global__ __launch_bounds__(256) void ln_pad_kernel(
    const float* __restrict__ h, const float* __restrict__ w,
    const float* __restrict__ b, unsigned short* __restrict__ xph){
  const int r = blockIdx.x;
  const int t = threadIdx.x;
  if (r < PADR){
    xph[(size_t)r * D_ + t] = 0;
    xph[(size_t)r * D_ + 256 + t] = 0;
    return;
  }
  __shared__ float s4[4];
  const float* x = h + (size_t)(r - PADR) * D_;
  float a0 = x[t], a1 = x[t + 256];
  float mu = blockSum256(a0 + a1, s4) * (1.f / 512.f);
  float d0 = a0 - mu, d1 = a1 - mu;
  float var = blockSum256(d0 * d0 + d1 * d1, s4) * (1.f / 512.f);
  float rs = rsqrtf(var + 1e-5f);
  xph[(size_t)r * D_ + t]       = f2bf(d0 * rs * w[t] + b[t]);
  xph[(size_t)r * D_ + 256 + t] = f2bf(d1 * rs * w[t + 256] + b[t + 256]);
}

// ---------------- qkv MFMA: q/k/v all bf16 head-major (q scaled 1/8) ----------
__global__ __launch_bounds__(256) void qkv_mfma_kernel(
    const unsigned short* __restrict__ A, const unsigned short* __restrict__ Bt,
    unsigned short* __restrict__ q16, unsigned short* __restrict__ k16,
    unsigned short* __restrict__ v16){
  __shared__ unsigned short As[64 * 40], Bs[64 * 40];
  f32x4 z4 = {0.f, 0.f, 0.f, 0.f};
  f32x4 acc[2][2] = {{z4, z4}, {z4, z4}};
  const int bm = blockIdx.x * 64, bn = blockIdx.y * 64;
  mfma_tile64(A, NP_, bm, Bt, bn, D_, acc, As, Bs);
  const int lane = threadIdx.x & 63, wave = threadIdx.x >> 6;
  const int wr = wave >> 1, wc = wave & 1;
  const int m16 = lane & 15, quad = lane >> 4;
#pragma unroll
  for (int mi = 0; mi < 2; mi++)
#pragma unroll
    for (int ni = 0; ni < 2; ni++){
      int col = bn + wc * 32 + ni * 16 + m16;
      int which = col >> 9, hh = (col >> 6) & 7, d = col & 63;
      size_t cbase = (size_t)hh * NP_ * HD_ + d;
      unsigned short* dst;
      float sc = 1.f;
      if (which == 0){ dst = q16; sc = 0.125f; }
      else if (which == 1) dst = k16;
      else dst = v16;
#pragma unroll
      for (int r = 0; r < 4; r++){
        int row = bm + wr * 32 + mi * 16 + quad * 4 + r;
        dst[cbase + (size_t)row * HD_] = f2bf(acc[mi][ni][r] * sc);
      }
    }
}

// ---------------- landmarks: bf16 q/k -> ql/kl fp32 + qlh/klh bf16 ----------
__global__ __launch_bounds__(64) void landmark_kernel(
    const unsigned short* __restrict__ q16, const unsigned short* __restrict__ k16,
    float* __restrict__ ql, float* __restrict__ kl,
    unsigned short* __restrict__ qlh, unsigned short* __restrict__ klh){
  const int im = blockIdx.x, h = blockIdx.y, d = threadIdx.x;
  size_t base = ((size_t)h * NP_ + (size_t)im * LCH) * HD_ + d;
  float sq = 0.f, sk = 0.f;
  for (int r = 0; r < LCH; r++){
    sq += bfu(q16[base + (size_t)r * HD_]);
    sk += bfu(k16[base + (size_t)r * HD_]);
  }
  float qm = sq * (1.f / 82.f), km = sk * (1.f / 82.f);
  size_t oidx = ((size_t)h * MLM + im) * HD_ + d;
  ql[oidx] = qm;  qlh[oidx] = f2bf(qm);
  kl[oidx] = km;  klh[oidx] = f2bf(km);
}

// ---------------- a2 = softmax(ql @ kl^T) ----------------
__global__ __launch_bounds__(256) void a2_kernel(
    const float* __restrict__ ql, const float* __restrict__ kl,
    float* __restrict__ a2){
  const int im = blockIdx.x, h = blockIdx.y, t = threadIdx.x;
  __shared__ __align__(16) float qs[64];
  __shared__ float s4[4];
  if (t < 64) qs[t] = ql[((size_t)h * MLM + im) * HD_ + t];
  __syncthreads();
  const float4* kr4 = (const float4*)(kl + ((size_t)h * MLM + t) * HD_);
  const float4* qs4 = (const float4*)qs;
  float s = 0.f;
#pragma unroll
  for (int d4 = 0; d4 < 16; d4++){
    float4 kv = kr4[d4], qv = qs4[d4];
    s += qv.x*kv.x + qv.y*kv.y + qv.z*kv.z + qv.w*kv.w;
  }
  float mx = blockMax256(s, s4);
  float e = __expf(s - mx);
  float S = blockSum256(e, s4);
  a2[((size_t)h * MLM + im) * MLM + t] = e / S;
}

// ---------------- pinv scaling ----------------
__global__ void zero2_kernel(unsigned int* p){ if (threadIdx.x < 2) p[threadIdx.x] = 0u; }

__global__ __launch_bounds__(256) void pinv_scale_kernel(
    const float* __restrict__ a2, unsigned int* __restrict__ scal){
  const int h = blockIdx.x, j = threadIdx.x;
  const float* A = a2 + (size_t)h * MLM * MLM;
  float rs = 0.f, cs = 0.f;
  for (int t = 0; t < MLM; t++){
    rs += fabsf(A[(size_t)j * MLM + t]);
    cs += fabsf(A[(size_t)t * MLM + j]);
  }
  __shared__ float s4[4];
  float rmax = blockMax256(rs, s4);
  float cmax = blockMax256(cs, s4);
  if (j == 0){
    atomicMax(&scal[0], __float_as_uint(rmax));
    atomicMax(&scal[1], __float_as_uint(cmax));
  }
}

__global__ __launch_bounds__(256) void pinv_init_kernel(
    const float* __restrict__ a2, const unsigned int* __restrict__ scal,
    float* __restrict__ z){
  const int i = blockIdx.x, h = blockIdx.y, j = threadIdx.x;
  float inv = 1.f / (__uint_as_float(scal[0]) * __uint_as_float(scal[1]));
  z[((size_t)h * MLM + i) * MLM + j] = a2[((size_t)h * MLM + j) * MLM + i] * inv;
}

// ---------------- batched 256^3: C = c1*(A @ (c0*I + sgn*B)), split-bf16 MFMA --
// hi/lo two-term split: A*B ~= Ah*Bh + Ah*Bl + Al*Bh (error ~2^-16 rel).
// grid (4,4,8), block 256 (4 waves).
__global__ __launch_bounds__(256) void bmm256_mfma_kernel(
    const float* __restrict__ Ab, const float* __restrict__ Bb,
    float* __restrict__ Cb, float c0, float sgn, float c1){
  __shared__ unsigned short Ash[64 * 40], Asl[64 * 40];
  __shared__ unsigned short Bsh[64 * 40], Bsl[64 * 40];
  const int h = blockIdx.z;
  const float* A = Ab + (size_t)h * 65536;
  const float* B = Bb + (size_t)h * 65536;
  float* C = Cb + (size_t)h * 65536;
  const int bm = blockIdx.x * 64, bn = blockIdx.y * 64;
  const int t = threadIdx.x, lane = t & 63, w = t >> 6;
  const int wr = w >> 1, wc = w & 1, m16 = lane & 15, quad = lane >> 4;
  f32x4 z4 = {0.f, 0.f, 0.f, 0.f};
  f32x4 acc[2][2] = {{z4, z4}, {z4, z4}};
  for (int kc = 0; kc < 256; kc += 32){
    {
      // A rows (row-major): row = t>>2, cols kc + (t&3)*8 .. +7
      int row = t >> 2, c8 = (t & 3) * 8;
      const float* src = A + (size_t)(bm + row) * 256 + kc + c8;
      float xs[8];
      *(float4*)(xs)     = *(const float4*)src;
      *(float4*)(xs + 4) = *(const float4*)(src + 4);
#pragma unroll
      for (int j = 0; j < 8; j++){
        unsigned short hi = f2bf(xs[j]);
        Ash[row * 40 + c8 + j] = hi;
        Asl[row * 40 + c8 + j] = f2bf(xs[j] - bfu(hi));
      }
      // B rows k (row-major), store TRANSPOSED: Bs[n][k]
      int k = t >> 3, n8 = (t & 7) * 8;
      const float* bsrc = B + (size_t)(kc + k) * 256 + bn + n8;
      float ys[8];
      *(float4*)(ys)     = *(const float4*)bsrc;
      *(float4*)(ys + 4) = *(const float4*)(bsrc + 4);
#pragma unroll
      for (int j = 0; j < 8; j++){
        float xv = sgn * ys[j];
        if (kc + k == bn + n8 + j) xv += c0;
        unsigned short hi = f2bf(xv);
        Bsh[(n8 + j) * 40 + k] = hi;
        Bsl[(n8 + j) * 40 + k] = f2bf(xv - bfu(hi));
      }
    }
    __syncthreads();
    bf16x8 ah[2], al[2], bh[2], bl[2];
#pragma unroll
    for (int mi = 0; mi < 2; mi++){
      ah[mi] = *(const bf16x8*)(Ash + (wr * 32 + mi * 16 + m16) * 40 + quad * 8);
      al[mi] = *(const bf16x8*)(Asl + (wr * 32 + mi * 16 + m16) * 40 + quad * 8);
      bh[mi] = *(const bf16x8*)(Bsh + (wc * 32 + mi * 16 + m16) * 40 + quad * 8);
      bl[mi] = *(const bf16x8*)(Bsl + (wc * 32 + mi * 16 + m16) * 40 + quad * 8);
    }
#pragma unroll
    for (int mi = 0; mi < 2; mi++)
#pragma unroll
      for (int ni = 0; ni < 2; ni++){
        acc[mi][ni] = __builtin_amdgcn_mfma_f32_16x16x32_bf16(ah[mi], bh[ni], acc[mi][ni], 0, 0, 0);
        acc[mi][ni] = __builtin_amdgcn_mfma_f32_16x16x32_bf16(ah[mi], bl[ni], acc[mi][ni], 0, 0, 0);
        acc[mi][ni] = __builtin_amdgcn_mfma_f32_16x16x32_bf16(al[mi], bh[ni], acc[mi][ni], 0, 0, 0);
      }
    __syncthreads();
  }
#pragma unroll
  for (int mi = 0; mi < 2; mi++)
#pragma unroll
    for (int ni = 0; ni < 2; ni++)
#pragma unroll
      for (int r = 0; r < 4; r++){
        int row = bm + wr * 32 + mi * 16 + quad * 4 + r;
        int col = bn + wc * 32 + ni * 16 + m16;
        C[(size_t)row * 256 + col] = c1 * acc[mi][ni][r];
      }
}

// ---------------- a3v split-K flash, bf16 MFMA ----------------
__global__ __launch_bounds__(256) void a3v_part_kernel(
    const unsigned short* __restrict__ qlh, const unsigned short* __restrict__ k16,
    const unsigned short* __restrict__ v16, float* __restrict__ pacc,
    float* __restrict__ pml){
  __shared__ __align__(16) unsigned short qs16[64 * 72];
  __shared__ __align__(16) unsigned short kb16[64 * 72];   // K, then P
  __shared__ __align__(16) unsigned short vt16[64 * 72];   // V^T [d][n]
  const int lt = blockIdx.x, h = blockIdx.y, ch = blockIdx.z;
  const int t = threadIdx.x;
  const int lane = t & 63, w = t >> 6;
  const int m16 = lane & 15, quad = lane >> 4;

  const unsigned short* qg = qlh + ((size_t)h * MLM + lt * 64) * HD_;
  for (int idx = t; idx < 512; idx += 256){
    int row = idx >> 3, off = (idx & 7) * 8;
    *(uint4*)(qs16 + row * 72 + off) = *(const uint4*)(qg + (size_t)row * HD_ + off);
  }
  f32x4 z4 = {0.f, 0.f, 0.f, 0.f};
  f32x4 acc_o[4] = {z4, z4, z4, z4};
  float mreg[4], lreg[4];
#pragma unroll
  for (int r = 0; r < 4; r++){ mreg[r] = -3.0e38f; lreg[r] = 0.f; }
  const unsigned short* kg = k16 + ((size_t)h * NP_ + ch * CHTOK) * HD_;
  const unsigned short* vg = v16 + ((size_t)h * NP_ + ch * CHTOK) * HD_;

  for (int sc = 0; sc < 8; sc++){
    __syncthreads();
    for (int idx = t; idx < 512; idx += 256){
      int row = idx >> 3, off = (idx & 7) * 8;
      *(uint4*)(kb16 + row * 72 + off) =
          *(const uint4*)(kg + (size_t)(sc * 64 + row) * HD_ + off);
      uint4 pv = *(const uint4*)(vg + (size_t)(sc * 64 + row) * HD_ + off);
      unsigned int uu[4] = {pv.x, pv.y, pv.z, pv.w};
#pragma unroll
      for (int j = 0; j < 4; j++){
        vt16[(off + 2 * j)     * 72 + row] = (unsigned short)(uu[j] & 0xffffu);
        vt16[(off + 2 * j + 1) * 72 + row] = (unsigned short)(uu[j] >> 16);
      }
    }
    __syncthreads();
    f32x4 acc_s[4] = {z4, z4, z4, z4};
#pragma unroll
    for (int kc = 0; kc < 64; kc += 32){
      bf16x8 a = *(const bf16x8*)(qs16 + (w * 16 + m16) * 72 + kc + quad * 8);
#pragma unroll
      for (int ni = 0; ni < 4; ni++){
        bf16x8 b = *(const bf16x8*)(kb16 + (ni * 16 + m16) * 72 + kc + quad * 8);
        acc_s[ni] = __builtin_amdgcn_mfma_f32_16x16x32_bf16(a, b, acc_s[ni], 0, 0, 0);
      }
    }
    __syncthreads();
#pragma unroll
    for (int r = 0; r < 4; r++){
      float cm = fmaxf(fmaxf(acc_s[0][r], acc_s[1][r]), fmaxf(acc_s[2][r], acc_s[3][r]));
#pragma unroll
      for (int o = 1; o < 16; o <<= 1) cm = fmaxf(cm, __shfl_xor(cm, o));
      float mn = fmaxf(mreg[r], cm);
      float scl = __expf(mreg[r] - mn);
      float p0 = __expf(acc_s[0][r] - mn), p1 = __expf(acc_s[1][r] - mn);
      float p2 = __expf(acc_s[2][r] - mn), p3 = __expf(acc_s[3][r] - mn);
      float ls = (p0 + p1) + (p2 + p3);
#pragma unroll
      for (int o = 1; o < 16; o <<= 1) ls += __shfl_xor(ls, o);
      lreg[r] = lreg[r] * scl + ls;
      mreg[r] = mn;
      acc_o[0][r] *= scl; acc_o[1][r] *= scl;
      acc_o[2][r] *= scl; acc_o[3][r] *= scl;
      int prow = (w * 16 + quad * 4 + r) * 72 + m16;
      kb16[prow + 0]  = f2bf(p0);
      kb16[prow + 16] = f2bf(p1);
      kb16[prow + 32] = f2bf(p2);
      kb16[prow + 48] = f2bf(p3);
    }
    __syncthreads();
#pragma unroll
    for (int kc = 0; kc < 64; kc += 32){
      bf16x8 a = *(const bf16x8*)(kb16 + (w * 16 + m16) * 72 + kc + quad * 8);
#pragma unroll
      for (int ni = 0; ni < 4; ni++){
        bf16x8 b = *(const bf16x8*)(vt16 + (ni * 16 + m16) * 72 + kc + quad * 8);
        acc_o[ni] = __builtin_amdgcn_mfma_f32_16x16x32_bf16(a, b, acc_o[ni], 0, 0, 0);
      }
    }
  }
#pragma unroll
  for (int r = 0; r < 4; r++){
    int im = lt * 64 + w * 16 + quad * 4 + r;
    size_t base = ((size_t)h * NCH + ch) * MLM + im;
#pragma unroll
    for (int ni = 0; ni < 4; ni++)
      pacc[base * HD_ + ni * 16 + m16] = acc_o[ni][r];
    if (m16 == 0){
      pml[base * 2]     = mreg[r];
      pml[base * 2 + 1] = lreg[r];
    }
  }
}

__global__ __launch_bounds__(64) void a3v_combine_kernel(
    const float* __restrict__ pacc, const float* __restrict__ pml,
    float* __restrict__ t1){
  const int im = blockIdx.x, h = blockIdx.y, lane = threadIdx.x;
  float M = -3.0e38f;
  for (int c = 0; c < NCH; c++)
    M = fmaxf(M, pml[(((size_t)h * NCH + c) * MLM + im) * 2]);
  float accv = 0.f, L = 0.f;
  for (int c = 0; c < NCH; c++){
    size_t base = ((size_t)h * NCH + c) * MLM + im;
    float mc = pml[base * 2], lc = pml[base * 2 + 1];
    float w = __expf(mc - M);
    accv += w * pacc[base * HD_ + lane];
    L += w * lc;
  }
  t1[((size_t)h * MLM + im) * HD_ + lane] = accv / L;
}

// ---------------- t2^T = (z @ t1)^T, bf16 [h][d][im] ----------------
__global__ __launch_bounds__(256) void zt1_kernel(
    const float* __restrict__ z, const float* __restrict__ t1,
    unsigned short* __restrict__ t2t){
  const int h = blockIdx.y;
  const int t = threadIdx.x;
  const int d = t & 63, ri = t >> 6;
  const int im = blockIdx.x * 4 + ri;
  const float* zr = z + ((size_t)h * MLM + im) * MLM;
  const float* t1h = t1 + (size_t)h * MLM * HD_;
  float acc = 0.f;
#pragma unroll 8
  for (int kk = 0; kk < MLM; kk++) acc += zr[kk] * t1h[(size_t)kk * HD_ + d];
  t2t[((size_t)h * HD_ + d) * MLM + im] = f2bf(acc);
}

// ---------------- out tile MFMA: 64 tokens x 1 head per block ----------------
// S = q16 @ klh^T (4 chunks), exact softmax in C-layout regs, P->LDS bf16,
// O = P @ t2 via t2t (B-operand), epilogue via LDS round-trip + conv33 + store.
__global__ __launch_bounds__(256) void out_tile_kernel(
    const unsigned short* __restrict__ q16, const unsigned short* __restrict__ klh,
    const unsigned short* __restrict__ t2t, const unsigned short* __restrict__ v16,
    const float* __restrict__ resw, unsigned short* __restrict__ outh){
  __shared__ __align__(16) unsigned short smem[64 * 72 * 2 + 64 * 264];
  unsigned short* qs16 = smem;                 // 64 x 72
  unsigned short* kb16 = smem + 64 * 72;       // 64 x 72 (kl chunks, t2t chunks)
  unsigned short* Ps   = smem + 64 * 72 * 2;   // 64 x 264 (P bf16; later O f32 + v tile)
  const int tile = blockIdx.x, h = blockIdx.y;
  const int n0 = PADR + tile * 64;
  const int t = threadIdx.x;
  const int lane = t & 63, w = t >> 6;
  const int m16 = lane & 15, quad = lane >> 4;

  // stage q tile (64 x 64 bf16), zero-guarded
  {
    const unsigned short* qh = q16 + (size_t)h * NP_ * HD_;
    for (int idx = t; idx < 512; idx += 256){
      int row = idx >> 3, off = (idx & 7) * 8;
      int n = n0 + row;
      uint4 val = {0u, 0u, 0u, 0u};
      if (n < NP_) val = *(const uint4*)(qh + (size_t)n * HD_ + off);
      *(uint4*)(qs16 + row * 72 + off) = val;
    }
  }
  // S phase: acc_s[16], cols mc*16+m16 with mc = m*4+ni
  f32x4 z4 = {0.f, 0.f, 0.f, 0.f};
  f32x4 acc_s[16];
#pragma unroll
  for (int i = 0; i < 16; i++) acc_s[i] = z4;
  const unsigned short* klg = klh + (size_t)h * MLM * HD_;
  for (int m = 0; m < 4; m++){
    __syncthreads();
    for (int idx = t; idx < 512; idx += 256){
      int row = idx >> 3, off = (idx & 7) * 8;
      *(uint4*)(kb16 + row * 72 + off) =
          *(const uint4*)(klg + (size_t)(m * 64 + row) * HD_ + off);
    }
    __syncthreads();
#pragma unroll
    for (int kc = 0; kc < 64; kc += 32){
      bf16x8 a = *(const bf16x8*)(qs16 + (w * 16 + m16) * 72 + kc + quad * 8);
#pragma unroll
      for (int ni = 0; ni < 4; ni++){
        bf16x8 b = *(const bf16x8*)(kb16 + (ni * 16 + m16) * 72 + kc + quad * 8);
        acc_s[m * 4 + ni] = __builtin_amdgcn_mfma_f32_16x16x32_bf16(a, b, acc_s[m * 4 + ni], 0, 0, 0);
      }
    }
  }
  __syncthreads();
  // exact softmax per row (row = w*16 + quad*4 + r); write P bf16 to Ps
#pragma unroll
  for (int r = 0; r < 4; r++){
    float mx = acc_s[0][r];
#pragma unroll
    for (int mc = 1; mc < 16; mc++) mx = fmaxf(mx, acc_s[mc][r]);
#pragma unroll
    for (int o = 1; o < 16; o <<= 1) mx = fmaxf(mx, __shfl_xor(mx, o));
    float p[16]; float sum = 0.f;
#pragma unroll
    for (int mc = 0; mc < 16; mc++){ p[mc] = __expf(acc_s[mc][r] - mx); sum += p[mc]; }
#pragma unroll
    for (int o = 1; o < 16; o <<= 1) sum += __shfl_xor(sum, o);
    float inv = 1.f / sum;
    int prow = (w * 16 + quad * 4 + r) * 264;
#pragma unroll
    for (int mc = 0; mc < 16; mc++)
      Ps[prow + (mc >> 2) * 64 + (mc & 3) * 16 + m16] = f2bf(p[mc] * inv);
  }
  // PV phase: O = P @ t2 via t2t chunks
  f32x4 acc_o[4] = {z4, z4, z4, z4};
  const unsigned short* t2g = t2t + (size_t)h * HD_ * MLM;
  for (int ch = 0; ch < 4; ch++){
    __syncthreads();
    {
      int row = t >> 2, c8 = (t & 3) * 16;
      const unsigned short* src = t2g + (size_t)row * MLM + ch * 64 + c8;
      *(uint4*)(kb16 + row * 72 + c8)     = *(const uint4*)src;
      *(uint4*)(kb16 + row * 72 + c8 + 8) = *(const uint4*)(src + 8);
    }
    __syncthreads();
#pragma unroll
    for (int kc = 0; kc < 64; kc += 32){
      bf16x8 a = *(const bf16x8*)(Ps + (w * 16 + m16) * 264 + ch * 64 + kc + quad * 8);
#pragma unroll
      for (int ni = 0; ni < 4; ni++){
        bf16x8 b = *(const bf16x8*)(kb16 + (ni * 16 + m16) * 72 + kc + quad * 8);
        acc_o[ni] = __builtin_amdgcn_mfma_f32_16x16x32_bf16(a, b, acc_o[ni], 0, 0, 0);
      }
    }
  }
  __syncthreads();   // all Ps reads done before overwrite
  // epilogue: O -> LDS fp32 (Ps area), v tile bf16 (after O area)
  float* Obuf = (float*)Ps;                          // 64 x 66 f32
  unsigned short* vtile = (unsigned short*)(Obuf + 64 * 66);  // 96 x 72 bf16
#pragma unroll
  for (int r = 0; r < 4; r++){
    int row = w * 16 + quad * 4 + r;
#pragma unroll
    for (int ni = 0; ni < 4; ni++)
      Obuf[row * 66 + ni * 16 + m16] = acc_o[ni][r];
  }
  {
    const unsigned short* vh = v16 + (size_t)h * NP_ * HD_;
    for (int idx = t; idx < 768; idx += 256){
      int row = idx >> 3, off = (idx & 7) * 8;
      int nn = n0 - 16 + row;
      uint4 val = {0u, 0u, 0u, 0u};
      if (nn < NP_) val = *(const uint4*)(vh + (size_t)nn * HD_ + off);
      *(uint4*)(vtile + row * 72 + off) = val;
    }
  }
  __syncthreads();
  float wreg[33];
  {
    const float* wr = resw + h * 33;
#pragma unroll
    for (int kk = 0; kk < 33; kk++) wreg[kk] = wr[kk];
  }
  const int ty = t >> 4, tx = t & 15;
#pragma unroll
  for (int i = 0; i < 4; i++){
    int lrow = ty * 4 + i;
    float c0v = 0.f, c1v = 0.f, c2v = 0.f, c3v = 0.f;
    for (int kk = 0; kk < 33; kk++){
      uint2 uv = *(const uint2*)(vtile + (lrow + kk) * 72 + tx * 4);
      float wv = wreg[kk];
      c0v += __uint_as_float(uv.x << 16) * wv;
      c1v += __uint_as_float(uv.x & 0xffff0000u) * wv;
      c2v += __uint_as_float(uv.y << 16) * wv;
      c3v += __uint_as_float(uv.y & 0xffff0000u) * wv;
    }
    int trow = tile * 64 + lrow;
    if (trow < NTOK){
      const float* orow = Obuf + lrow * 66 + tx * 4;
      unsigned long long pk =
          (unsigned long long)f2bf(orow[0] + c0v)
        | ((unsigned long long)f2bf(orow[1] + c1v) << 16)
        | ((unsigned long long)f2bf(orow[2] + c2v) << 32)
        | ((unsigned long long)f2bf(orow[3] + c3v) << 48);
      *(unsigned long long*)(outh + (size_t)trow * D_ + h * HD_ + tx * 4) = pk;
    }
  }
}

// ---------------- proj MFMA: h += outh @ out_wt^T + bias ----------------
__global__ __launch_bounds__(256) void proj_mfma_kernel(
    const unsigned short* __restrict__ A, const unsigned short* __restrict__ Bt,
    const float* __restrict__ bias, float* __restrict__ h){
  __shared__ unsigned short As[64 * 40], Bs[64 * 40];
  f32x4 z4 = {0.f, 0.f, 0.f, 0.f};
  f32x4 acc[2][2] = {{z4, z4}, {z4, z4}};
  const int bm = blockIdx.x * 64, bn = blockIdx.y * 64;
  mfma_tile64(A, NTOK, bm, Bt, bn, D_, acc, As, Bs);
  const int lane = threadIdx.x & 63, wave = threadIdx.x >> 6;
  const int wr = wave >> 1, wc = wave & 1;
  const int m16 = lane & 15, quad = lane >> 4;
#pragma unroll
  for (int mi = 0; mi < 2; mi++)
#pragma unroll
    for (int ni = 0; ni < 2; ni++){
      int col = bn + wc * 32 + ni * 16 + m16;
      float bv = bias[col];
#pragma unroll
      for (int r = 0; r < 4; r++){
        int row = bm + wr * 32 + mi * 16 + quad * 4 + r;
        if (row < NTOK) h[(size_t)row * D_ + col] += acc[mi][ni][r] + bv;
      }
    }
}

// ---------------- PPEG ----------------
__global__ __launch_bounds__(512) void ppeg_combine_kernel(
    const float* __restrict__ w7, const float* __restrict__ b7,
    const float* __restrict__ w5, const float* __restrict__ b5,
    const float* __restrict__ w3, const float* __restrict__ b3,
    float* __restrict__ wcomb, float* __restrict__ bcomb){
  const int c = threadIdx.x;
#pragma unroll
  for (int i = 0; i < 7; i++){
#pragma unroll
    for (int j = 0; j < 7; j++){
      int di = i - 3, dj = j - 3;
      float wv = w7[(size_t)c * 49 + i * 7 + j];
      if (di >= -2 && di <= 2 && dj >= -2 && dj <= 2)
        wv += w5[(size_t)c * 25 + (di + 2) * 5 + (dj + 2)];
      if (di >= -1 && di <= 1 && dj >= -1 && dj <= 1)
        wv += w3[(size_t)c * 9 + (di + 1) * 3 + (dj + 1)];
      if (di == 0 && dj == 0) wv += 1.f;
      wcomb[(size_t)(i * 7 + j) * 512 + c] = wv;
    }
  }
  bcomb[c] = b7[c] + b5[c] + b3[c];
}

__global__ __launch_bounds__(512) void ppeg_conv_kernel(
    const float* __restrict__ h, const float* __restrict__ wcomb,
    const float* __restrict__ bcomb, float* __restrict__ tmp){
  const int c = threadIdx.x;
  const int y = blockIdx.y;
  const int x0 = blockIdx.x * 8;
  float wc[49];
#pragma unroll
  for (int kk = 0; kk < 49; kk++) wc[kk] = wcomb[(size_t)kk * 512 + c];
  float acc[8];
  const float bv = bcomb[c];
#pragma unroll
  for (int p = 0; p < 8; p++) acc[p] = bv;
#pragma unroll
  for (int i = 0; i < 7; i++){
    const int yy = y + i - 3;
    if (yy < 0 || yy >= HHW) continue;
    const float* hrow = h + (size_t)(1 + yy * HHW) * D_ + c;
    float line[14];
#pragma unroll
    for (int j = 0; j < 14; j++){
      const int xx = x0 + j - 3;
      line[j] = (xx >= 0 && xx < HHW) ? hrow[(size_t)xx * D_] : 0.f;
    }
#pragma unroll
    for (int p = 0; p < 8; p++)
#pragma unroll
      for (int j = 0; j < 7; j++)
        acc[p] += line[p + j] * wc[i * 7 + j];
  }
#pragma unroll
  for (int p = 0; p < 8; p++)
    tmp[(size_t)(y * HHW + x0 + p) * D_ + c] = acc[p];
}

__global__ void ppeg_copy_kernel(const float* __restrict__ tmp, float* __restrict__ h){
  size_t idx = (size_t)blockIdx.x * 256 + threadIdx.x;
  if (idx < (size_t)NFEAT * D_) h[idx + D_] = tmp[idx];
}

// ---------------- final ----------------
__global__ __launch_bounds__(512) void final_kernel(
    const float* __restrict__ h, const float* __restrict__ w,
    const float* __restrict__ b, const float* __restrict__ fc3w,
    const float* __restrict__ fc3b, float* __restrict__ out){
  __shared__ float vec[512];
  __shared__ float s8[8];
  __shared__ float lg[4];
  const int t = threadIdx.x;
  float x = h[t];
  float v = waveSumF(x);
  if ((t & 63) == 0) s8[t >> 6] = v;
  __syncthreads();
  float sum = 0.f;
#pragma unroll
  for (int i = 0; i < 8; i++) sum += s8[i];
  float mu = sum * (1.f / 512.f);
  __syncthreads();
  float d = x - mu;
  v = waveSumF(d * d);
  if ((t & 63) == 0) s8[t >> 6] = v;
  __syncthreads();
  float var = 0.f;
#pragma unroll
  for (int i = 0; i < 8; i++) var += s8[i];
  var *= (1.f / 512.f);
  float rs = rsqrtf(var + 1e-5f);
  vec[t] = d * rs * w[t] + b[t];
  __syncthreads();
  if (t < 4){
    float acc = fc3b[t];
    for (int kk = 0; kk < 512; kk++) acc += vec[kk] * fc3w[kk * 4 + t];
    lg[t] = acc;
  }
  __syncthreads();
  if (t == 0){
    float m = fmaxf(fmaxf(lg[0], lg[1]), fmaxf(lg[2], lg[3]));
    float e[4], se = 0.f;
#pragma unroll
    for (int i = 0; i < 4; i++){ e[i] = __expf(lg[i] - m); se += e[i]; }
    int am = 0; float bm = lg[0];
#pragma unroll
    for (int i = 1; i < 4; i++) if (lg[i] > bm){ bm = lg[i]; am = i; }
#pragma unroll
    for (int i = 0; i < 4; i++){ out[i] = lg[i]; out[4 + i] = e[i] / se; }
    out[8] = (float)am;
  }
}

// ---------------------------------------------------------------------------
extern "C" void kernel_launch(void* const* d_in, const int* in_sizes, int n_in,
                              void* d_out, int out_size, void* d_ws, size_t ws_size,
                              hipStream_t stream) {
  const float* x       = (const float*)d_in[0];
  const float* fc1_w   = (const float*)d_in[1];
  const float* fc1_b   = (const float*)d_in[2];
  const float* cls_tok = (const float*)d_in[3];
  const float* l1_nw   = (const float*)d_in[4];
  const float* l1_nb   = (const float*)d_in[5];
  const float* l1_qkvw = (const float*)d_in[6];
  const float* l1_outw = (const float*)d_in[7];
  const float* l1_outb = (const float*)d_in[8];
  const float* l1_resw = (const float*)d_in[9];
  const float* ppeg_w7 = (const float*)d_in[10];
  const float* ppeg_b7 = (const float*)d_in[11];
  const float* ppeg_w5 = (const float*)d_in[12];
  const float* ppeg_b5 = (const float*)d_in[13];
  const float* ppeg_w3 = (const float*)d_in[14];
  const float* ppeg_b3 = (const float*)d_in[15];
  const float* l2_nw   = (const float*)d_in[16];
  const float* l2_nb   = (const float*)d_in[17];
  const float* l2_qkvw = (const float*)d_in[18];
  const float* l2_outw = (const float*)d_in[19];
  const float* l2_outb = (const float*)d_in[20];
  const float* l2_resw = (const float*)d_in[21];
  const float* norm_w  = (const float*)d_in[22];
  const float* norm_b  = (const float*)d_in[23];
  const float* fc3_w   = (const float*)d_in[24];
  const float* fc3_b   = (const float*)d_in[25];

  // workspace layout (float units)
  float* W = (float*)d_ws;
  size_t o = 0;
  float* hbuf = W + o; o += (size_t)NTOK * D_;
  float* xp   = W + o; o += (size_t)NP_ * D_;   // xph / pacc+pml / outh / ppeg tmp
  float* qb   = W + o; o += (size_t)NH_ * NP_ * HD_;   // bf16 q; also Ah pre-layer
  float* kb   = W + o; o += (size_t)NH_ * NP_ * HD_;   // bf16 k
  float* vb   = W + o; o += (size_t)NH_ * NP_ * HD_;   // bf16 v
  float* qlb  = W + o; o += (size_t)NH_ * MLM * HD_;
  float* klb  = W + o; o += (size_t)NH_ * MLM * HD_;
  float* a2b  = W + o; o += (size_t)NH_ * MLM * MLM;
  float* z0   = W + o; o += (size_t)NH_ * MLM * MLM;
  float* z1   = W + o; o += (size_t)NH_ * MLM * MLM;
  float* ta   = W + o; o += (size_t)NH_ * MLM * MLM;
  float* tb   = W + o; o += (size_t)NH_ * MLM * MLM;
  float* tc   = W + o; o += (size_t)NH_ * MLM * MLM;
  float* t1b  = W + o; o += (size_t)NH_ * MLM * HD_;
  float* t2r  = W + o; o += (size_t)NH_ * MLM * HD_;   // t2t bf16 lives here
  unsigned int* scal = (unsigned int*)(W + o); o += 16;
  float* wcomb = W + o; o += 49 * 512;
  float* bcomb = W + o; o += 512;
  unsigned short* fc1_wt  = (unsigned short*)(W + o); o += (size_t)D_ * E_ / 2;
  unsigned short* qkv_wt1 = (unsigned short*)(W + o); o += (size_t)1536 * D_ / 2;
  unsigned short* qkv_wt2 = (unsigned short*)(W + o); o += (size_t)1536 * D_ / 2;
  unsigned short* out_wt1 = (unsigned short*)(W + o); o += (size_t)D_ * D_ / 2;
  unsigned short* out_wt2 = (unsigned short*)(W + o); o += (size_t)D_ * D_ / 2;
  unsigned short* qlh = (unsigned short*)(W + o); o += (size_t)NH_ * MLM * HD_ / 2;
  unsigned short* klh = (unsigned short*)(W + o); o += (size_t)NH_ * MLM * HD_ / 2;

  unsigned short* xph = (unsigned short*)xp;
  float* pacc = xp;
  float* pml  = xp + (size_t)NH_ * NCH * MLM * HD_;
  unsigned short* outh = (unsigned short*)xp;
  unsigned short* Ah  = (unsigned short*)qb;
  unsigned short* q16 = (unsigned short*)qb;
  unsigned short* k16 = (unsigned short*)kb;
  unsigned short* v16 = (unsigned short*)vb;
  unsigned short* t2t = (unsigned short*)t2r;

  // ---- weight prep (once per launch) ----
  wtrans_kernel<<<dim3(E_ / 32, D_ / 32), dim3(32, 8), 0, stream>>>(fc1_w, fc1_wt, E_, D_);
  wtrans_kernel<<<dim3(D_ / 32, 1536 / 32), dim3(32, 8), 0, stream>>>(l1_qkvw, qkv_wt1, D_, 1536);
  wtrans_kernel<<<dim3(D_ / 32, 1536 / 32), dim3(32, 8), 0, stream>>>(l2_qkvw, qkv_wt2, D_, 1536);
  wtrans_kernel<<<dim3(D_ / 32, D_ / 32), dim3(32, 8), 0, stream>>>(l1_outw, out_wt1, D_, D_);
  wtrans_kernel<<<dim3(D_ / 32, D_ / 32), dim3(32, 8), 0, stream>>>(l2_outw, out_wt2, D_, D_);
  ppeg_combine_kernel<<<1, 512, 0, stream>>>(ppeg_w7, ppeg_b7, ppeg_w5, ppeg_b5,
                                             ppeg_w3, ppeg_b3, wcomb, bcomb);

  // ---- fc1 (maxpool -> bf16 -> MFMA) ----
  pool_bf16_kernel<<<20480, 256, 0, stream>>>(x, Ah);
  fc1_mfma_kernel<<<dim3(320, 8), 256, 0, stream>>>(Ah, fc1_wt, fc1_b, hbuf);
  cls_kernel<<<2, 256, 0, stream>>>(cls_tok, hbuf);

  auto run_layer = [&](const float* nw, const float* nb,
                       const unsigned short* qkvwt, const unsigned short* outwt,
                       const float* outb, const float* resw){
    ln_pad_kernel<<<NP_, 256, 0, stream>>>(hbuf, nw, nb, xph);
    qkv_mfma_kernel<<<dim3(328, 24), 256, 0, stream>>>(xph, qkvwt, q16, k16, v16);
    landmark_kernel<<<dim3(256, 8), 64, 0, stream>>>(q16, k16, qlb, klb, qlh, klh);
    a2_kernel<<<dim3(256, 8), 256, 0, stream>>>(qlb, klb, a2b);
    zero2_kernel<<<1, 64, 0, stream>>>(scal);
    pinv_scale_kernel<<<8, 256, 0, stream>>>(a2b, scal);
    pinv_init_kernel<<<dim3(256, 8), 256, 0, stream>>>(a2b, scal, z0);
    float* zc = z0; float* za = z1;
    for (int it = 0; it < 6; it++){
      bmm256_mfma_kernel<<<dim3(4, 4, 8), 256, 0, stream>>>(a2b, zc, ta, 0.f, 1.f, 1.f);
      bmm256_mfma_kernel<<<dim3(4, 4, 8), 256, 0, stream>>>(ta, ta, tb, 7.f, -1.f, 1.f);
      bmm256_mfma_kernel<<<dim3(4, 4, 8), 256, 0, stream>>>(ta, tb, tc, 15.f, -1.f, 1.f);
      bmm256_mfma_kernel<<<dim3(4, 4, 8), 256, 0, stream>>>(zc, tc, za, 13.f, -1.f, 0.25f);
      float* tswap = zc; zc = za; za = tswap;
    }
    a3v_part_kernel<<<dim3(4, 8, NCH), 256, 0, stream>>>(qlh, k16, v16, pacc, pml);
    a3v_combine_kernel<<<dim3(256, 8), 64, 0, stream>>>(pacc, pml, t1b);
    zt1_kernel<<<dim3(64, 8), 256, 0, stream>>>(zc, t1b, t2t);
    out_tile_kernel<<<dim3(325, 8), 256, 0, stream>>>(q16, klh, t2t, v16, resw, outh);
    proj_mfma_kernel<<<dim3(325, 8), 256, 0, stream>>>(outh, outwt, outb, hbuf);
  };

  run_layer(l1_nw, l1_nb, qkv_wt1, out_wt1, l1_outb, l1_resw);
  ppeg_conv_kernel<<<dim3(HHW / 8, HHW), 512, 0, stream>>>(hbuf, wcomb, bcomb, xp);
  ppeg_copy_kernel<<<(NFEAT * D_ + 255) / 256, 256, 0, stream>>>(xp, hbuf);
  run_layer(l2_nw, l2_nb, qkv_wt2, out_wt2, l2_outb, l2_resw);
  final_kernel<<<1, 512, 0, stream>>>(hbuf, norm_w, norm_b, fc3_w, fc3_b, (float*)d_out);
}